// Round 7
// baseline (3727.453 us; speedup 1.0000x reference)
//
#include <hip/hip_runtime.h>
#include <stdint.h>

// MinGRUBlock on MI355X (gfx950). Input/output dtype (f32 vs bf16) DETECTED at
// runtime from x's bit patterns (flag in ws). Internals bf16. Residual in ws.
// Small GEMMs: mfma_f32_16x16x32_bf16, 128x128 tile, BK=64, global_load_lds
// w=16, XOR-swizzled LDS (chunk c of row r at c^(r&7)).
// Big GEMMs (FF gate/value and FF out): 256x256 tile, 8 waves, BK=32,
// 2 phases/tile, ONE barrier per phase, 64 KiB LDS -> TWO blocks per CU
// (co-residency: block A's MFMA phase overlaps block B's LDS/barrier phase —
// the separate-pipe overlap rounds 1-6 failed to get in-wave; occupancy
// 21%->~40%). Counted vmcnt(2) publish, XOR swizzle key (r^(r>>2))&3 on 64-B
// rows (verified 2-way max = free). Per-K work identical to the BK=64 kernel.
// W_gate/W_value interleaved at 16-col granularity (lane-local silu-combine).
// Scan: 3-phase chunked, h_t = sigmoid(-g)*h + sigmoid(g)*gfun(hid), f32 carry.

#define DM     1024
#define SEQL   4096
#define FFN    2730
#define FFP    2816
#define NH_OFF 16777216L
#define CHLEN  128

using bf16x8 = __attribute__((ext_vector_type(8))) short;
using f32x4  = __attribute__((ext_vector_type(4))) float;

__device__ __forceinline__ float bf2f(unsigned short h) {
  union { unsigned int u; float f; } v; v.u = ((unsigned int)h) << 16; return v.f;
}
__device__ __forceinline__ unsigned short f2bf(float f) {
  union { float f; unsigned int u; } v; v.f = f;
  unsigned int u = v.u;
  return (unsigned short)((u + 0x7fffu + ((u >> 16) & 1u)) >> 16);
}
__device__ __forceinline__ float ldin(const void* p, long i, int f32mode) {
  return f32mode ? ((const float*)p)[i] : bf2f(((const unsigned short*)p)[i]);
}
__device__ __forceinline__ void stout(void* p, long i, int f32mode, float v) {
  if (f32mode) ((float*)p)[i] = v; else ((unsigned short*)p)[i] = f2bf(v);
}
__device__ __forceinline__ void gload_lds16(const unsigned short* g, unsigned short* lds) {
  __builtin_amdgcn_global_load_lds(
      (const __attribute__((address_space(1))) unsigned int*)g,
      (__attribute__((address_space(3))) unsigned int*)lds,
      16, 0, 0);
}

// ---------------- dtype detection --------------------------------------------
__global__ void detect_k(const unsigned short* __restrict__ x, int* __restrict__ flag) {
  __shared__ int cnt;
  if (threadIdx.x == 0) cnt = 0;
  __syncthreads();
  int c = 0;
  for (int j = 0; j < 4; j++) {
    unsigned short v = x[2 * (threadIdx.x * 4 + j)];
    int ex = (v >> 7) & 0xFF;
    if (ex >= 0x84) c++;
  }
  atomicAdd(&cnt, c);
  __syncthreads();
  if (threadIdx.x == 0) *flag = (cnt >= 32) ? 1 : 0;
}

// ---------------- GEMM: C[M,N] = A[M,K] * B^T  (B stored [N][K], ldb=K) -------
// EPI 0: bf16 plain. EPI 1: bf16 = acc + bias[col] + raw_res (flag).
// EPI 2: bf16 = acc + bf16res. EPI 3: raw_out (flag) = acc + bf16res.
template <int EPI>
__launch_bounds__(256)
__global__ void gemm_bf16(const unsigned short* __restrict__ A, int lda, int aOffZ,
                          const unsigned short* __restrict__ Bm, int bOffZ, int K,
                          void* __restrict__ Cout, int ldc, int cOffZ, long outOff,
                          const unsigned short* __restrict__ bias,
                          const void* __restrict__ res, int ldres, long resOff,
                          const int* __restrict__ flagp) {
  __shared__ __align__(16) unsigned short As[128][64];
  __shared__ __align__(16) unsigned short Bs[128][64];

  const int tid  = threadIdx.x;
  const int w    = tid >> 6;
  const int lane = tid & 63;
  const int z    = blockIdx.z;
  const long tm  = (long)blockIdx.y * 128;
  const long tn  = (long)blockIdx.x * 128;

  const unsigned short* Ag = A + (long)z * aOffZ;
  const unsigned short* Bg = Bm + (long)z * bOffZ;

  f32x4 acc[4][4];
#pragma unroll
  for (int i = 0; i < 4; i++)
#pragma unroll
    for (int j = 0; j < 4; j++) acc[i][j] = (f32x4){0.f, 0.f, 0.f, 0.f};

  const int wrow = w * 32;
  const int srow = lane >> 3;                    // 0..7
  const int scol = (((lane & 7) ^ srow) * 8);    // xor-swizzled source chunk
  const int wm   = (w >> 1) * 64;
  const int wn   = (w & 1) * 64;
  const int quad = lane >> 4;
  const int lo   = lane & 15;
  const int sw   = lo & 7;                       // row-based xor key for reads

  for (int k0 = 0; k0 < K; k0 += 64) {
    __syncthreads();
#pragma unroll
    for (int i = 0; i < 4; i++) {
      const int r = wrow + i * 8;  // wave-uniform LDS base
      gload_lds16(Ag + (tm + r + srow) * (long)lda + k0 + scol, &As[r][0]);
      gload_lds16(Bg + (tn + r + srow) * (long)K + k0 + scol, &Bs[r][0]);
    }
    __syncthreads();
#pragma unroll
    for (int kk = 0; kk < 64; kk += 32) {
      const int kc = kk >> 3;  // 0 or 4
      bf16x8 af[4], bfr[4];
#pragma unroll
      for (int mt = 0; mt < 4; mt++)
        af[mt] = *(const bf16x8*)&As[wm + mt * 16 + lo][((quad + kc) ^ sw) * 8];
#pragma unroll
      for (int nt = 0; nt < 4; nt++)
        bfr[nt] = *(const bf16x8*)&Bs[wn + nt * 16 + lo][((quad + kc) ^ sw) * 8];
#pragma unroll
      for (int mt = 0; mt < 4; mt++)
#pragma unroll
        for (int nt = 0; nt < 4; nt++)
          acc[mt][nt] = __builtin_amdgcn_mfma_f32_16x16x32_bf16(af[mt], bfr[nt], acc[mt][nt], 0, 0, 0);
    }
  }

  const int f32m = (EPI == 1 || EPI == 3) ? *flagp : 0;
#pragma unroll
  for (int mt = 0; mt < 4; mt++) {
#pragma unroll
    for (int nt = 0; nt < 4; nt++) {
#pragma unroll
      for (int r = 0; r < 4; r++) {
        const long grow = tm + wm + mt * 16 + quad * 4 + r;
        const long gcol = tn + wn + nt * 16 + lo;
        float v         = acc[mt][nt][r];
        if (EPI == 0) {
          ((unsigned short*)Cout + (long)z * cOffZ)[grow * (long)ldc + gcol] = f2bf(v);
        } else if (EPI == 1) {
          v += bf2f(bias[gcol]) + ldin(res, resOff + grow * (long)ldres + gcol, f32m);
          ((unsigned short*)Cout)[grow * (long)ldc + gcol] = f2bf(v);
        } else if (EPI == 2) {
          v += bf2f(((const unsigned short*)res + (long)z * cOffZ)[grow * (long)ldres + gcol]);
          ((unsigned short*)Cout + (long)z * cOffZ)[grow * (long)ldc + gcol] = f2bf(v);
        } else {  // EPI == 3: final output
          v += bf2f(((const unsigned short*)res)[grow * (long)ldres + gcol]);
          stout(Cout, outOff + grow * (long)ldc + gcol, f32m, v);
        }
      }
    }
  }
}

// ---------------- fused FF GEMM (legacy 128^2 path, used when MT<256) ---------
__launch_bounds__(256)
__global__ void gemm_ff(const unsigned short* __restrict__ A,
                        const unsigned short* __restrict__ Bgm,
                        const unsigned short* __restrict__ Bvm,
                        unsigned short* __restrict__ Cout) {
  __shared__ __align__(16) unsigned short As[128][64];
  __shared__ __align__(16) unsigned short Bgs[128][64];
  __shared__ __align__(16) unsigned short Bvs[128][64];

  const int tid  = threadIdx.x;
  const int w    = tid >> 6;
  const int lane = tid & 63;
  const long tm  = (long)blockIdx.y * 128;
  const long tn  = (long)blockIdx.x * 128;

  f32x4 accG[4][4], accV[4][4];
#pragma unroll
  for (int i = 0; i < 4; i++)
#pragma unroll
    for (int j = 0; j < 4; j++) {
      accG[i][j] = (f32x4){0.f, 0.f, 0.f, 0.f};
      accV[i][j] = (f32x4){0.f, 0.f, 0.f, 0.f};
    }

  const int wrow = w * 32;
  const int srow = lane >> 3;
  const int scol = (((lane & 7) ^ srow) * 8);
  const int wm   = (w >> 1) * 64;
  const int wn   = (w & 1) * 64;
  const int quad = lane >> 4;
  const int lo   = lane & 15;
  const int sw   = lo & 7;

  for (int k0 = 0; k0 < DM; k0 += 64) {
    __syncthreads();
#pragma unroll
    for (int i = 0; i < 4; i++) {
      const int r = wrow + i * 8;
      gload_lds16(A + (tm + r + srow) * (long)DM + k0 + scol, &As[r][0]);
      gload_lds16(Bgm + (tn + r + srow) * (long)DM + k0 + scol, &Bgs[r][0]);
      gload_lds16(Bvm + (tn + r + srow) * (long)DM + k0 + scol, &Bvs[r][0]);
    }
    __syncthreads();
#pragma unroll
    for (int kk = 0; kk < 64; kk += 32) {
      const int kc = kk >> 3;
      bf16x8 af[4], bfr[4];
#pragma unroll
      for (int mt = 0; mt < 4; mt++)
        af[mt] = *(const bf16x8*)&As[wm + mt * 16 + lo][((quad + kc) ^ sw) * 8];
#pragma unroll
      for (int nt = 0; nt < 4; nt++)
        bfr[nt] = *(const bf16x8*)&Bgs[wn + nt * 16 + lo][((quad + kc) ^ sw) * 8];
#pragma unroll
      for (int mt = 0; mt < 4; mt++)
#pragma unroll
        for (int nt = 0; nt < 4; nt++)
          accG[mt][nt] = __builtin_amdgcn_mfma_f32_16x16x32_bf16(af[mt], bfr[nt], accG[mt][nt], 0, 0, 0);
#pragma unroll
      for (int nt = 0; nt < 4; nt++)
        bfr[nt] = *(const bf16x8*)&Bvs[wn + nt * 16 + lo][((quad + kc) ^ sw) * 8];
#pragma unroll
      for (int mt = 0; mt < 4; mt++)
#pragma unroll
        for (int nt = 0; nt < 4; nt++)
          accV[mt][nt] = __builtin_amdgcn_mfma_f32_16x16x32_bf16(af[mt], bfr[nt], accV[mt][nt], 0, 0, 0);
    }
  }

#pragma unroll
  for (int mt = 0; mt < 4; mt++) {
#pragma unroll
    for (int nt = 0; nt < 4; nt++) {
#pragma unroll
      for (int r = 0; r < 4; r++) {
        const long grow = tm + wm + mt * 16 + quad * 4 + r;
        const long gcol = tn + wn + nt * 16 + lo;
        const float g   = accG[mt][nt][r];
        const float s   = g / (1.f + __expf(-g));
        Cout[grow * (long)FFP + gcol] = f2bf(s * accV[mt][nt][r]);
      }
    }
  }
}

// ---------------- 256^2 GEMM, BK=32, 2-phase, 2 blocks/CU --------------------
// C[M,N'] = A[M,K] * B^T (B stored [NB][K]). 512 threads = 8 waves (2M x 4N).
// Per wave: 128x64 output. BK=32, double-buffered 64 KiB LDS -> 2 blocks/CU
// (the round-7 lever: co-resident blocks overlap LDS-pipe and MFMA-pipe
// phases across blocks; rounds 1-6 showed in-wave overlap caps at ~34%).
// Swizzle: 64-B rows, 4 chunks of 16 B; chunk c of row r stored at
// c ^ key(r), key(r) = (r ^ (r>>2)) & 3. Read-side bank aliasing: 2-way max
// (free, m136). Phases per tile t (cb = t&1, compile-time via 2x unroll):
//   P0: read aL(m0-3) [4] + b(n0-3) [4]; stage A(t+1)->cb^1 [2 gloads]
//       (A[cb^1] dead since P1(t-1) bar); MFMA m0-3 x n0-3; bar
//   P1: read aH(m4-7) [4]; stage B(t+2)->cb [2] (B[cb] dead since P0 bar);
//       MFMA m4-7 x n0-3; vmcnt(2); bar
// vmcnt ledger: queue after P1(t) = [A(t+1)x2 @P0(t), B(t+2)x2 @P1(t)];
// vmcnt(2) drains A(t+1) and all older (incl. B(t+1) @P1(t-1)) -> tile t+1
// fully resident for P0(t+1). Prologue: B(0),A(0),B(1) [6]; vmcnt(2); bar
// (A(1) arrives via P0(0)'s stage). Tail: t=NT-2: SA=1 (A(NT-1)), SB=0,
// vmcnt(0); t=NT-1: none. NT = K/32 even >= 4 (K=1024 -> 32, K=2816 -> 88).
// Registers: frags 32 VGPR peak + acc 128 + misc -> no spill risk
// (WRITE_SIZE must stay ~90112 KB).
// EPI 0: FF fused, B rows interleaved gate/value at 16-col granularity
//   (row R: tile=R>>8, pair=(R&255)>>5, sel=(R>>4)&1, col=tile*128+pair*16+(R&15));
//   epilogue: ffin[row][col] = silu(accG)*accV, lane-local (nt even=gate, odd=val).
// EPI 1: out(raw flag) = acc + bf16 res.
template <int EPI>
__launch_bounds__(512, 4)
__global__ void gemm256(const unsigned short* __restrict__ A,
                        const unsigned short* __restrict__ Bm,
                        int K,
                        void* __restrict__ Cout,
                        const unsigned short* __restrict__ res,
                        long outOff,
                        const int* __restrict__ flagp) {
  __shared__ __align__(16) unsigned short As[2][256][32];
  __shared__ __align__(16) unsigned short Bs[2][256][32];

  const int tid  = threadIdx.x;
  const int w    = tid >> 6;
  const int lane = tid & 63;
  const int wr   = w >> 2;      // 0..1
  const int wc   = w & 3;       // 0..3
  const int quad = lane >> 4;
  const int lo   = lane & 15;
  const int rkey = ((lo & 3) ^ (lo >> 2)) & 3;   // read-side swizzle key

  // bijective XCD-aware block swizzle (m204 formula)
  const int gx  = gridDim.x;
  int bid       = blockIdx.y * gx + blockIdx.x;
  const int nwg = gx * gridDim.y;
  {
    const int q = nwg >> 3, r8 = nwg & 7;
    const int xc8 = bid & 7, j = bid >> 3;
    bid = (xc8 < r8 ? xc8 * (q + 1) : r8 * (q + 1) + (xc8 - r8) * q) + j;
  }
  const long tn = (long)(bid % gx) * 256;  // B-row tile base
  const long tm = (long)(bid / gx) * 256;  // M tile base

  const int NT = K >> 5;  // even, >= 4 by construction

  // staging source addressing: per-lane swizzled global address, linear LDS.
  // granule = 128 rows (8 waves x 16 rows); thread covers row w*16+(lane>>2),
  // store chunk pos lane&3, source chunk (lane&3)^key(row).
  const int srow = lane >> 2;                    // 0..15 (row within wave slab)
  const int spos = lane & 3;
  const int skey = ((srow & 3) ^ (srow >> 2)) & 3;
  const unsigned short* Ab = A + (tm + (long)w * 16 + srow) * (long)K + (spos ^ skey) * 8;
  const unsigned short* Bb = Bm + (tn + (long)w * 16 + srow) * (long)K + (spos ^ skey) * 8;

#define STAGE_A(BUF, TT, G) \
  gload_lds16(Ab + (long)((G) * 128) * K + (long)(TT) * 32, &As[BUF][(G) * 128 + w * 16][0])
#define STAGE_B(BUF, TT, G) \
  gload_lds16(Bb + (long)((G) * 128) * K + (long)(TT) * 32, &Bs[BUF][(G) * 128 + w * 16][0])

  // prologue (age order): B(0), A(0), B(1); A(1) arrives via P0(0)'s stage
  STAGE_B(0, 0, 0); STAGE_B(0, 0, 1);
  STAGE_A(0, 0, 0); STAGE_A(0, 0, 1);
  STAGE_B(1, 1, 0); STAGE_B(1, 1, 1);

  f32x4 acc[8][4];
#pragma unroll
  for (int i = 0; i < 8; i++)
#pragma unroll
    for (int j = 0; j < 4; j++) acc[i][j] = (f32x4){0.f, 0.f, 0.f, 0.f};

  // tile0 landed for every wave (B(1)'s 2 remain in flight)
  asm volatile("s_waitcnt vmcnt(2)" ::: "memory");
  __builtin_amdgcn_s_barrier();

  bf16x8 aF[4], bF[4];

#define LDA4(CBUF, MB)                                                            \
  _Pragma("unroll") for (int m = 0; m < 4; m++) {                                 \
    aF[m] = *(const bf16x8*)&As[CBUF][wr * 128 + ((MB) + m) * 16 + lo]            \
                                    [(quad ^ rkey) * 8];                          \
  }
#define LDB4(CBUF)                                                                \
  _Pragma("unroll") for (int n = 0; n < 4; n++) {                                 \
    bF[n] = *(const bf16x8*)&Bs[CBUF][wc * 64 + n * 16 + lo]                      \
                                    [(quad ^ rkey) * 8];                          \
  }
#define MFMA16(MB)                                                                \
  __builtin_amdgcn_s_setprio(1);                                                  \
  _Pragma("unroll") for (int m = 0; m < 4; m++) {                                 \
    _Pragma("unroll") for (int n = 0; n < 4; n++) {                               \
      acc[(MB) + m][n] = __builtin_amdgcn_mfma_f32_16x16x32_bf16(                 \
          aF[m], bF[n], acc[(MB) + m][n], 0, 0, 0);                               \
    }                                                                             \
  }                                                                               \
  __builtin_amdgcn_s_setprio(0);

// One sub-tile. SA: stage A(TT+1)->CBUF^1 at P0; SB: stage B(TT+2)->CBUF at P1;
// VM: 2 steady / 0 tail / -1 none.
#define SUBTILE(CBUF, TT, SA, SB, VM)                                             \
  {                                                                               \
    /* P0: reads aL+b (published at prev P1); stage A(TT+1); MFMA m0-3 */         \
    LDA4(CBUF, 0);                                                                \
    LDB4(CBUF);                                                                   \
    if (SA) { STAGE_A(CBUF ^ 1, (TT) + 1, 0); STAGE_A(CBUF ^ 1, (TT) + 1, 1); }   \
    MFMA16(0);                                                                    \
    __builtin_amdgcn_s_barrier();                                                 \
    /* P1: read aH; stage B(TT+2) (B[CBUF] dead since P0 bar); MFMA m4-7 */       \
    LDA4(CBUF, 4);                                                                \
    if (SB) { STAGE_B(CBUF, (TT) + 2, 0); STAGE_B(CBUF, (TT) + 2, 1); }           \
    MFMA16(4);                                                                    \
    if ((VM) == 2) asm volatile("s_waitcnt vmcnt(2)" ::: "memory");               \
    else if ((VM) == 0) asm volatile("s_waitcnt vmcnt(0)" ::: "memory");          \
    __builtin_amdgcn_s_barrier();                                                 \
  }

  // main loop: subtiles 0..NT-3 (stage targets TT+1 <= NT-2, TT+2 <= NT-1)
  for (int t = 0; t + 3 < NT; t += 2) {
    SUBTILE(0, t, 1, 1, 2)
    SUBTILE(1, t + 1, 1, 1, 2)
  }
  // tails: NT-2 (stage A(NT-1) only; drain everything), NT-1 (no stages/wait)
  SUBTILE(0, NT - 2, 1, 0, 0)
  SUBTILE(1, NT - 1, 0, 0, -1)

  if (EPI == 0) {
    // silu(gate) * value, lane-local pairing; ffin col base = tn/2
    const long colb = (tn >> 1);
    const long rowb = tm + wr * 128;
#pragma unroll
    for (int m = 0; m < 8; m++) {
#pragma unroll
      for (int np = 0; np < 2; np++) {
        const long col = colb + (wc * 2 + np) * 16 + lo;
#pragma unroll
        for (int r = 0; r < 4; r++) {
          const long row = rowb + m * 16 + quad * 4 + r;
          const float g  = acc[m][2 * np][r];
          const float v  = acc[m][2 * np + 1][r];
          const float s  = g / (1.f + __expf(-g));
          ((unsigned short*)Cout)[row * (long)FFP + col] = f2bf(s * v);
        }
      }
    }
  } else {
    const int f32m = *flagp;
    const long rowb = tm + wr * 128;
    const long colb = tn + wc * 64;
#pragma unroll
    for (int m = 0; m < 8; m++) {
#pragma unroll
      for (int n = 0; n < 4; n++) {
#pragma unroll
        for (int r = 0; r < 4; r++) {
          const long row = rowb + m * 16 + quad * 4 + r;
          const long col = colb + n * 16 + lo;
          float v = acc[m][n][r] + bf2f(res[row * (long)DM + col]);
          stout(Cout, outOff + row * (long)DM + col, f32m, v);
        }
      }
    }
  }
#undef STAGE_A
#undef STAGE_B
#undef LDA4
#undef LDB4
#undef MFMA16
#undef SUBTILE
}

// ---------------- RMSNorm: raw input variant (flag) --------------------------
__global__ void rmsnorm_x(const void* __restrict__ in, long elemOff,
                          const unsigned short* __restrict__ gamma,
                          unsigned short* __restrict__ out,
                          const int* __restrict__ flagp) {
  const int t    = blockIdx.x;
  const int lane = threadIdx.x;
  const int f32m = *flagp;
  float v[16];
  const long base = elemOff + (long)t * DM;
  if (f32m) {
    const float4* rp = (const float4*)((const float*)in + base);
#pragma unroll
    for (int j = 0; j < 4; j++) {
      float4 u     = rp[j * 64 + lane];
      v[j * 4 + 0] = u.x; v[j * 4 + 1] = u.y; v[j * 4 + 2] = u.z; v[j * 4 + 3] = u.w;
    }
  } else {
    const ushort4* rp = (const ushort4*)((const unsigned short*)in + base);
#pragma unroll
    for (int j = 0; j < 4; j++) {
      ushort4 u    = rp[j * 64 + lane];
      v[j * 4 + 0] = bf2f(u.x); v[j * 4 + 1] = bf2f(u.y);
      v[j * 4 + 2] = bf2f(u.z); v[j * 4 + 3] = bf2f(u.w);
    }
  }
  float s = 0.f;
#pragma unroll
  for (int i = 0; i < 16; i++) s = fmaf(v[i], v[i], s);
#pragma unroll
  for (int off = 32; off > 0; off >>= 1) s += __shfl_xor(s, off, 64);
  const float scale = 32.f / fmaxf(sqrtf(s), 1e-12f);
  ushort4* op       = (ushort4*)(out + (long)t * DM);
  const ushort4* gp = (const ushort4*)gamma;
#pragma unroll
  for (int j = 0; j < 4; j++) {
    ushort4 g = gp[j * 64 + lane];
    ushort4 o;
    o.x = f2bf(v[j * 4 + 0] * scale * (bf2f(g.x) + 1.f));
    o.y = f2bf(v[j * 4 + 1] * scale * (bf2f(g.y) + 1.f));
    o.z = f2bf(v[j * 4 + 2] * scale * (bf2f(g.z) + 1.f));
    o.w = f2bf(v[j * 4 + 3] * scale * (bf2f(g.w) + 1.f));
    op[j * 64 + lane] = o;
  }
}

// ---------------- RMSNorm (bf16 in/out) --------------------------------------
__global__ void rmsnorm_k(const unsigned short* __restrict__ in,
                          const unsigned short* __restrict__ gamma,
                          unsigned short* __restrict__ out) {
  const int t    = blockIdx.x;
  const int lane = threadIdx.x;
  float v[16];
  const ushort4* rp = (const ushort4*)(in + (long)t * DM);
#pragma unroll
  for (int j = 0; j < 4; j++) {
    ushort4 u    = rp[j * 64 + lane];
    v[j * 4 + 0] = bf2f(u.x); v[j * 4 + 1] = bf2f(u.y);
    v[j * 4 + 2] = bf2f(u.z); v[j * 4 + 3] = bf2f(u.w);
  }
  float s = 0.f;
#pragma unroll
  for (int i = 0; i < 16; i++) s = fmaf(v[i], v[i], s);
#pragma unroll
  for (int off = 32; off > 0; off >>= 1) s += __shfl_xor(s, off, 64);
  const float scale = 32.f / fmaxf(sqrtf(s), 1e-12f);
  ushort4* op       = (ushort4*)(out + (long)t * DM);
  const ushort4* gp = (const ushort4*)gamma;
#pragma unroll
  for (int j = 0; j < 4; j++) {
    ushort4 g = gp[j * 64 + lane];
    ushort4 o;
    o.x = f2bf(v[j * 4 + 0] * scale * (bf2f(g.x) + 1.f));
    o.y = f2bf(v[j * 4 + 1] * scale * (bf2f(g.y) + 1.f));
    o.z = f2bf(v[j * 4 + 2] * scale * (bf2f(g.z) + 1.f));
    o.w = f2bf(v[j * 4 + 3] * scale * (bf2f(g.w) + 1.f));
    op[j * 64 + lane] = o;
  }
}

// ---------------- causal depthwise conv K=4 ----------------------------------
__global__ void dwconv_k(const unsigned short* __restrict__ xn,
                         const unsigned short* __restrict__ dww,
                         const unsigned short* __restrict__ dwb,
                         unsigned short* __restrict__ y, int l0) {
  const int t = blockIdx.x;
  const int d = blockIdx.y * 256 + threadIdx.x;
  const int l = l0 + (t & (SEQL - 1));
  ushort4 w4  = ((const ushort4*)dww)[d];
  float wk[4] = {bf2f(w4.x), bf2f(w4.y), bf2f(w4.z), bf2f(w4.w)};
  float acc   = bf2f(dwb[d]);
#pragma unroll
  for (int k = 0; k < 4; k++) {
    const int ll = l + k - 3;
    if (ll >= 0) acc = fmaf(bf2f(xn[(long)(t + k - 3) * DM + d]), wk[k], acc);
  }
  y[(long)t * DM + d] = f2bf(acc);
}

// ---------------- scan --------------------------------------------------------
__device__ __forceinline__ void cv_compute(float gt, float& c, float& sg) {
  gt = fminf(fmaxf(gt, -40.f), 40.f);
  const float e  = __expf(-fabsf(gt));
  const float r  = 1.f / (1.f + e);
  const float rs = e * r;
  c  = (gt >= 0.f) ? rs : r;   // sigmoid(-gt)
  sg = (gt >= 0.f) ? r : rs;   // sigmoid(gt)
}
__device__ __forceinline__ float gfun(float hid) {
  hid = fminf(fmaxf(hid, -40.f), 40.f);
  if (hid >= 0.f) return hid + 0.5f;
  const float e = __expf(hid);
  return e / (1.f + e);
}

__global__ void scan_p1(const unsigned short* __restrict__ hg, float* __restrict__ cC,
                        float* __restrict__ cV, int chTot, int SL) {
  const int e = threadIdx.x, bh = blockIdx.y, cid = blockIdx.x;
  const int bL = bh >> 2, hh = bh & 3;
  long base = ((long)(bL * SL + cid * CHLEN)) * 3072 + hh * 768 + e;
  float C = 1.f, V = 0.f;
  for (int i = 0; i < CHLEN; i++) {
    const float hid = bf2f(hg[base]), gt = bf2f(hg[base + 384]);
    float c, sg; cv_compute(gt, c, sg);
    C *= c;
    V = fmaf(c, V, sg * gfun(hid));
    base += 3072;
  }
  const int idx = cid * chTot + bh * 384 + e;
  cC[idx] = C; cV[idx] = V;
}

__global__ void scan_p2(const float* __restrict__ cC, const float* __restrict__ cV,
                        float* __restrict__ hin, int chTot, int CHNp,
                        const float* __restrict__ hcarry, int useCarry) {
  const int ch = blockIdx.x * 384 + threadIdx.x;
  float h = useCarry ? hcarry[ch] : 0.f;
  for (int cid = 0; cid < CHNp; cid++) {
    const int idx = cid * chTot + ch;
    hin[idx] = h;
    h = fmaf(cC[idx], h, cV[idx]);
  }
}

__global__ void scan_p3(const unsigned short* __restrict__ hg, const float* __restrict__ hin,
                        unsigned short* __restrict__ hout, void* __restrict__ nh, long nhOff,
                        float* __restrict__ hcarry, int chTot, int SL, int CHNp,
                        int writeNh, const int* __restrict__ flagp) {
  const int e = threadIdx.x, bh = blockIdx.y, cid = blockIdx.x;
  const int bL = bh >> 2, hh = bh & 3;
  const long tok = (long)bL * SL + (long)cid * CHLEN;
  long base  = tok * 3072 + hh * 768 + e;
  long obase = tok * 1536 + hh * 384 + e;
  float h = hin[cid * chTot + bh * 384 + e];
  for (int i = 0; i < CHLEN; i++) {
    const float hid = bf2f(hg[base]), gt = bf2f(hg[base + 384]);
    float c, sg; cv_compute(gt, c, sg);
    h = fmaf(c, h, sg * gfun(hid));
    hout[obase] = f2bf(h);
    base += 3072; obase += 1536;
  }
  if (cid == CHNp - 1) {
    hcarry[bh * 384 + e] = h;
    if (writeNh) stout(nh, nhOff + bL * 1536 + hh * 384 + e, *flagp, h);
  }
}

// ---------------- weight conversion / transposes (flag-branching reads) -------
__global__ void cvt_k(const void* __restrict__ in, unsigned short* __restrict__ out,
                      int n, const int* __restrict__ flagp) {
  const int i = blockIdx.x * 256 + threadIdx.x;
  if (i < n) out[i] = f2bf(ldin(in, i, *flagp));
}
__global__ void tr_whg(const void* __restrict__ in, unsigned short* __restrict__ out,
                       const int* __restrict__ flagp) {
  const int idx = blockIdx.x * 256 + threadIdx.x;  // (h*768+n)*256+k
  const int k = idx & 255, n = (idx >> 8) % 768, h = idx / (768 * 256);
  out[idx] = f2bf(ldin(in, (long)(h * 256 + k) * 768 + n, *flagp));
}
__global__ void tr_wout(const void* __restrict__ in, unsigned short* __restrict__ out,
                        const int* __restrict__ flagp) {
  const int idx = blockIdx.x * 256 + threadIdx.x;  // (h*256+n)*384+k
  const int k = idx % 384, n = (idx / 384) & 255, h = idx / (384 * 256);
  out[idx] = f2bf(ldin(in, (long)(h * 384 + k) * 256 + n, *flagp));
}
__global__ void tr_wg(const void* __restrict__ in, unsigned short* __restrict__ out,
                      const int* __restrict__ flagp) {
  const int idx = blockIdx.x * 256 + threadIdx.x;  // n*1024+k, n<2816
  const int k = idx & 1023, n = idx >> 10;
  out[idx] = (n < FFN) ? f2bf(ldin(in, (long)k * FFN + n, *flagp)) : (unsigned short)0;
}
// interleaved gate/value: B row R -> tile=R>>8, pair=(R&255)>>5, sel=(R>>4)&1,
// col = tile*128 + pair*16 + (R&15); out[R][k] = W_{sel}[k][col] (0 if col>=FFN)
__global__ void tr_wgv(const void* __restrict__ wg, const void* __restrict__ wv,
                       unsigned short* __restrict__ out, const int* __restrict__ flagp) {
  const int idx = blockIdx.x * 256 + threadIdx.x;  // R*1024+k, R<5632
  const int k = idx & 1023, R = idx >> 10;
  const int tile = R >> 8, rb = R & 255;
  const int pair = rb >> 5, sel = (rb >> 4) & 1, r16 = rb & 15;
  const int col  = tile * 128 + pair * 16 + r16;
  const void* src = sel ? wv : wg;
  out[idx] = (col < FFN) ? f2bf(ldin(src, (long)k * FFN + col, *flagp)) : (unsigned short)0;
}
__global__ void tr_wfo(const void* __restrict__ in, unsigned short* __restrict__ out,
                       const int* __restrict__ flagp) {
  const int idx = blockIdx.x * 256 + threadIdx.x;  // n*2816+kk
  const int kk = idx % FFP, n = idx / FFP;
  out[idx] = (kk < FFN) ? f2bf(ldin(in, (long)kk * DM + n, *flagp)) : (unsigned short)0;
}

// ---------------- launch ------------------------------------------------------
extern "C" void kernel_launch(void* const* d_in, const int* in_sizes, int n_in,
                              void* d_out, int out_size, void* d_ws, size_t ws_size,
                              hipStream_t stream) {
  const void* x      = d_in[0];
  const void* dw_w   = d_in[1];
  const void* dw_b   = d_in[2];
  const void* pw_w   = d_in[3];  // [N=1024][K=1024] already
  const void* pw_b   = d_in[4];
  const void* conv_g = d_in[5];
  const void* gru_g  = d_in[6];
  const void* ff_g   = d_in[7];
  const void* w_hg   = d_in[8];
  const void* w_out  = d_in[9];
  const void* w_gate = d_in[10];
  const void* w_val  = d_in[11];
  const void* w_ffo  = d_in[12];

  // Pass size from ws_size (deterministic): need(MT) = 21,795,072 + MT*13,888.
  const long FIXED = 21795072L;
  int MT = 128;
  if      (ws_size >= (size_t)(FIXED + 16384L * 13888)) MT = 16384;
  else if (ws_size >= (size_t)(FIXED + 8192L * 13888))  MT = 8192;
  else if (ws_size >= (size_t)(FIXED + 4096L * 13888))  MT = 4096;
  else if (ws_size >= (size_t)(FIXED + 2048L * 13888))  MT = 2048;
  else if (ws_size >= (size_t)(FIXED + 1024L * 13888))  MT = 1024;
  else if (ws_size >= (size_t)(FIXED + 512L * 13888))   MT = 512;
  else if (ws_size >= (size_t)(FIXED + 256L * 13888))   MT = 256;

  const int SL    = (MT >= SEQL) ? SEQL : MT;
  const int nSeq  = MT / SL;
  const int CHNp  = SL / CHLEN;
  const int chTot = nSeq * 1536;
  const int big   = (MT >= 256);  // 256^2 pipelined path for the two FF GEMMs

  char* p = (char*)d_ws;
  unsigned short* whgT  = (unsigned short*)p; p += 1572864;
  unsigned short* woutT = (unsigned short*)p; p += 786432;
  unsigned short* wgT   = (unsigned short*)p; p += 5767168;
  unsigned short* wvT   = (unsigned short*)p; p += 5767168;
  unsigned short* wfoT  = (unsigned short*)p; p += 5767168;
  unsigned short* pwT   = (unsigned short*)p; p += 2097152;
  unsigned short* dwwB  = (unsigned short*)p; p += 8192;
  unsigned short* dwbB  = (unsigned short*)p; p += 2048;
  unsigned short* pwbB  = (unsigned short*)p; p += 2048;
  unsigned short* cgB   = (unsigned short*)p; p += 2048;
  unsigned short* ggB   = (unsigned short*)p; p += 2048;
  unsigned short* fgB   = (unsigned short*)p; p += 2048;
  int*            flag  = (int*)p;            p += 256;
  float*          hcarry= (float*)p;          p += 12288;
  float*          cC    = (float*)p;          p += (long)MT * 192;
  float*          cV    = (float*)p;          p += (long)MT * 192;
  float*          hin   = (float*)p;          p += (long)MT * 192;
  unsigned short* xnb   = (unsigned short*)p; p += 6144 + (long)MT * 2048;
  unsigned short* xc    = (unsigned short*)p; p += (long)MT * 2048;
  unsigned short* hbuf  = (unsigned short*)p; p += (long)MT * 3072;
  unsigned short* ybuf  = (unsigned short*)p;  // region R: ybuf / hg / ffin
  unsigned short* hg    = (unsigned short*)p;
  unsigned short* ffin  = (unsigned short*)p;
  unsigned short* xn    = xnb + 3 * DM;
  unsigned short* wgvT  = wgT;  // interleaved [5632][1024] spans wgT+wvT slots

  // dtype detection + weight conversion (once per call)
  detect_k<<<1, 256, 0, stream>>>((const unsigned short*)x, flag);
  tr_whg<<<3072, 256, 0, stream>>>(w_hg, whgT, flag);
  tr_wout<<<1536, 256, 0, stream>>>(w_out, woutT, flag);
  if (big) {
    tr_wgv<<<22528, 256, 0, stream>>>(w_gate, w_val, wgvT, flag);
  } else {
    tr_wg<<<11264, 256, 0, stream>>>(w_gate, wgT, flag);
    tr_wg<<<11264, 256, 0, stream>>>(w_val, wvT, flag);
  }
  tr_wfo<<<11264, 256, 0, stream>>>(w_ffo, wfoT, flag);
  cvt_k<<<4096, 256, 0, stream>>>(pw_w, pwT, 1048576, flag);
  cvt_k<<<16, 256, 0, stream>>>(dw_w, dwwB, 4096, flag);
  cvt_k<<<4, 256, 0, stream>>>(dw_b, dwbB, 1024, flag);
  cvt_k<<<4, 256, 0, stream>>>(pw_b, pwbB, 1024, flag);
  cvt_k<<<4, 256, 0, stream>>>(conv_g, cgB, 1024, flag);
  cvt_k<<<4, 256, 0, stream>>>(gru_g, ggB, 1024, flag);
  cvt_k<<<4, 256, 0, stream>>>(ff_g, fgB, 1024, flag);

  for (long t0 = 0; t0 < 16384; t0 += MT) {
    const int l0     = (int)(t0 & (SEQL - 1));
    const int P      = (l0 > 0) ? 3 : 0;
    const int seqEnd = (l0 + SL == SEQL);
    const long nhOff = NH_OFF + (t0 / SEQL) * 1536;

    // conv block: xc = pw(dwconv(rmsnorm(x))) + pw_b + x
    rmsnorm_x<<<MT + P, 64, 0, stream>>>(x, (t0 - P) * DM, cgB, xn - (long)P * DM, flag);
    dwconv_k<<<dim3(MT, 4), 256, 0, stream>>>(xn, dwwB, dwbB, ybuf, l0);
    gemm_bf16<1><<<dim3(8, MT / 128, 1), 256, 0, stream>>>(ybuf, DM, 0, pwT, 0, DM,
        xc, DM, 0, 0L, pwbB, x, DM, t0 * DM, flag);

    // GRU block
    rmsnorm_k<<<MT, 64, 0, stream>>>(xc, ggB, xn);
    gemm_bf16<0><<<dim3(6, MT / 128, 4), 256, 0, stream>>>(xn, DM, 256, whgT, 196608, 256,
        hg, 3072, 768, 0L, nullptr, nullptr, 0, 0L, nullptr);
    scan_p1<<<dim3(CHNp, nSeq * 4), 384, 0, stream>>>(hg, cC, cV, chTot, SL);
    scan_p2<<<nSeq * 4, 384, 0, stream>>>(cC, cV, hin, chTot, CHNp, hcarry, l0 > 0);
    scan_p3<<<dim3(CHNp, nSeq * 4), 384, 0, stream>>>(hg, hin, hbuf, d_out, nhOff,
        hcarry, chTot, SL, CHNp, seqEnd, flag);
    gemm_bf16<2><<<dim3(2, MT / 128, 4), 256, 0, stream>>>(hbuf, 1536, 384, woutT, 98304, 384,
        xc, DM, 256, 0L, nullptr, xc, DM, 0L, nullptr);

    // FF block
    rmsnorm_k<<<MT, 64, 0, stream>>>(xc, fgB, xn);
    if (big) {
      gemm256<0><<<dim3(22, MT / 256), 512, 0, stream>>>(xn, wgvT, DM,
          ffin, nullptr, 0L, nullptr);
      gemm256<1><<<dim3(4, MT / 256), 512, 0, stream>>>(ffin, wfoT, FFP,
          d_out, xc, t0 * DM, flag);
    } else {
      gemm_ff<<<dim3(22, MT / 128), 256, 0, stream>>>(xn, wgT, wvT, ffin);
      gemm_bf16<3><<<dim3(8, MT / 128, 1), 256, 0, stream>>>(ffin, FFP, 0, wfoT, 0, FFP,
          d_out, DM, 0, t0 * DM, nullptr, xc, DM, 0L, flag);
    }
  }
}

// Round 8
// 1444.917 us; speedup vs baseline: 2.5797x; 2.5797x over previous
//
#include <hip/hip_runtime.h>
#include <stdint.h>

// MinGRUBlock on MI355X (gfx950). Input/output dtype (f32 vs bf16) DETECTED at
// runtime from x's bit patterns (flag in ws). Internals bf16. Residual in ws.
// Small GEMMs: mfma_f32_16x16x32_bf16, 128x128 tile, BK=64, global_load_lds
// w=16, XOR-swizzled LDS (chunk c of row r at c^(r&7)).
// Big GEMMs (FF gate/value and FF out): 256x256 tile, SIXTEEN waves (1024 thr,
// 4 waves/SIMD via __launch_bounds__(1024,4)), per-wave output 64x64 so
// acc = 64 VGPR and frag peak = 48 -> ~127 regs fits the 128/wave budget at
// 4 waves/SIMD (round-7 lesson: 8-wave 256^2 acc=128 regs is incompatible
// with >2 waves/SIMD on the unified file -> total accumulator spill).
// BK=64, dbuf 128 KiB LDS (1 block/CU), round-5 hazard-proven 4-phase quadrant
// schedule (Q0 aL*b01, Q1 aL*b23, Q2 aH*b23, Q3 aH*b01; stage B@P2/A@P3 into
// dead slots; proven zero-conflict chunk-XOR swizzle; vmcnt(4) publish).
// W_gate/W_value interleaved at 16-col granularity (lane-local silu-combine).
// Scan: 3-phase chunked, h_t = sigmoid(-g)*h + sigmoid(g)*gfun(hid), f32 carry.

#define DM     1024
#define SEQL   4096
#define FFN    2730
#define FFP    2816
#define NH_OFF 16777216L
#define CHLEN  128

using bf16x8 = __attribute__((ext_vector_type(8))) short;
using f32x4  = __attribute__((ext_vector_type(4))) float;

__device__ __forceinline__ float bf2f(unsigned short h) {
  union { unsigned int u; float f; } v; v.u = ((unsigned int)h) << 16; return v.f;
}
__device__ __forceinline__ unsigned short f2bf(float f) {
  union { float f; unsigned int u; } v; v.f = f;
  unsigned int u = v.u;
  return (unsigned short)((u + 0x7fffu + ((u >> 16) & 1u)) >> 16);
}
__device__ __forceinline__ float ldin(const void* p, long i, int f32mode) {
  return f32mode ? ((const float*)p)[i] : bf2f(((const unsigned short*)p)[i]);
}
__device__ __forceinline__ void stout(void* p, long i, int f32mode, float v) {
  if (f32mode) ((float*)p)[i] = v; else ((unsigned short*)p)[i] = f2bf(v);
}
__device__ __forceinline__ void gload_lds16(const unsigned short* g, unsigned short* lds) {
  __builtin_amdgcn_global_load_lds(
      (const __attribute__((address_space(1))) unsigned int*)g,
      (__attribute__((address_space(3))) unsigned int*)lds,
      16, 0, 0);
}

// ---------------- dtype detection --------------------------------------------
__global__ void detect_k(const unsigned short* __restrict__ x, int* __restrict__ flag) {
  __shared__ int cnt;
  if (threadIdx.x == 0) cnt = 0;
  __syncthreads();
  int c = 0;
  for (int j = 0; j < 4; j++) {
    unsigned short v = x[2 * (threadIdx.x * 4 + j)];
    int ex = (v >> 7) & 0xFF;
    if (ex >= 0x84) c++;
  }
  atomicAdd(&cnt, c);
  __syncthreads();
  if (threadIdx.x == 0) *flag = (cnt >= 32) ? 1 : 0;
}

// ---------------- GEMM: C[M,N] = A[M,K] * B^T  (B stored [N][K], ldb=K) -------
// EPI 0: bf16 plain. EPI 1: bf16 = acc + bias[col] + raw_res (flag).
// EPI 2: bf16 = acc + bf16res. EPI 3: raw_out (flag) = acc + bf16res.
template <int EPI>
__launch_bounds__(256)
__global__ void gemm_bf16(const unsigned short* __restrict__ A, int lda, int aOffZ,
                          const unsigned short* __restrict__ Bm, int bOffZ, int K,
                          void* __restrict__ Cout, int ldc, int cOffZ, long outOff,
                          const unsigned short* __restrict__ bias,
                          const void* __restrict__ res, int ldres, long resOff,
                          const int* __restrict__ flagp) {
  __shared__ __align__(16) unsigned short As[128][64];
  __shared__ __align__(16) unsigned short Bs[128][64];

  const int tid  = threadIdx.x;
  const int w    = tid >> 6;
  const int lane = tid & 63;
  const int z    = blockIdx.z;
  const long tm  = (long)blockIdx.y * 128;
  const long tn  = (long)blockIdx.x * 128;

  const unsigned short* Ag = A + (long)z * aOffZ;
  const unsigned short* Bg = Bm + (long)z * bOffZ;

  f32x4 acc[4][4];
#pragma unroll
  for (int i = 0; i < 4; i++)
#pragma unroll
    for (int j = 0; j < 4; j++) acc[i][j] = (f32x4){0.f, 0.f, 0.f, 0.f};

  const int wrow = w * 32;
  const int srow = lane >> 3;                    // 0..7
  const int scol = (((lane & 7) ^ srow) * 8);    // xor-swizzled source chunk
  const int wm   = (w >> 1) * 64;
  const int wn   = (w & 1) * 64;
  const int quad = lane >> 4;
  const int lo   = lane & 15;
  const int sw   = lo & 7;                       // row-based xor key for reads

  for (int k0 = 0; k0 < K; k0 += 64) {
    __syncthreads();
#pragma unroll
    for (int i = 0; i < 4; i++) {
      const int r = wrow + i * 8;  // wave-uniform LDS base
      gload_lds16(Ag + (tm + r + srow) * (long)lda + k0 + scol, &As[r][0]);
      gload_lds16(Bg + (tn + r + srow) * (long)K + k0 + scol, &Bs[r][0]);
    }
    __syncthreads();
#pragma unroll
    for (int kk = 0; kk < 64; kk += 32) {
      const int kc = kk >> 3;  // 0 or 4
      bf16x8 af[4], bfr[4];
#pragma unroll
      for (int mt = 0; mt < 4; mt++)
        af[mt] = *(const bf16x8*)&As[wm + mt * 16 + lo][((quad + kc) ^ sw) * 8];
#pragma unroll
      for (int nt = 0; nt < 4; nt++)
        bfr[nt] = *(const bf16x8*)&Bs[wn + nt * 16 + lo][((quad + kc) ^ sw) * 8];
#pragma unroll
      for (int mt = 0; mt < 4; mt++)
#pragma unroll
        for (int nt = 0; nt < 4; nt++)
          acc[mt][nt] = __builtin_amdgcn_mfma_f32_16x16x32_bf16(af[mt], bfr[nt], acc[mt][nt], 0, 0, 0);
    }
  }

  const int f32m = (EPI == 1 || EPI == 3) ? *flagp : 0;
#pragma unroll
  for (int mt = 0; mt < 4; mt++) {
#pragma unroll
    for (int nt = 0; nt < 4; nt++) {
#pragma unroll
      for (int r = 0; r < 4; r++) {
        const long grow = tm + wm + mt * 16 + quad * 4 + r;
        const long gcol = tn + wn + nt * 16 + lo;
        float v         = acc[mt][nt][r];
        if (EPI == 0) {
          ((unsigned short*)Cout + (long)z * cOffZ)[grow * (long)ldc + gcol] = f2bf(v);
        } else if (EPI == 1) {
          v += bf2f(bias[gcol]) + ldin(res, resOff + grow * (long)ldres + gcol, f32m);
          ((unsigned short*)Cout)[grow * (long)ldc + gcol] = f2bf(v);
        } else if (EPI == 2) {
          v += bf2f(((const unsigned short*)res + (long)z * cOffZ)[grow * (long)ldres + gcol]);
          ((unsigned short*)Cout + (long)z * cOffZ)[grow * (long)ldc + gcol] = f2bf(v);
        } else {  // EPI == 3: final output
          v += bf2f(((const unsigned short*)res)[grow * (long)ldres + gcol]);
          stout(Cout, outOff + grow * (long)ldc + gcol, f32m, v);
        }
      }
    }
  }
}

// ---------------- fused FF GEMM (legacy 128^2 path, used when MT<256) ---------
__launch_bounds__(256)
__global__ void gemm_ff(const unsigned short* __restrict__ A,
                        const unsigned short* __restrict__ Bgm,
                        const unsigned short* __restrict__ Bvm,
                        unsigned short* __restrict__ Cout) {
  __shared__ __align__(16) unsigned short As[128][64];
  __shared__ __align__(16) unsigned short Bgs[128][64];
  __shared__ __align__(16) unsigned short Bvs[128][64];

  const int tid  = threadIdx.x;
  const int w    = tid >> 6;
  const int lane = tid & 63;
  const long tm  = (long)blockIdx.y * 128;
  const long tn  = (long)blockIdx.x * 128;

  f32x4 accG[4][4], accV[4][4];
#pragma unroll
  for (int i = 0; i < 4; i++)
#pragma unroll
    for (int j = 0; j < 4; j++) {
      accG[i][j] = (f32x4){0.f, 0.f, 0.f, 0.f};
      accV[i][j] = (f32x4){0.f, 0.f, 0.f, 0.f};
    }

  const int wrow = w * 32;
  const int srow = lane >> 3;
  const int scol = (((lane & 7) ^ srow) * 8);
  const int wm   = (w >> 1) * 64;
  const int wn   = (w & 1) * 64;
  const int quad = lane >> 4;
  const int lo   = lane & 15;
  const int sw   = lo & 7;

  for (int k0 = 0; k0 < DM; k0 += 64) {
    __syncthreads();
#pragma unroll
    for (int i = 0; i < 4; i++) {
      const int r = wrow + i * 8;
      gload_lds16(A + (tm + r + srow) * (long)DM + k0 + scol, &As[r][0]);
      gload_lds16(Bgm + (tn + r + srow) * (long)DM + k0 + scol, &Bgs[r][0]);
      gload_lds16(Bvm + (tn + r + srow) * (long)DM + k0 + scol, &Bvs[r][0]);
    }
    __syncthreads();
#pragma unroll
    for (int kk = 0; kk < 64; kk += 32) {
      const int kc = kk >> 3;
      bf16x8 af[4], bfr[4];
#pragma unroll
      for (int mt = 0; mt < 4; mt++)
        af[mt] = *(const bf16x8*)&As[wm + mt * 16 + lo][((quad + kc) ^ sw) * 8];
#pragma unroll
      for (int nt = 0; nt < 4; nt++)
        bfr[nt] = *(const bf16x8*)&Bgs[wn + nt * 16 + lo][((quad + kc) ^ sw) * 8];
#pragma unroll
      for (int mt = 0; mt < 4; mt++)
#pragma unroll
        for (int nt = 0; nt < 4; nt++)
          accG[mt][nt] = __builtin_amdgcn_mfma_f32_16x16x32_bf16(af[mt], bfr[nt], accG[mt][nt], 0, 0, 0);
#pragma unroll
      for (int nt = 0; nt < 4; nt++)
        bfr[nt] = *(const bf16x8*)&Bvs[wn + nt * 16 + lo][((quad + kc) ^ sw) * 8];
#pragma unroll
      for (int mt = 0; mt < 4; mt++)
#pragma unroll
        for (int nt = 0; nt < 4; nt++)
          accV[mt][nt] = __builtin_amdgcn_mfma_f32_16x16x32_bf16(af[mt], bfr[nt], accV[mt][nt], 0, 0, 0);
    }
  }

#pragma unroll
  for (int mt = 0; mt < 4; mt++) {
#pragma unroll
    for (int nt = 0; nt < 4; nt++) {
#pragma unroll
      for (int r = 0; r < 4; r++) {
        const long grow = tm + wm + mt * 16 + quad * 4 + r;
        const long gcol = tn + wn + nt * 16 + lo;
        const float g   = accG[mt][nt][r];
        const float s   = g / (1.f + __expf(-g));
        Cout[grow * (long)FFP + gcol] = f2bf(s * accV[mt][nt][r]);
      }
    }
  }
}

// ---------------- 256^2 GEMM, 16 waves, 4-phase, 4 waves/SIMD ----------------
// C[M,N'] = A[M,K] * B^T (B stored [NB][K]). 1024 threads = 16 waves (4M x 4N),
// per-wave output 64x64 -> acc[4][4] = 64 VGPR, frag peak 48 -> ~127 regs,
// fits 128/wave at 4 waves/SIMD (launch_bounds(1024,4)). BK=64, dbuf 128 KiB
// LDS (1 block/CU, 16 waves = 50% occ). Round-5 proven schedule & swizzle:
// chunk c of row r stored at c^(r&7) (measured 0 bank conflicts).
// Quadrants: Q0 aL*b01, Q1 aL*b23, Q2 aH*b23, Q3 aH*b01 (adjacent share an
// operand; b01 held tile-long = 16 regs).
//   P0: read aL[4]+b01[4]; MFMA Q0; read b23[4] (consumed P1); bar
//   P1: MFMA Q1 (regs only); bar
//   P2: stage B(t+2)->cb (B[cb] reads all drained pre-P1-bar); read aH[4];
//       MFMA Q2; bar
//   P3: stage A(t+2)->cb (A[cb] reads drained pre-P2-bar); MFMA Q3;
//       vmcnt(4|0); bar
// Staging: per wave 2 gloads/matrix/tile (rows w*16..w*16+15). vmcnt ledger at
// P3(t)-end (oldest->newest): B(t+1)@P2(t-1), A(t+1)@P3(t-1), B(t+2)@P2(t),
// A(t+2)@P3(t); vmcnt(4) keeps the newest 4 -> tile t+1 fully resident before
// P0(t+1), published by the barrier. Prologue: B(0),A(0),B(1),A(1); vmcnt(4);
// bar. Tails: t=NT-2 no stages vmcnt(0); t=NT-1 none. NT even >= 4.
// Spill check (round-3/6/7 lesson): VGPR_Count must be ~128 (NOT 64) and
// WRITE_SIZE ~90112 KB.
// EPI 0: FF fused, B rows interleaved gate/value at 16-col granularity
//   (row R: tile=R>>8, pair=(R&255)>>5, sel=(R>>4)&1, col=tile*128+pair*16+(R&15));
//   epilogue: ffin[row][col] = silu(accG)*accV, lane-local (n even=gate, odd=val).
// EPI 1: out(raw flag) = acc + bf16 res.
template <int EPI>
__launch_bounds__(1024, 4)
__global__ void gemm256(const unsigned short* __restrict__ A,
                        const unsigned short* __restrict__ Bm,
                        int K,
                        void* __restrict__ Cout,
                        const unsigned short* __restrict__ res,
                        long outOff,
                        const int* __restrict__ flagp) {
  __shared__ __align__(16) unsigned short As[2][256][64];
  __shared__ __align__(16) unsigned short Bs[2][256][64];

  const int tid  = threadIdx.x;
  const int w    = tid >> 6;      // 0..15
  const int lane = tid & 63;
  const int wr   = w >> 2;        // 0..3  (M band of 64)
  const int wc   = w & 3;         // 0..3  (N band of 64)
  const int quad = lane >> 4;
  const int lo   = lane & 15;
  const int sw   = lo & 7;

  // bijective XCD-aware block swizzle (m204 formula)
  const int gx  = gridDim.x;
  int bid       = blockIdx.y * gx + blockIdx.x;
  const int nwg = gx * gridDim.y;
  {
    const int q = nwg >> 3, r8 = nwg & 7;
    const int xc8 = bid & 7, j = bid >> 3;
    bid = (xc8 < r8 ? xc8 * (q + 1) : r8 * (q + 1) + (xc8 - r8) * q) + j;
  }
  const long tn = (long)(bid % gx) * 256;  // B-row tile base
  const long tm = (long)(bid / gx) * 256;  // M tile base

  const int NT = K >> 6;  // even, >= 4 by construction

  // staging source addressing: per-lane swizzled global address, linear LDS.
  // Each wave covers rows w*16..w*16+15 (2 gloads of 8 rows each).
  const int srow = lane >> 3;                 // 0..7
  const int sch  = (lane & 7) ^ srow;         // source chunk = pos ^ key(row)
  const unsigned short* Ab = A + (tm + (long)w * 16 + srow) * (long)K + sch * 8;
  const unsigned short* Bb = Bm + (tn + (long)w * 16 + srow) * (long)K + sch * 8;

#define STAGE_A(BUF, TT)                                                          \
  gload_lds16(Ab + (long)(TT) * 64, &As[BUF][w * 16][0]);                         \
  gload_lds16(Ab + 8L * K + (long)(TT) * 64, &As[BUF][w * 16 + 8][0]);
#define STAGE_B(BUF, TT)                                                          \
  gload_lds16(Bb + (long)(TT) * 64, &Bs[BUF][w * 16][0]);                         \
  gload_lds16(Bb + 8L * K + (long)(TT) * 64, &Bs[BUF][w * 16 + 8][0]);

  // prologue (steady-state age order per tile: B then A)
  STAGE_B(0, 0)
  STAGE_A(0, 0)
  STAGE_B(1, 1)
  STAGE_A(1, 1)

  f32x4 acc[4][4];
#pragma unroll
  for (int i = 0; i < 4; i++)
#pragma unroll
    for (int j = 0; j < 4; j++) acc[i][j] = (f32x4){0.f, 0.f, 0.f, 0.f};

  // tile0 landed for every wave (tile1's 4 remain in flight)
  asm volatile("s_waitcnt vmcnt(4)" ::: "memory");
  __builtin_amdgcn_s_barrier();

  bf16x8 aL[2][2], aH[2][2], b01[2][2], b23[2][2];

#define LDAL(CBUF)                                                                \
  _Pragma("unroll") for (int m = 0; m < 2; m++) {                                 \
    _Pragma("unroll") for (int c = 0; c < 2; c++) {                               \
      aL[m][c] = *(const bf16x8*)&As[CBUF][wr * 64 + m * 16 + lo]                 \
                                        [((quad + 4 * c) ^ sw) * 8];              \
    }                                                                             \
  }
#define LDAH(CBUF)                                                                \
  _Pragma("unroll") for (int m = 0; m < 2; m++) {                                 \
    _Pragma("unroll") for (int c = 0; c < 2; c++) {                               \
      aH[m][c] = *(const bf16x8*)&As[CBUF][wr * 64 + 32 + m * 16 + lo]            \
                                        [((quad + 4 * c) ^ sw) * 8];              \
    }                                                                             \
  }
#define LDB01(CBUF)                                                               \
  _Pragma("unroll") for (int n = 0; n < 2; n++) {                                 \
    _Pragma("unroll") for (int c = 0; c < 2; c++) {                               \
      b01[n][c] = *(const bf16x8*)&Bs[CBUF][wc * 64 + n * 16 + lo]                \
                                         [((quad + 4 * c) ^ sw) * 8];             \
    }                                                                             \
  }
#define LDB23(CBUF)                                                               \
  _Pragma("unroll") for (int n = 0; n < 2; n++) {                                 \
    _Pragma("unroll") for (int c = 0; c < 2; c++) {                               \
      b23[n][c] = *(const bf16x8*)&Bs[CBUF][wc * 64 + 32 + n * 16 + lo]           \
                                         [((quad + 4 * c) ^ sw) * 8];             \
    }                                                                             \
  }
#define MFMA_Q(MB, AF, NB, BF)                                                    \
  __builtin_amdgcn_s_setprio(1);                                                  \
  _Pragma("unroll") for (int m = 0; m < 2; m++) {                                 \
    _Pragma("unroll") for (int n = 0; n < 2; n++) {                               \
      _Pragma("unroll") for (int c = 0; c < 2; c++) {                             \
        acc[(MB) + m][(NB) + n] = __builtin_amdgcn_mfma_f32_16x16x32_bf16(        \
            AF[m][c], BF[n][c], acc[(MB) + m][(NB) + n], 0, 0, 0);                \
      }                                                                           \
    }                                                                             \
  }                                                                               \
  __builtin_amdgcn_s_setprio(0);

// One sub-tile. STG: stage tile TT+2 into CBUF; VM: 4 steady / 0 tail / -1 none.
#define SUBTILE(CBUF, TT, STG, VM)                                                \
  {                                                                               \
    /* P0: in-phase reads (tile published at prev P3); MFMA Q0; prefetch b23 */  \
    LDAL(CBUF);                                                                   \
    LDB01(CBUF);                                                                  \
    MFMA_Q(0, aL, 0, b01);                                                        \
    LDB23(CBUF);                                                                  \
    __builtin_amdgcn_s_barrier();                                                 \
    /* P1: MFMA Q1 — all operands in registers */                                 \
    MFMA_Q(0, aL, 2, b23);                                                        \
    __builtin_amdgcn_s_barrier();                                                 \
    /* P2: stage B(TT+2) (B[CBUF] reads drained pre-P1-bar); read aH; Q2 */      \
    if (STG) { STAGE_B(CBUF, (TT) + 2) }                                          \
    LDAH(CBUF);                                                                   \
    MFMA_Q(2, aH, 2, b23);                                                        \
    __builtin_amdgcn_s_barrier();                                                 \
    /* P3: stage A(TT+2) (A[CBUF] reads drained pre-P2-bar); Q3; publish */      \
    if (STG) { STAGE_A(CBUF, (TT) + 2) }                                          \
    MFMA_Q(2, aH, 0, b01);                                                        \
    if ((VM) == 4) asm volatile("s_waitcnt vmcnt(4)" ::: "memory");               \
    else if ((VM) == 0) asm volatile("s_waitcnt vmcnt(0)" ::: "memory");          \
    __builtin_amdgcn_s_barrier();                                                 \
  }

  // main loop: subtiles 0..NT-3 (stage targets TT+2 <= NT-1 all valid)
  for (int t = 0; t + 3 < NT; t += 2) {
    SUBTILE(0, t, 1, 4)
    SUBTILE(1, t + 1, 1, 4)
  }
  // tails: NT-2 (no stages; drain everything), NT-1 (no stages/wait)
  SUBTILE(0, NT - 2, 0, 0)
  SUBTILE(1, NT - 1, 0, -1)

  if (EPI == 0) {
    // silu(gate) * value, lane-local pairing; ffin col base = tn/2
    const long colb = (tn >> 1);
    const long rowb = tm + wr * 64;
#pragma unroll
    for (int m = 0; m < 4; m++) {
#pragma unroll
      for (int np = 0; np < 2; np++) {
        const long col = colb + (wc * 2 + np) * 16 + lo;
#pragma unroll
        for (int r = 0; r < 4; r++) {
          const long row = rowb + m * 16 + quad * 4 + r;
          const float g  = acc[m][2 * np][r];
          const float v  = acc[m][2 * np + 1][r];
          const float s  = g / (1.f + __expf(-g));
          ((unsigned short*)Cout)[row * (long)FFP + col] = f2bf(s * v);
        }
      }
    }
  } else {
    const int f32m = *flagp;
    const long rowb = tm + wr * 64;
    const long colb = tn + wc * 64;
#pragma unroll
    for (int m = 0; m < 4; m++) {
#pragma unroll
      for (int n = 0; n < 4; n++) {
#pragma unroll
        for (int r = 0; r < 4; r++) {
          const long row = rowb + m * 16 + quad * 4 + r;
          const long col = colb + n * 16 + lo;
          float v = acc[m][n][r] + bf2f(res[row * (long)DM + col]);
          stout(Cout, outOff + row * (long)DM + col, f32m, v);
        }
      }
    }
  }
#undef STAGE_A
#undef STAGE_B
#undef LDAL
#undef LDAH
#undef LDB01
#undef LDB23
#undef MFMA_Q
#undef SUBTILE
}

// ---------------- RMSNorm: raw input variant (flag) --------------------------
__global__ void rmsnorm_x(const void* __restrict__ in, long elemOff,
                          const unsigned short* __restrict__ gamma,
                          unsigned short* __restrict__ out,
                          const int* __restrict__ flagp) {
  const int t    = blockIdx.x;
  const int lane = threadIdx.x;
  const int f32m = *flagp;
  float v[16];
  const long base = elemOff + (long)t * DM;
  if (f32m) {
    const float4* rp = (const float4*)((const float*)in + base);
#pragma unroll
    for (int j = 0; j < 4; j++) {
      float4 u     = rp[j * 64 + lane];
      v[j * 4 + 0] = u.x; v[j * 4 + 1] = u.y; v[j * 4 + 2] = u.z; v[j * 4 + 3] = u.w;
    }
  } else {
    const ushort4* rp = (const ushort4*)((const unsigned short*)in + base);
#pragma unroll
    for (int j = 0; j < 4; j++) {
      ushort4 u    = rp[j * 64 + lane];
      v[j * 4 + 0] = bf2f(u.x); v[j * 4 + 1] = bf2f(u.y);
      v[j * 4 + 2] = bf2f(u.z); v[j * 4 + 3] = bf2f(u.w);
    }
  }
  float s = 0.f;
#pragma unroll
  for (int i = 0; i < 16; i++) s = fmaf(v[i], v[i], s);
#pragma unroll
  for (int off = 32; off > 0; off >>= 1) s += __shfl_xor(s, off, 64);
  const float scale = 32.f / fmaxf(sqrtf(s), 1e-12f);
  ushort4* op       = (ushort4*)(out + (long)t * DM);
  const ushort4* gp = (const ushort4*)gamma;
#pragma unroll
  for (int j = 0; j < 4; j++) {
    ushort4 g = gp[j * 64 + lane];
    ushort4 o;
    o.x = f2bf(v[j * 4 + 0] * scale * (bf2f(g.x) + 1.f));
    o.y = f2bf(v[j * 4 + 1] * scale * (bf2f(g.y) + 1.f));
    o.z = f2bf(v[j * 4 + 2] * scale * (bf2f(g.z) + 1.f));
    o.w = f2bf(v[j * 4 + 3] * scale * (bf2f(g.w) + 1.f));
    op[j * 64 + lane] = o;
  }
}

// ---------------- RMSNorm (bf16 in/out) --------------------------------------
__global__ void rmsnorm_k(const unsigned short* __restrict__ in,
                          const unsigned short* __restrict__ gamma,
                          unsigned short* __restrict__ out) {
  const int t    = blockIdx.x;
  const int lane = threadIdx.x;
  float v[16];
  const ushort4* rp = (const ushort4*)(in + (long)t * DM);
#pragma unroll
  for (int j = 0; j < 4; j++) {
    ushort4 u    = rp[j * 64 + lane];
    v[j * 4 + 0] = bf2f(u.x); v[j * 4 + 1] = bf2f(u.y);
    v[j * 4 + 2] = bf2f(u.z); v[j * 4 + 3] = bf2f(u.w);
  }
  float s = 0.f;
#pragma unroll
  for (int i = 0; i < 16; i++) s = fmaf(v[i], v[i], s);
#pragma unroll
  for (int off = 32; off > 0; off >>= 1) s += __shfl_xor(s, off, 64);
  const float scale = 32.f / fmaxf(sqrtf(s), 1e-12f);
  ushort4* op       = (ushort4*)(out + (long)t * DM);
  const ushort4* gp = (const ushort4*)gamma;
#pragma unroll
  for (int j = 0; j < 4; j++) {
    ushort4 g = gp[j * 64 + lane];
    ushort4 o;
    o.x = f2bf(v[j * 4 + 0] * scale * (bf2f(g.x) + 1.f));
    o.y = f2bf(v[j * 4 + 1] * scale * (bf2f(g.y) + 1.f));
    o.z = f2bf(v[j * 4 + 2] * scale * (bf2f(g.z) + 1.f));
    o.w = f2bf(v[j * 4 + 3] * scale * (bf2f(g.w) + 1.f));
    op[j * 64 + lane] = o;
  }
}

// ---------------- causal depthwise conv K=4 ----------------------------------
__global__ void dwconv_k(const unsigned short* __restrict__ xn,
                         const unsigned short* __restrict__ dww,
                         const unsigned short* __restrict__ dwb,
                         unsigned short* __restrict__ y, int l0) {
  const int t = blockIdx.x;
  const int d = blockIdx.y * 256 + threadIdx.x;
  const int l = l0 + (t & (SEQL - 1));
  ushort4 w4  = ((const ushort4*)dww)[d];
  float wk[4] = {bf2f(w4.x), bf2f(w4.y), bf2f(w4.z), bf2f(w4.w)};
  float acc   = bf2f(dwb[d]);
#pragma unroll
  for (int k = 0; k < 4; k++) {
    const int ll = l + k - 3;
    if (ll >= 0) acc = fmaf(bf2f(xn[(long)(t + k - 3) * DM + d]), wk[k], acc);
  }
  y[(long)t * DM + d] = f2bf(acc);
}

// ---------------- scan --------------------------------------------------------
__device__ __forceinline__ void cv_compute(float gt, float& c, float& sg) {
  gt = fminf(fmaxf(gt, -40.f), 40.f);
  const float e  = __expf(-fabsf(gt));
  const float r  = 1.f / (1.f + e);
  const float rs = e * r;
  c  = (gt >= 0.f) ? rs : r;   // sigmoid(-gt)
  sg = (gt >= 0.f) ? r : rs;   // sigmoid(gt)
}
__device__ __forceinline__ float gfun(float hid) {
  hid = fminf(fmaxf(hid, -40.f), 40.f);
  if (hid >= 0.f) return hid + 0.5f;
  const float e = __expf(hid);
  return e / (1.f + e);
}

__global__ void scan_p1(const unsigned short* __restrict__ hg, float* __restrict__ cC,
                        float* __restrict__ cV, int chTot, int SL) {
  const int e = threadIdx.x, bh = blockIdx.y, cid = blockIdx.x;
  const int bL = bh >> 2, hh = bh & 3;
  long base = ((long)(bL * SL + cid * CHLEN)) * 3072 + hh * 768 + e;
  float C = 1.f, V = 0.f;
  for (int i = 0; i < CHLEN; i++) {
    const float hid = bf2f(hg[base]), gt = bf2f(hg[base + 384]);
    float c, sg; cv_compute(gt, c, sg);
    C *= c;
    V = fmaf(c, V, sg * gfun(hid));
    base += 3072;
  }
  const int idx = cid * chTot + bh * 384 + e;
  cC[idx] = C; cV[idx] = V;
}

__global__ void scan_p2(const float* __restrict__ cC, const float* __restrict__ cV,
                        float* __restrict__ hin, int chTot, int CHNp,
                        const float* __restrict__ hcarry, int useCarry) {
  const int ch = blockIdx.x * 384 + threadIdx.x;
  float h = useCarry ? hcarry[ch] : 0.f;
  for (int cid = 0; cid < CHNp; cid++) {
    const int idx = cid * chTot + ch;
    hin[idx] = h;
    h = fmaf(cC[idx], h, cV[idx]);
  }
}

__global__ void scan_p3(const unsigned short* __restrict__ hg, const float* __restrict__ hin,
                        unsigned short* __restrict__ hout, void* __restrict__ nh, long nhOff,
                        float* __restrict__ hcarry, int chTot, int SL, int CHNp,
                        int writeNh, const int* __restrict__ flagp) {
  const int e = threadIdx.x, bh = blockIdx.y, cid = blockIdx.x;
  const int bL = bh >> 2, hh = bh & 3;
  const long tok = (long)bL * SL + (long)cid * CHLEN;
  long base  = tok * 3072 + hh * 768 + e;
  long obase = tok * 1536 + hh * 384 + e;
  float h = hin[cid * chTot + bh * 384 + e];
  for (int i = 0; i < CHLEN; i++) {
    const float hid = bf2f(hg[base]), gt = bf2f(hg[base + 384]);
    float c, sg; cv_compute(gt, c, sg);
    h = fmaf(c, h, sg * gfun(hid));
    hout[obase] = f2bf(h);
    base += 3072; obase += 1536;
  }
  if (cid == CHNp - 1) {
    hcarry[bh * 384 + e] = h;
    if (writeNh) stout(nh, nhOff + bL * 1536 + hh * 384 + e, *flagp, h);
  }
}

// ---------------- weight conversion / transposes (flag-branching reads) -------
__global__ void cvt_k(const void* __restrict__ in, unsigned short* __restrict__ out,
                      int n, const int* __restrict__ flagp) {
  const int i = blockIdx.x * 256 + threadIdx.x;
  if (i < n) out[i] = f2bf(ldin(in, i, *flagp));
}
__global__ void tr_whg(const void* __restrict__ in, unsigned short* __restrict__ out,
                       const int* __restrict__ flagp) {
  const int idx = blockIdx.x * 256 + threadIdx.x;  // (h*768+n)*256+k
  const int k = idx & 255, n = (idx >> 8) % 768, h = idx / (768 * 256);
  out[idx] = f2bf(ldin(in, (long)(h * 256 + k) * 768 + n, *flagp));
}
__global__ void tr_wout(const void* __restrict__ in, unsigned short* __restrict__ out,
                        const int* __restrict__ flagp) {
  const int idx = blockIdx.x * 256 + threadIdx.x;  // (h*256+n)*384+k
  const int k = idx % 384, n = (idx / 384) & 255, h = idx / (384 * 256);
  out[idx] = f2bf(ldin(in, (long)(h * 384 + k) * 256 + n, *flagp));
}
__global__ void tr_wg(const void* __restrict__ in, unsigned short* __restrict__ out,
                      const int* __restrict__ flagp) {
  const int idx = blockIdx.x * 256 + threadIdx.x;  // n*1024+k, n<2816
  const int k = idx & 1023, n = idx >> 10;
  out[idx] = (n < FFN) ? f2bf(ldin(in, (long)k * FFN + n, *flagp)) : (unsigned short)0;
}
// interleaved gate/value: B row R -> tile=R>>8, pair=(R&255)>>5, sel=(R>>4)&1,
// col = tile*128 + pair*16 + (R&15); out[R][k] = W_{sel}[k][col] (0 if col>=FFN)
__global__ void tr_wgv(const void* __restrict__ wg, const void* __restrict__ wv,
                       unsigned short* __restrict__ out, const int* __restrict__ flagp) {
  const int idx = blockIdx.x * 256 + threadIdx.x;  // R*1024+k, R<5632
  const int k = idx & 1023, R = idx >> 10;
  const int tile = R >> 8, rb = R & 255;
  const int pair = rb >> 5, sel = (rb >> 4) & 1, r16 = rb & 15;
  const int col  = tile * 128 + pair * 16 + r16;
  const void* src = sel ? wv : wg;
  out[idx] = (col < FFN) ? f2bf(ldin(src, (long)k * FFN + col, *flagp)) : (unsigned short)0;
}
__global__ void tr_wfo(const void* __restrict__ in, unsigned short* __restrict__ out,
                       const int* __restrict__ flagp) {
  const int idx = blockIdx.x * 256 + threadIdx.x;  // n*2816+kk
  const int kk = idx % FFP, n = idx / FFP;
  out[idx] = (kk < FFN) ? f2bf(ldin(in, (long)kk * DM + n, *flagp)) : (unsigned short)0;
}

// ---------------- launch ------------------------------------------------------
extern "C" void kernel_launch(void* const* d_in, const int* in_sizes, int n_in,
                              void* d_out, int out_size, void* d_ws, size_t ws_size,
                              hipStream_t stream) {
  const void* x      = d_in[0];
  const void* dw_w   = d_in[1];
  const void* dw_b   = d_in[2];
  const void* pw_w   = d_in[3];  // [N=1024][K=1024] already
  const void* pw_b   = d_in[4];
  const void* conv_g = d_in[5];
  const void* gru_g  = d_in[6];
  const void* ff_g   = d_in[7];
  const void* w_hg   = d_in[8];
  const void* w_out  = d_in[9];
  const void* w_gate = d_in[10];
  const void* w_val  = d_in[11];
  const void* w_ffo  = d_in[12];

  // Pass size from ws_size (deterministic): need(MT) = 21,795,072 + MT*13,888.
  const long FIXED = 21795072L;
  int MT = 128;
  if      (ws_size >= (size_t)(FIXED + 16384L * 13888)) MT = 16384;
  else if (ws_size >= (size_t)(FIXED + 8192L * 13888))  MT = 8192;
  else if (ws_size >= (size_t)(FIXED + 4096L * 13888))  MT = 4096;
  else if (ws_size >= (size_t)(FIXED + 2048L * 13888))  MT = 2048;
  else if (ws_size >= (size_t)(FIXED + 1024L * 13888))  MT = 1024;
  else if (ws_size >= (size_t)(FIXED + 512L * 13888))   MT = 512;
  else if (ws_size >= (size_t)(FIXED + 256L * 13888))   MT = 256;

  const int SL    = (MT >= SEQL) ? SEQL : MT;
  const int nSeq  = MT / SL;
  const int CHNp  = SL / CHLEN;
  const int chTot = nSeq * 1536;
  const int big   = (MT >= 256);  // 256^2 16-wave path for the two FF GEMMs

  char* p = (char*)d_ws;
  unsigned short* whgT  = (unsigned short*)p; p += 1572864;
  unsigned short* woutT = (unsigned short*)p; p += 786432;
  unsigned short* wgT   = (unsigned short*)p; p += 5767168;
  unsigned short* wvT   = (unsigned short*)p; p += 5767168;
  unsigned short* wfoT  = (unsigned short*)p; p += 5767168;
  unsigned short* pwT   = (unsigned short*)p; p += 2097152;
  unsigned short* dwwB  = (unsigned short*)p; p += 8192;
  unsigned short* dwbB  = (unsigned short*)p; p += 2048;
  unsigned short* pwbB  = (unsigned short*)p; p += 2048;
  unsigned short* cgB   = (unsigned short*)p; p += 2048;
  unsigned short* ggB   = (unsigned short*)p; p += 2048;
  unsigned short* fgB   = (unsigned short*)p; p += 2048;
  int*            flag  = (int*)p;            p += 256;
  float*          hcarry= (float*)p;          p += 12288;
  float*          cC    = (float*)p;          p += (long)MT * 192;
  float*          cV    = (float*)p;          p += (long)MT * 192;
  float*          hin   = (float*)p;          p += (long)MT * 192;
  unsigned short* xnb   = (unsigned short*)p; p += 6144 + (long)MT * 2048;
  unsigned short* xc    = (unsigned short*)p; p += (long)MT * 2048;
  unsigned short* hbuf  = (unsigned short*)p; p += (long)MT * 3072;
  unsigned short* ybuf  = (unsigned short*)p;  // region R: ybuf / hg / ffin
  unsigned short* hg    = (unsigned short*)p;
  unsigned short* ffin  = (unsigned short*)p;
  unsigned short* xn    = xnb + 3 * DM;
  unsigned short* wgvT  = wgT;  // interleaved [5632][1024] spans wgT+wvT slots

  // dtype detection + weight conversion (once per call)
  detect_k<<<1, 256, 0, stream>>>((const unsigned short*)x, flag);
  tr_whg<<<3072, 256, 0, stream>>>(w_hg, whgT, flag);
  tr_wout<<<1536, 256, 0, stream>>>(w_out, woutT, flag);
  if (big) {
    tr_wgv<<<22528, 256, 0, stream>>>(w_gate, w_val, wgvT, flag);
  } else {
    tr_wg<<<11264, 256, 0, stream>>>(w_gate, wgT, flag);
    tr_wg<<<11264, 256, 0, stream>>>(w_val, wvT, flag);
  }
  tr_wfo<<<11264, 256, 0, stream>>>(w_ffo, wfoT, flag);
  cvt_k<<<4096, 256, 0, stream>>>(pw_w, pwT, 1048576, flag);
  cvt_k<<<16, 256, 0, stream>>>(dw_w, dwwB, 4096, flag);
  cvt_k<<<4, 256, 0, stream>>>(dw_b, dwbB, 1024, flag);
  cvt_k<<<4, 256, 0, stream>>>(pw_b, pwbB, 1024, flag);
  cvt_k<<<4, 256, 0, stream>>>(conv_g, cgB, 1024, flag);
  cvt_k<<<4, 256, 0, stream>>>(gru_g, ggB, 1024, flag);
  cvt_k<<<4, 256, 0, stream>>>(ff_g, fgB, 1024, flag);

  for (long t0 = 0; t0 < 16384; t0 += MT) {
    const int l0     = (int)(t0 & (SEQL - 1));
    const int P      = (l0 > 0) ? 3 : 0;
    const int seqEnd = (l0 + SL == SEQL);
    const long nhOff = NH_OFF + (t0 / SEQL) * 1536;

    // conv block: xc = pw(dwconv(rmsnorm(x))) + pw_b + x
    rmsnorm_x<<<MT + P, 64, 0, stream>>>(x, (t0 - P) * DM, cgB, xn - (long)P * DM, flag);
    dwconv_k<<<dim3(MT, 4), 256, 0, stream>>>(xn, dwwB, dwbB, ybuf, l0);
    gemm_bf16<1><<<dim3(8, MT / 128, 1), 256, 0, stream>>>(ybuf, DM, 0, pwT, 0, DM,
        xc, DM, 0, 0L, pwbB, x, DM, t0 * DM, flag);

    // GRU block
    rmsnorm_k<<<MT, 64, 0, stream>>>(xc, ggB, xn);
    gemm_bf16<0><<<dim3(6, MT / 128, 4), 256, 0, stream>>>(xn, DM, 256, whgT, 196608, 256,
        hg, 3072, 768, 0L, nullptr, nullptr, 0, 0L, nullptr);
    scan_p1<<<dim3(CHNp, nSeq * 4), 384, 0, stream>>>(hg, cC, cV, chTot, SL);
    scan_p2<<<nSeq * 4, 384, 0, stream>>>(cC, cV, hin, chTot, CHNp, hcarry, l0 > 0);
    scan_p3<<<dim3(CHNp, nSeq * 4), 384, 0, stream>>>(hg, hin, hbuf, d_out, nhOff,
        hcarry, chTot, SL, CHNp, seqEnd, flag);
    gemm_bf16<2><<<dim3(2, MT / 128, 4), 256, 0, stream>>>(hbuf, 1536, 384, woutT, 98304, 384,
        xc, DM, 256, 0L, nullptr, xc, DM, 0L, nullptr);

    // FF block
    rmsnorm_k<<<MT, 64, 0, stream>>>(xc, fgB, xn);
    if (big) {
      gemm256<0><<<dim3(22, MT / 256), 1024, 0, stream>>>(xn, wgvT, DM,
          ffin, nullptr, 0L, nullptr);
      gemm256<1><<<dim3(4, MT / 256), 1024, 0, stream>>>(ffin, wfoT, FFP,
          d_out, xc, t0 * DM, flag);
    } else {
      gemm_ff<<<dim3(22, MT / 128), 256, 0, stream>>>(xn, wgT, wvT, ffin);
      gemm_bf16<3><<<dim3(8, MT / 128, 1), 256, 0, stream>>>(ffin, FFP, 0, wfoT, 0, FFP,
          d_out, DM, 0, t0 * DM, nullptr, xc, DM, 0L, flag);
    }
  }
}

// Round 9
// 958.766 us; speedup vs baseline: 3.8878x; 1.5071x over previous
//
#include <hip/hip_runtime.h>
#include <stdint.h>

// MinGRUBlock on MI355X (gfx950). Input/output dtype (f32 vs bf16) DETECTED at
// runtime from x's bit patterns (flag in ws). Internals bf16. Residual in ws.
// Small GEMMs: mfma_f32_16x16x32_bf16, 128x128 tile, BK=64, global_load_lds
// w=16, XOR-swizzled LDS (chunk c of row r at c^(r&7)).
// Big GEMMs (FF gate/value and FF out): 256x256 tile, 16 waves (1024 thr,
// 4 waves/SIMD), per-wave 64x64 -> acc 64 AGPR; ONE a-bank + ONE b-bank
// (32 VGPR frag peak, round-8 lesson: 48-peak + 64 acc left zero headroom at
// the 128-reg budget -> spill). Quadrants Q0 aL*b01, Q1 aL*b23, Q2 aH*b23,
// Q3 aH*b01' (b01 re-read at P3; +4 ds_reads/tile buys 16 regs). Staging:
// during tile t, stage tile t+1 into buf^1 (dead since tile t-1's end bar);
// publish vmcnt(0)+bar at P3-end (~3-phase latency cover). BK=64, dbuf
// 128 KiB LDS, proven zero-conflict chunk-XOR swizzle.
// W_gate/W_value interleaved at 16-col granularity (lane-local silu-combine).
// Scan: 3-phase chunked, h_t = sigmoid(-g)*h + sigmoid(g)*gfun(hid), f32 carry.

#define DM     1024
#define SEQL   4096
#define FFN    2730
#define FFP    2816
#define NH_OFF 16777216L
#define CHLEN  128

using bf16x8 = __attribute__((ext_vector_type(8))) short;
using f32x4  = __attribute__((ext_vector_type(4))) float;

__device__ __forceinline__ float bf2f(unsigned short h) {
  union { unsigned int u; float f; } v; v.u = ((unsigned int)h) << 16; return v.f;
}
__device__ __forceinline__ unsigned short f2bf(float f) {
  union { float f; unsigned int u; } v; v.f = f;
  unsigned int u = v.u;
  return (unsigned short)((u + 0x7fffu + ((u >> 16) & 1u)) >> 16);
}
__device__ __forceinline__ float ldin(const void* p, long i, int f32mode) {
  return f32mode ? ((const float*)p)[i] : bf2f(((const unsigned short*)p)[i]);
}
__device__ __forceinline__ void stout(void* p, long i, int f32mode, float v) {
  if (f32mode) ((float*)p)[i] = v; else ((unsigned short*)p)[i] = f2bf(v);
}
__device__ __forceinline__ void gload_lds16(const unsigned short* g, unsigned short* lds) {
  __builtin_amdgcn_global_load_lds(
      (const __attribute__((address_space(1))) unsigned int*)g,
      (__attribute__((address_space(3))) unsigned int*)lds,
      16, 0, 0);
}

// ---------------- dtype detection --------------------------------------------
__global__ void detect_k(const unsigned short* __restrict__ x, int* __restrict__ flag) {
  __shared__ int cnt;
  if (threadIdx.x == 0) cnt = 0;
  __syncthreads();
  int c = 0;
  for (int j = 0; j < 4; j++) {
    unsigned short v = x[2 * (threadIdx.x * 4 + j)];
    int ex = (v >> 7) & 0xFF;
    if (ex >= 0x84) c++;
  }
  atomicAdd(&cnt, c);
  __syncthreads();
  if (threadIdx.x == 0) *flag = (cnt >= 32) ? 1 : 0;
}

// ---------------- GEMM: C[M,N] = A[M,K] * B^T  (B stored [N][K], ldb=K) -------
// EPI 0: bf16 plain. EPI 1: bf16 = acc + bias[col] + raw_res (flag).
// EPI 2: bf16 = acc + bf16res. EPI 3: raw_out (flag) = acc + bf16res.
template <int EPI>
__launch_bounds__(256)
__global__ void gemm_bf16(const unsigned short* __restrict__ A, int lda, int aOffZ,
                          const unsigned short* __restrict__ Bm, int bOffZ, int K,
                          void* __restrict__ Cout, int ldc, int cOffZ, long outOff,
                          const unsigned short* __restrict__ bias,
                          const void* __restrict__ res, int ldres, long resOff,
                          const int* __restrict__ flagp) {
  __shared__ __align__(16) unsigned short As[128][64];
  __shared__ __align__(16) unsigned short Bs[128][64];

  const int tid  = threadIdx.x;
  const int w    = tid >> 6;
  const int lane = tid & 63;
  const int z    = blockIdx.z;
  const long tm  = (long)blockIdx.y * 128;
  const long tn  = (long)blockIdx.x * 128;

  const unsigned short* Ag = A + (long)z * aOffZ;
  const unsigned short* Bg = Bm + (long)z * bOffZ;

  f32x4 acc[4][4];
#pragma unroll
  for (int i = 0; i < 4; i++)
#pragma unroll
    for (int j = 0; j < 4; j++) acc[i][j] = (f32x4){0.f, 0.f, 0.f, 0.f};

  const int wrow = w * 32;
  const int srow = lane >> 3;                    // 0..7
  const int scol = (((lane & 7) ^ srow) * 8);    // xor-swizzled source chunk
  const int wm   = (w >> 1) * 64;
  const int wn   = (w & 1) * 64;
  const int quad = lane >> 4;
  const int lo   = lane & 15;
  const int sw   = lo & 7;                       // row-based xor key for reads

  for (int k0 = 0; k0 < K; k0 += 64) {
    __syncthreads();
#pragma unroll
    for (int i = 0; i < 4; i++) {
      const int r = wrow + i * 8;  // wave-uniform LDS base
      gload_lds16(Ag + (tm + r + srow) * (long)lda + k0 + scol, &As[r][0]);
      gload_lds16(Bg + (tn + r + srow) * (long)K + k0 + scol, &Bs[r][0]);
    }
    __syncthreads();
#pragma unroll
    for (int kk = 0; kk < 64; kk += 32) {
      const int kc = kk >> 3;  // 0 or 4
      bf16x8 af[4], bfr[4];
#pragma unroll
      for (int mt = 0; mt < 4; mt++)
        af[mt] = *(const bf16x8*)&As[wm + mt * 16 + lo][((quad + kc) ^ sw) * 8];
#pragma unroll
      for (int nt = 0; nt < 4; nt++)
        bfr[nt] = *(const bf16x8*)&Bs[wn + nt * 16 + lo][((quad + kc) ^ sw) * 8];
#pragma unroll
      for (int mt = 0; mt < 4; mt++)
#pragma unroll
        for (int nt = 0; nt < 4; nt++)
          acc[mt][nt] = __builtin_amdgcn_mfma_f32_16x16x32_bf16(af[mt], bfr[nt], acc[mt][nt], 0, 0, 0);
    }
  }

  const int f32m = (EPI == 1 || EPI == 3) ? *flagp : 0;
#pragma unroll
  for (int mt = 0; mt < 4; mt++) {
#pragma unroll
    for (int nt = 0; nt < 4; nt++) {
#pragma unroll
      for (int r = 0; r < 4; r++) {
        const long grow = tm + wm + mt * 16 + quad * 4 + r;
        const long gcol = tn + wn + nt * 16 + lo;
        float v         = acc[mt][nt][r];
        if (EPI == 0) {
          ((unsigned short*)Cout + (long)z * cOffZ)[grow * (long)ldc + gcol] = f2bf(v);
        } else if (EPI == 1) {
          v += bf2f(bias[gcol]) + ldin(res, resOff + grow * (long)ldres + gcol, f32m);
          ((unsigned short*)Cout)[grow * (long)ldc + gcol] = f2bf(v);
        } else if (EPI == 2) {
          v += bf2f(((const unsigned short*)res + (long)z * cOffZ)[grow * (long)ldres + gcol]);
          ((unsigned short*)Cout + (long)z * cOffZ)[grow * (long)ldc + gcol] = f2bf(v);
        } else {  // EPI == 3: final output
          v += bf2f(((const unsigned short*)res)[grow * (long)ldres + gcol]);
          stout(Cout, outOff + grow * (long)ldc + gcol, f32m, v);
        }
      }
    }
  }
}

// ---------------- fused FF GEMM (legacy 128^2 path, used when MT<256) ---------
__launch_bounds__(256)
__global__ void gemm_ff(const unsigned short* __restrict__ A,
                        const unsigned short* __restrict__ Bgm,
                        const unsigned short* __restrict__ Bvm,
                        unsigned short* __restrict__ Cout) {
  __shared__ __align__(16) unsigned short As[128][64];
  __shared__ __align__(16) unsigned short Bgs[128][64];
  __shared__ __align__(16) unsigned short Bvs[128][64];

  const int tid  = threadIdx.x;
  const int w    = tid >> 6;
  const int lane = tid & 63;
  const long tm  = (long)blockIdx.y * 128;
  const long tn  = (long)blockIdx.x * 128;

  f32x4 accG[4][4], accV[4][4];
#pragma unroll
  for (int i = 0; i < 4; i++)
#pragma unroll
    for (int j = 0; j < 4; j++) {
      accG[i][j] = (f32x4){0.f, 0.f, 0.f, 0.f};
      accV[i][j] = (f32x4){0.f, 0.f, 0.f, 0.f};
    }

  const int wrow = w * 32;
  const int srow = lane >> 3;
  const int scol = (((lane & 7) ^ srow) * 8);
  const int wm   = (w >> 1) * 64;
  const int wn   = (w & 1) * 64;
  const int quad = lane >> 4;
  const int lo   = lane & 15;
  const int sw   = lo & 7;

  for (int k0 = 0; k0 < DM; k0 += 64) {
    __syncthreads();
#pragma unroll
    for (int i = 0; i < 4; i++) {
      const int r = wrow + i * 8;
      gload_lds16(A + (tm + r + srow) * (long)DM + k0 + scol, &As[r][0]);
      gload_lds16(Bgm + (tn + r + srow) * (long)DM + k0 + scol, &Bgs[r][0]);
      gload_lds16(Bvm + (tn + r + srow) * (long)DM + k0 + scol, &Bvs[r][0]);
    }
    __syncthreads();
#pragma unroll
    for (int kk = 0; kk < 64; kk += 32) {
      const int kc = kk >> 3;
      bf16x8 af[4], bfr[4];
#pragma unroll
      for (int mt = 0; mt < 4; mt++)
        af[mt] = *(const bf16x8*)&As[wm + mt * 16 + lo][((quad + kc) ^ sw) * 8];
#pragma unroll
      for (int nt = 0; nt < 4; nt++)
        bfr[nt] = *(const bf16x8*)&Bgs[wn + nt * 16 + lo][((quad + kc) ^ sw) * 8];
#pragma unroll
      for (int mt = 0; mt < 4; mt++)
#pragma unroll
        for (int nt = 0; nt < 4; nt++)
          accG[mt][nt] = __builtin_amdgcn_mfma_f32_16x16x32_bf16(af[mt], bfr[nt], accG[mt][nt], 0, 0, 0);
#pragma unroll
      for (int nt = 0; nt < 4; nt++)
        bfr[nt] = *(const bf16x8*)&Bvs[wn + nt * 16 + lo][((quad + kc) ^ sw) * 8];
#pragma unroll
      for (int mt = 0; mt < 4; mt++)
#pragma unroll
        for (int nt = 0; nt < 4; nt++)
          accV[mt][nt] = __builtin_amdgcn_mfma_f32_16x16x32_bf16(af[mt], bfr[nt], accV[mt][nt], 0, 0, 0);
    }
  }

#pragma unroll
  for (int mt = 0; mt < 4; mt++) {
#pragma unroll
    for (int nt = 0; nt < 4; nt++) {
#pragma unroll
      for (int r = 0; r < 4; r++) {
        const long grow = tm + wm + mt * 16 + quad * 4 + r;
        const long gcol = tn + wn + nt * 16 + lo;
        const float g   = accG[mt][nt][r];
        const float s   = g / (1.f + __expf(-g));
        Cout[grow * (long)FFP + gcol] = f2bf(s * accV[mt][nt][r]);
      }
    }
  }
}

// ---------------- 256^2 GEMM, 16 waves, 4 waves/SIMD, 32-reg frag peak -------
// C[M,N'] = A[M,K] * B^T (B stored [NB][K]). 1024 threads = 16 waves (4M x 4N),
// per-wave output 64x64 -> acc[4][4] = 64 AGPR. ONE a-bank a[2][2] (16 VGPR) +
// ONE b-bank b[2][2] (16 VGPR) -> frag peak 32; total ~114 of the 128/wave
// budget at 4 waves/SIMD (round-8 spilled at ~132; need headroom).
// BK=64, dbuf 128 KiB LDS (1 block/CU, 16 waves = 50% occ). Chunk-XOR swizzle
// (store chunk at pos, source chunk pos^(row&7); reads (quad+4c)^(lo&7)) —
// measured 0 bank conflicts in rounds 1-6.
// Quadrants (a overwritten at P2, b at P1/P3 — compiler orders WAR):
//   P0: read aL(rows 0-31)+b01(cols 0-31); stage B(t+1)->buf^1; MFMA Q0; bar
//   P1: read b23(cols 32-63);              stage A(t+1)->buf^1; MFMA Q1; bar
//   P2: read aH(rows 32-63);                                    MFMA Q2; bar
//   P3: re-read b01;                       MFMA Q3; vmcnt(0);           bar
// Staging targets buf^1 which holds tile t-1, dead since tile t-1's end
// barrier (2+ barriers before the stage issue). Publish: vmcnt(0)+bar at
// P3-end; stage issued @P0/P1 -> ~3-phase (~1800 cyc) latency cover > 900 cyc
// HBM. Prologue: stage tile0->buf0, vmcnt(0), bar. Tail: tile NT-1 no stage /
// no wait. NT even >= 4 (K=1024 -> 16, K=2816 -> 44).
// Spill check: WRITE_SIZE ~90112 KB, no GB-scale scratch (rounds 3/6/7/8).
// EPI 0: FF fused, B rows interleaved gate/value at 16-col granularity
//   (row R: tile=R>>8, pair=(R&255)>>5, sel=(R>>4)&1, col=tile*128+pair*16+(R&15));
//   epilogue: ffin[row][col] = silu(accG)*accV, lane-local (n even=gate, odd=val).
// EPI 1: out(raw flag) = acc + bf16 res.
template <int EPI>
__launch_bounds__(1024, 4)
__global__ void gemm256(const unsigned short* __restrict__ A,
                        const unsigned short* __restrict__ Bm,
                        int K,
                        void* __restrict__ Cout,
                        const unsigned short* __restrict__ res,
                        long outOff,
                        const int* __restrict__ flagp) {
  __shared__ __align__(16) unsigned short As[2][256][64];
  __shared__ __align__(16) unsigned short Bs[2][256][64];

  const int tid  = threadIdx.x;
  const int w    = tid >> 6;      // 0..15
  const int lane = tid & 63;
  const int wr   = w >> 2;        // 0..3  (M band of 64)
  const int wc   = w & 3;         // 0..3  (N band of 64)
  const int quad = lane >> 4;
  const int lo   = lane & 15;
  const int sw   = lo & 7;

  // bijective XCD-aware block swizzle (m204 formula)
  const int gx  = gridDim.x;
  int bid       = blockIdx.y * gx + blockIdx.x;
  const int nwg = gx * gridDim.y;
  {
    const int q = nwg >> 3, r8 = nwg & 7;
    const int xc8 = bid & 7, j = bid >> 3;
    bid = (xc8 < r8 ? xc8 * (q + 1) : r8 * (q + 1) + (xc8 - r8) * q) + j;
  }
  const long tn = (long)(bid % gx) * 256;  // B-row tile base
  const long tm = (long)(bid / gx) * 256;  // M tile base

  const int NT = K >> 6;  // even, >= 4 by construction

  // staging source addressing: per-lane swizzled global address, linear LDS.
  // Each wave covers rows w*16..w*16+15 (2 gloads of 8 rows each).
  const int srow = lane >> 3;                 // 0..7
  const int sch  = (lane & 7) ^ srow;         // source chunk = pos ^ key(row)
  const unsigned short* Ab = A + (tm + (long)w * 16 + srow) * (long)K + sch * 8;
  const unsigned short* Bb = Bm + (tn + (long)w * 16 + srow) * (long)K + sch * 8;

#define STAGE_A(BUF, TT)                                                          \
  gload_lds16(Ab + (long)(TT) * 64, &As[BUF][w * 16][0]);                         \
  gload_lds16(Ab + 8L * K + (long)(TT) * 64, &As[BUF][w * 16 + 8][0]);
#define STAGE_B(BUF, TT)                                                          \
  gload_lds16(Bb + (long)(TT) * 64, &Bs[BUF][w * 16][0]);                         \
  gload_lds16(Bb + 8L * K + (long)(TT) * 64, &Bs[BUF][w * 16 + 8][0]);

  // prologue: tile 0 only (tile 1 staged during tile 0)
  STAGE_B(0, 0)
  STAGE_A(0, 0)

  f32x4 acc[4][4];
#pragma unroll
  for (int i = 0; i < 4; i++)
#pragma unroll
    for (int j = 0; j < 4; j++) acc[i][j] = (f32x4){0.f, 0.f, 0.f, 0.f};

  asm volatile("s_waitcnt vmcnt(0)" ::: "memory");
  __builtin_amdgcn_s_barrier();

  bf16x8 a[2][2], b[2][2];

#define LDA2(CBUF, RB)                                                            \
  _Pragma("unroll") for (int m = 0; m < 2; m++) {                                 \
    _Pragma("unroll") for (int c = 0; c < 2; c++) {                               \
      a[m][c] = *(const bf16x8*)&As[CBUF][wr * 64 + ((RB) + m) * 16 + lo]         \
                                       [((quad + 4 * c) ^ sw) * 8];               \
    }                                                                             \
  }
#define LDB2(CBUF, NB)                                                            \
  _Pragma("unroll") for (int n = 0; n < 2; n++) {                                 \
    _Pragma("unroll") for (int c = 0; c < 2; c++) {                               \
      b[n][c] = *(const bf16x8*)&Bs[CBUF][wc * 64 + ((NB) + n) * 16 + lo]         \
                                       [((quad + 4 * c) ^ sw) * 8];               \
    }                                                                             \
  }
#define MFMA_Q(MB, NB)                                                            \
  __builtin_amdgcn_s_setprio(1);                                                  \
  _Pragma("unroll") for (int m = 0; m < 2; m++) {                                 \
    _Pragma("unroll") for (int n = 0; n < 2; n++) {                               \
      _Pragma("unroll") for (int c = 0; c < 2; c++) {                             \
        acc[(MB) + m][(NB) + n] = __builtin_amdgcn_mfma_f32_16x16x32_bf16(        \
            a[m][c], b[n][c], acc[(MB) + m][(NB) + n], 0, 0, 0);                  \
      }                                                                           \
    }                                                                             \
  }                                                                               \
  __builtin_amdgcn_s_setprio(0);

// One sub-tile. STG: stage tile TT+1 into CBUF^1 (holds dead tile TT-1).
#define SUBTILE(CBUF, TT, STG)                                                    \
  {                                                                               \
    /* P0: aL + b01; stage B(TT+1); MFMA Q0 = mLo x nLo */                        \
    LDA2(CBUF, 0);                                                                \
    LDB2(CBUF, 0);                                                                \
    if (STG) { STAGE_B(CBUF ^ 1, (TT) + 1) }                                      \
    MFMA_Q(0, 0);                                                                 \
    __builtin_amdgcn_s_barrier();                                                 \
    /* P1: b23 (b01 consumed); stage A(TT+1); MFMA Q1 = mLo x nHi */              \
    LDB2(CBUF, 2);                                                                \
    if (STG) { STAGE_A(CBUF ^ 1, (TT) + 1) }                                      \
    MFMA_Q(0, 2);                                                                 \
    __builtin_amdgcn_s_barrier();                                                 \
    /* P2: aH (aL consumed); MFMA Q2 = mHi x nHi */                               \
    LDA2(CBUF, 2);                                                                \
    MFMA_Q(2, 2);                                                                 \
    __builtin_amdgcn_s_barrier();                                                 \
    /* P3: re-read b01; MFMA Q3 = mHi x nLo; publish staged tile */               \
    LDB2(CBUF, 0);                                                                \
    MFMA_Q(2, 0);                                                                 \
    if (STG) asm volatile("s_waitcnt vmcnt(0)" ::: "memory");                     \
    __builtin_amdgcn_s_barrier();                                                 \
  }

  // main loop: tiles 0..NT-2 stage their successor; tile NT-1 stages nothing
  for (int t = 0; t < NT - 2; t += 2) {
    SUBTILE(0, t, 1)
    SUBTILE(1, t + 1, 1)
  }
  SUBTILE(0, NT - 2, 1)
  SUBTILE(1, NT - 1, 0)

  if (EPI == 0) {
    // silu(gate) * value, lane-local pairing; ffin col base = tn/2
    const long colb = (tn >> 1);
    const long rowb = tm + wr * 64;
#pragma unroll
    for (int m = 0; m < 4; m++) {
#pragma unroll
      for (int np = 0; np < 2; np++) {
        const long col = colb + (wc * 2 + np) * 16 + lo;
#pragma unroll
        for (int r = 0; r < 4; r++) {
          const long row = rowb + m * 16 + quad * 4 + r;
          const float g  = acc[m][2 * np][r];
          const float v  = acc[m][2 * np + 1][r];
          const float s  = g / (1.f + __expf(-g));
          ((unsigned short*)Cout)[row * (long)FFP + col] = f2bf(s * v);
        }
      }
    }
  } else {
    const int f32m = *flagp;
    const long rowb = tm + wr * 64;
    const long colb = tn + wc * 64;
#pragma unroll
    for (int m = 0; m < 4; m++) {
#pragma unroll
      for (int n = 0; n < 4; n++) {
#pragma unroll
        for (int r = 0; r < 4; r++) {
          const long row = rowb + m * 16 + quad * 4 + r;
          const long col = colb + n * 16 + lo;
          float v = acc[m][n][r] + bf2f(res[row * (long)DM + col]);
          stout(Cout, outOff + row * (long)DM + col, f32m, v);
        }
      }
    }
  }
#undef STAGE_A
#undef STAGE_B
#undef LDA2
#undef LDB2
#undef MFMA_Q
#undef SUBTILE
}

// ---------------- RMSNorm: raw input variant (flag) --------------------------
__global__ void rmsnorm_x(const void* __restrict__ in, long elemOff,
                          const unsigned short* __restrict__ gamma,
                          unsigned short* __restrict__ out,
                          const int* __restrict__ flagp) {
  const int t    = blockIdx.x;
  const int lane = threadIdx.x;
  const int f32m = *flagp;
  float v[16];
  const long base = elemOff + (long)t * DM;
  if (f32m) {
    const float4* rp = (const float4*)((const float*)in + base);
#pragma unroll
    for (int j = 0; j < 4; j++) {
      float4 u     = rp[j * 64 + lane];
      v[j * 4 + 0] = u.x; v[j * 4 + 1] = u.y; v[j * 4 + 2] = u.z; v[j * 4 + 3] = u.w;
    }
  } else {
    const ushort4* rp = (const ushort4*)((const unsigned short*)in + base);
#pragma unroll
    for (int j = 0; j < 4; j++) {
      ushort4 u    = rp[j * 64 + lane];
      v[j * 4 + 0] = bf2f(u.x); v[j * 4 + 1] = bf2f(u.y);
      v[j * 4 + 2] = bf2f(u.z); v[j * 4 + 3] = bf2f(u.w);
    }
  }
  float s = 0.f;
#pragma unroll
  for (int i = 0; i < 16; i++) s = fmaf(v[i], v[i], s);
#pragma unroll
  for (int off = 32; off > 0; off >>= 1) s += __shfl_xor(s, off, 64);
  const float scale = 32.f / fmaxf(sqrtf(s), 1e-12f);
  ushort4* op       = (ushort4*)(out + (long)t * DM);
  const ushort4* gp = (const ushort4*)gamma;
#pragma unroll
  for (int j = 0; j < 4; j++) {
    ushort4 g = gp[j * 64 + lane];
    ushort4 o;
    o.x = f2bf(v[j * 4 + 0] * scale * (bf2f(g.x) + 1.f));
    o.y = f2bf(v[j * 4 + 1] * scale * (bf2f(g.y) + 1.f));
    o.z = f2bf(v[j * 4 + 2] * scale * (bf2f(g.z) + 1.f));
    o.w = f2bf(v[j * 4 + 3] * scale * (bf2f(g.w) + 1.f));
    op[j * 64 + lane] = o;
  }
}

// ---------------- RMSNorm (bf16 in/out) --------------------------------------
__global__ void rmsnorm_k(const unsigned short* __restrict__ in,
                          const unsigned short* __restrict__ gamma,
                          unsigned short* __restrict__ out) {
  const int t    = blockIdx.x;
  const int lane = threadIdx.x;
  float v[16];
  const ushort4* rp = (const ushort4*)(in + (long)t * DM);
#pragma unroll
  for (int j = 0; j < 4; j++) {
    ushort4 u    = rp[j * 64 + lane];
    v[j * 4 + 0] = bf2f(u.x); v[j * 4 + 1] = bf2f(u.y);
    v[j * 4 + 2] = bf2f(u.z); v[j * 4 + 3] = bf2f(u.w);
  }
  float s = 0.f;
#pragma unroll
  for (int i = 0; i < 16; i++) s = fmaf(v[i], v[i], s);
#pragma unroll
  for (int off = 32; off > 0; off >>= 1) s += __shfl_xor(s, off, 64);
  const float scale = 32.f / fmaxf(sqrtf(s), 1e-12f);
  ushort4* op       = (ushort4*)(out + (long)t * DM);
  const ushort4* gp = (const ushort4*)gamma;
#pragma unroll
  for (int j = 0; j < 4; j++) {
    ushort4 g = gp[j * 64 + lane];
    ushort4 o;
    o.x = f2bf(v[j * 4 + 0] * scale * (bf2f(g.x) + 1.f));
    o.y = f2bf(v[j * 4 + 1] * scale * (bf2f(g.y) + 1.f));
    o.z = f2bf(v[j * 4 + 2] * scale * (bf2f(g.z) + 1.f));
    o.w = f2bf(v[j * 4 + 3] * scale * (bf2f(g.w) + 1.f));
    op[j * 64 + lane] = o;
  }
}

// ---------------- causal depthwise conv K=4 ----------------------------------
__global__ void dwconv_k(const unsigned short* __restrict__ xn,
                         const unsigned short* __restrict__ dww,
                         const unsigned short* __restrict__ dwb,
                         unsigned short* __restrict__ y, int l0) {
  const int t = blockIdx.x;
  const int d = blockIdx.y * 256 + threadIdx.x;
  const int l = l0 + (t & (SEQL - 1));
  ushort4 w4  = ((const ushort4*)dww)[d];
  float wk[4] = {bf2f(w4.x), bf2f(w4.y), bf2f(w4.z), bf2f(w4.w)};
  float acc   = bf2f(dwb[d]);
#pragma unroll
  for (int k = 0; k < 4; k++) {
    const int ll = l + k - 3;
    if (ll >= 0) acc = fmaf(bf2f(xn[(long)(t + k - 3) * DM + d]), wk[k], acc);
  }
  y[(long)t * DM + d] = f2bf(acc);
}

// ---------------- scan --------------------------------------------------------
__device__ __forceinline__ void cv_compute(float gt, float& c, float& sg) {
  gt = fminf(fmaxf(gt, -40.f), 40.f);
  const float e  = __expf(-fabsf(gt));
  const float r  = 1.f / (1.f + e);
  const float rs = e * r;
  c  = (gt >= 0.f) ? rs : r;   // sigmoid(-gt)
  sg = (gt >= 0.f) ? r : rs;   // sigmoid(gt)
}
__device__ __forceinline__ float gfun(float hid) {
  hid = fminf(fmaxf(hid, -40.f), 40.f);
  if (hid >= 0.f) return hid + 0.5f;
  const float e = __expf(hid);
  return e / (1.f + e);
}

__global__ void scan_p1(const unsigned short* __restrict__ hg, float* __restrict__ cC,
                        float* __restrict__ cV, int chTot, int SL) {
  const int e = threadIdx.x, bh = blockIdx.y, cid = blockIdx.x;
  const int bL = bh >> 2, hh = bh & 3;
  long base = ((long)(bL * SL + cid * CHLEN)) * 3072 + hh * 768 + e;
  float C = 1.f, V = 0.f;
  for (int i = 0; i < CHLEN; i++) {
    const float hid = bf2f(hg[base]), gt = bf2f(hg[base + 384]);
    float c, sg; cv_compute(gt, c, sg);
    C *= c;
    V = fmaf(c, V, sg * gfun(hid));
    base += 3072;
  }
  const int idx = cid * chTot + bh * 384 + e;
  cC[idx] = C; cV[idx] = V;
}

__global__ void scan_p2(const float* __restrict__ cC, const float* __restrict__ cV,
                        float* __restrict__ hin, int chTot, int CHNp,
                        const float* __restrict__ hcarry, int useCarry) {
  const int ch = blockIdx.x * 384 + threadIdx.x;
  float h = useCarry ? hcarry[ch] : 0.f;
  for (int cid = 0; cid < CHNp; cid++) {
    const int idx = cid * chTot + ch;
    hin[idx] = h;
    h = fmaf(cC[idx], h, cV[idx]);
  }
}

__global__ void scan_p3(const unsigned short* __restrict__ hg, const float* __restrict__ hin,
                        unsigned short* __restrict__ hout, void* __restrict__ nh, long nhOff,
                        float* __restrict__ hcarry, int chTot, int SL, int CHNp,
                        int writeNh, const int* __restrict__ flagp) {
  const int e = threadIdx.x, bh = blockIdx.y, cid = blockIdx.x;
  const int bL = bh >> 2, hh = bh & 3;
  const long tok = (long)bL * SL + (long)cid * CHLEN;
  long base  = tok * 3072 + hh * 768 + e;
  long obase = tok * 1536 + hh * 384 + e;
  float h = hin[cid * chTot + bh * 384 + e];
  for (int i = 0; i < CHLEN; i++) {
    const float hid = bf2f(hg[base]), gt = bf2f(hg[base + 384]);
    float c, sg; cv_compute(gt, c, sg);
    h = fmaf(c, h, sg * gfun(hid));
    hout[obase] = f2bf(h);
    base += 3072; obase += 1536;
  }
  if (cid == CHNp - 1) {
    hcarry[bh * 384 + e] = h;
    if (writeNh) stout(nh, nhOff + bL * 1536 + hh * 384 + e, *flagp, h);
  }
}

// ---------------- weight conversion / transposes (flag-branching reads) -------
__global__ void cvt_k(const void* __restrict__ in, unsigned short* __restrict__ out,
                      int n, const int* __restrict__ flagp) {
  const int i = blockIdx.x * 256 + threadIdx.x;
  if (i < n) out[i] = f2bf(ldin(in, i, *flagp));
}
__global__ void tr_whg(const void* __restrict__ in, unsigned short* __restrict__ out,
                       const int* __restrict__ flagp) {
  const int idx = blockIdx.x * 256 + threadIdx.x;  // (h*768+n)*256+k
  const int k = idx & 255, n = (idx >> 8) % 768, h = idx / (768 * 256);
  out[idx] = f2bf(ldin(in, (long)(h * 256 + k) * 768 + n, *flagp));
}
__global__ void tr_wout(const void* __restrict__ in, unsigned short* __restrict__ out,
                        const int* __restrict__ flagp) {
  const int idx = blockIdx.x * 256 + threadIdx.x;  // (h*256+n)*384+k
  const int k = idx % 384, n = (idx / 384) & 255, h = idx / (384 * 256);
  out[idx] = f2bf(ldin(in, (long)(h * 384 + k) * 256 + n, *flagp));
}
__global__ void tr_wg(const void* __restrict__ in, unsigned short* __restrict__ out,
                      const int* __restrict__ flagp) {
  const int idx = blockIdx.x * 256 + threadIdx.x;  // n*1024+k, n<2816
  const int k = idx & 1023, n = idx >> 10;
  out[idx] = (n < FFN) ? f2bf(ldin(in, (long)k * FFN + n, *flagp)) : (unsigned short)0;
}
// interleaved gate/value: B row R -> tile=R>>8, pair=(R&255)>>5, sel=(R>>4)&1,
// col = tile*128 + pair*16 + (R&15); out[R][k] = W_{sel}[k][col] (0 if col>=FFN)
__global__ void tr_wgv(const void* __restrict__ wg, const void* __restrict__ wv,
                       unsigned short* __restrict__ out, const int* __restrict__ flagp) {
  const int idx = blockIdx.x * 256 + threadIdx.x;  // R*1024+k, R<5632
  const int k = idx & 1023, R = idx >> 10;
  const int tile = R >> 8, rb = R & 255;
  const int pair = rb >> 5, sel = (rb >> 4) & 1, r16 = rb & 15;
  const int col  = tile * 128 + pair * 16 + r16;
  const void* src = sel ? wv : wg;
  out[idx] = (col < FFN) ? f2bf(ldin(src, (long)k * FFN + col, *flagp)) : (unsigned short)0;
}
__global__ void tr_wfo(const void* __restrict__ in, unsigned short* __restrict__ out,
                       const int* __restrict__ flagp) {
  const int idx = blockIdx.x * 256 + threadIdx.x;  // n*2816+kk
  const int kk = idx % FFP, n = idx / FFP;
  out[idx] = (kk < FFN) ? f2bf(ldin(in, (long)kk * DM + n, *flagp)) : (unsigned short)0;
}

// ---------------- launch ------------------------------------------------------
extern "C" void kernel_launch(void* const* d_in, const int* in_sizes, int n_in,
                              void* d_out, int out_size, void* d_ws, size_t ws_size,
                              hipStream_t stream) {
  const void* x      = d_in[0];
  const void* dw_w   = d_in[1];
  const void* dw_b   = d_in[2];
  const void* pw_w   = d_in[3];  // [N=1024][K=1024] already
  const void* pw_b   = d_in[4];
  const void* conv_g = d_in[5];
  const void* gru_g  = d_in[6];
  const void* ff_g   = d_in[7];
  const void* w_hg   = d_in[8];
  const void* w_out  = d_in[9];
  const void* w_gate = d_in[10];
  const void* w_val  = d_in[11];
  const void* w_ffo  = d_in[12];

  // Pass size from ws_size (deterministic): need(MT) = 21,795,072 + MT*13,888.
  const long FIXED = 21795072L;
  int MT = 128;
  if      (ws_size >= (size_t)(FIXED + 16384L * 13888)) MT = 16384;
  else if (ws_size >= (size_t)(FIXED + 8192L * 13888))  MT = 8192;
  else if (ws_size >= (size_t)(FIXED + 4096L * 13888))  MT = 4096;
  else if (ws_size >= (size_t)(FIXED + 2048L * 13888))  MT = 2048;
  else if (ws_size >= (size_t)(FIXED + 1024L * 13888))  MT = 1024;
  else if (ws_size >= (size_t)(FIXED + 512L * 13888))   MT = 512;
  else if (ws_size >= (size_t)(FIXED + 256L * 13888))   MT = 256;

  const int SL    = (MT >= SEQL) ? SEQL : MT;
  const int nSeq  = MT / SL;
  const int CHNp  = SL / CHLEN;
  const int chTot = nSeq * 1536;
  const int big   = (MT >= 256);  // 256^2 16-wave path for the two FF GEMMs

  char* p = (char*)d_ws;
  unsigned short* whgT  = (unsigned short*)p; p += 1572864;
  unsigned short* woutT = (unsigned short*)p; p += 786432;
  unsigned short* wgT   = (unsigned short*)p; p += 5767168;
  unsigned short* wvT   = (unsigned short*)p; p += 5767168;
  unsigned short* wfoT  = (unsigned short*)p; p += 5767168;
  unsigned short* pwT   = (unsigned short*)p; p += 2097152;
  unsigned short* dwwB  = (unsigned short*)p; p += 8192;
  unsigned short* dwbB  = (unsigned short*)p; p += 2048;
  unsigned short* pwbB  = (unsigned short*)p; p += 2048;
  unsigned short* cgB   = (unsigned short*)p; p += 2048;
  unsigned short* ggB   = (unsigned short*)p; p += 2048;
  unsigned short* fgB   = (unsigned short*)p; p += 2048;
  int*            flag  = (int*)p;            p += 256;
  float*          hcarry= (float*)p;          p += 12288;
  float*          cC    = (float*)p;          p += (long)MT * 192;
  float*          cV    = (float*)p;          p += (long)MT * 192;
  float*          hin   = (float*)p;          p += (long)MT * 192;
  unsigned short* xnb   = (unsigned short*)p; p += 6144 + (long)MT * 2048;
  unsigned short* xc    = (unsigned short*)p; p += (long)MT * 2048;
  unsigned short* hbuf  = (unsigned short*)p; p += (long)MT * 3072;
  unsigned short* ybuf  = (unsigned short*)p;  // region R: ybuf / hg / ffin
  unsigned short* hg    = (unsigned short*)p;
  unsigned short* ffin  = (unsigned short*)p;
  unsigned short* xn    = xnb + 3 * DM;
  unsigned short* wgvT  = wgT;  // interleaved [5632][1024] spans wgT+wvT slots

  // dtype detection + weight conversion (once per call)
  detect_k<<<1, 256, 0, stream>>>((const unsigned short*)x, flag);
  tr_whg<<<3072, 256, 0, stream>>>(w_hg, whgT, flag);
  tr_wout<<<1536, 256, 0, stream>>>(w_out, woutT, flag);
  if (big) {
    tr_wgv<<<22528, 256, 0, stream>>>(w_gate, w_val, wgvT, flag);
  } else {
    tr_wg<<<11264, 256, 0, stream>>>(w_gate, wgT, flag);
    tr_wg<<<11264, 256, 0, stream>>>(w_val, wvT, flag);
  }
  tr_wfo<<<11264, 256, 0, stream>>>(w_ffo, wfoT, flag);
  cvt_k<<<4096, 256, 0, stream>>>(pw_w, pwT, 1048576, flag);
  cvt_k<<<16, 256, 0, stream>>>(dw_w, dwwB, 4096, flag);
  cvt_k<<<4, 256, 0, stream>>>(dw_b, dwbB, 1024, flag);
  cvt_k<<<4, 256, 0, stream>>>(pw_b, pwbB, 1024, flag);
  cvt_k<<<4, 256, 0, stream>>>(conv_g, cgB, 1024, flag);
  cvt_k<<<4, 256, 0, stream>>>(gru_g, ggB, 1024, flag);
  cvt_k<<<4, 256, 0, stream>>>(ff_g, fgB, 1024, flag);

  for (long t0 = 0; t0 < 16384; t0 += MT) {
    const int l0     = (int)(t0 & (SEQL - 1));
    const int P      = (l0 > 0) ? 3 : 0;
    const int seqEnd = (l0 + SL == SEQL);
    const long nhOff = NH_OFF + (t0 / SEQL) * 1536;

    // conv block: xc = pw(dwconv(rmsnorm(x))) + pw_b + x
    rmsnorm_x<<<MT + P, 64, 0, stream>>>(x, (t0 - P) * DM, cgB, xn - (long)P * DM, flag);
    dwconv_k<<<dim3(MT, 4), 256, 0, stream>>>(xn, dwwB, dwbB, ybuf, l0);
    gemm_bf16<1><<<dim3(8, MT / 128, 1), 256, 0, stream>>>(ybuf, DM, 0, pwT, 0, DM,
        xc, DM, 0, 0L, pwbB, x, DM, t0 * DM, flag);

    // GRU block
    rmsnorm_k<<<MT, 64, 0, stream>>>(xc, ggB, xn);
    gemm_bf16<0><<<dim3(6, MT / 128, 4), 256, 0, stream>>>(xn, DM, 256, whgT, 196608, 256,
        hg, 3072, 768, 0L, nullptr, nullptr, 0, 0L, nullptr);
    scan_p1<<<dim3(CHNp, nSeq * 4), 384, 0, stream>>>(hg, cC, cV, chTot, SL);
    scan_p2<<<nSeq * 4, 384, 0, stream>>>(cC, cV, hin, chTot, CHNp, hcarry, l0 > 0);
    scan_p3<<<dim3(CHNp, nSeq * 4), 384, 0, stream>>>(hg, hin, hbuf, d_out, nhOff,
        hcarry, chTot, SL, CHNp, seqEnd, flag);
    gemm_bf16<2><<<dim3(2, MT / 128, 4), 256, 0, stream>>>(hbuf, 1536, 384, woutT, 98304, 384,
        xc, DM, 256, 0L, nullptr, xc, DM, 0L, nullptr);

    // FF block
    rmsnorm_k<<<MT, 64, 0, stream>>>(xc, fgB, xn);
    if (big) {
      gemm256<0><<<dim3(22, MT / 256), 1024, 0, stream>>>(xn, wgvT, DM,
          ffin, nullptr, 0L, nullptr);
      gemm256<1><<<dim3(4, MT / 256), 1024, 0, stream>>>(ffin, wfoT, FFP,
          d_out, xc, t0 * DM, flag);
    } else {
      gemm_ff<<<dim3(22, MT / 128), 256, 0, stream>>>(xn, wgT, wvT, ffin);
      gemm_bf16<3><<<dim3(8, MT / 128, 1), 256, 0, stream>>>(ffin, FFP, 0, wfoT, 0, FFP,
          d_out, DM, 0, t0 * DM, nullptr, xc, DM, 0L, flag);
    }
  }
}

// Round 10
// 939.209 us; speedup vs baseline: 3.9687x; 1.0208x over previous
//
#include <hip/hip_runtime.h>
#include <stdint.h>

// MinGRUBlock on MI355X (gfx950). Input/output dtype (f32 vs bf16) DETECTED at
// runtime from x's bit patterns (flag in ws). Internals bf16. Residual in ws.
// Small GEMMs: mfma_f32_16x16x32_bf16, 128x128 tile, BK=64, global_load_lds
// w=16, XOR-swizzled LDS (chunk c of row r at c^(r&7)).
// Big GEMMs (FF gate/value and FF out): 256x256 tile, 16 waves (1024 thr,
// 4 waves/SIMD), per-wave 64x64, acc 64 AGPR + 32 VGPR frag peak, BK=64,
// dbuf 128 KiB LDS, chunk-XOR swizzle, stage-into-dead-buffer + vmcnt(0)
// publish (round-9 structure, best measured: MfmaUtil 36%, 228 us).
// Weight-prep transposes: LDS-tiled coalesced (round-10 change — the old
// scalar transposes did stride-4KB/11KB 4-byte scattered reads = one
// cacheline per element, ~100 us aggregate).
// Scan: 3-phase chunked, h_t = sigmoid(-g)*h + sigmoid(g)*gfun(hid), f32 carry.

#define DM     1024
#define SEQL   4096
#define FFN    2730
#define FFP    2816
#define NH_OFF 16777216L
#define CHLEN  128

using bf16x8 = __attribute__((ext_vector_type(8))) short;
using f32x4  = __attribute__((ext_vector_type(4))) float;

__device__ __forceinline__ float bf2f(unsigned short h) {
  union { unsigned int u; float f; } v; v.u = ((unsigned int)h) << 16; return v.f;
}
__device__ __forceinline__ unsigned short f2bf(float f) {
  union { float f; unsigned int u; } v; v.f = f;
  unsigned int u = v.u;
  return (unsigned short)((u + 0x7fffu + ((u >> 16) & 1u)) >> 16);
}
__device__ __forceinline__ float ldin(const void* p, long i, int f32mode) {
  return f32mode ? ((const float*)p)[i] : bf2f(((const unsigned short*)p)[i]);
}
__device__ __forceinline__ void stout(void* p, long i, int f32mode, float v) {
  if (f32mode) ((float*)p)[i] = v; else ((unsigned short*)p)[i] = f2bf(v);
}
__device__ __forceinline__ void gload_lds16(const unsigned short* g, unsigned short* lds) {
  __builtin_amdgcn_global_load_lds(
      (const __attribute__((address_space(1))) unsigned int*)g,
      (__attribute__((address_space(3))) unsigned int*)lds,
      16, 0, 0);
}

// ---------------- dtype detection --------------------------------------------
__global__ void detect_k(const unsigned short* __restrict__ x, int* __restrict__ flag) {
  __shared__ int cnt;
  if (threadIdx.x == 0) cnt = 0;
  __syncthreads();
  int c = 0;
  for (int j = 0; j < 4; j++) {
    unsigned short v = x[2 * (threadIdx.x * 4 + j)];
    int ex = (v >> 7) & 0xFF;
    if (ex >= 0x84) c++;
  }
  atomicAdd(&cnt, c);
  __syncthreads();
  if (threadIdx.x == 0) *flag = (cnt >= 32) ? 1 : 0;
}

// ---------------- GEMM: C[M,N] = A[M,K] * B^T  (B stored [N][K], ldb=K) -------
// EPI 0: bf16 plain. EPI 1: bf16 = acc + bias[col] + raw_res (flag).
// EPI 2: bf16 = acc + bf16res. EPI 3: raw_out (flag) = acc + bf16res.
template <int EPI>
__launch_bounds__(256)
__global__ void gemm_bf16(const unsigned short* __restrict__ A, int lda, int aOffZ,
                          const unsigned short* __restrict__ Bm, int bOffZ, int K,
                          void* __restrict__ Cout, int ldc, int cOffZ, long outOff,
                          const unsigned short* __restrict__ bias,
                          const void* __restrict__ res, int ldres, long resOff,
                          const int* __restrict__ flagp) {
  __shared__ __align__(16) unsigned short As[128][64];
  __shared__ __align__(16) unsigned short Bs[128][64];

  const int tid  = threadIdx.x;
  const int w    = tid >> 6;
  const int lane = tid & 63;
  const int z    = blockIdx.z;
  const long tm  = (long)blockIdx.y * 128;
  const long tn  = (long)blockIdx.x * 128;

  const unsigned short* Ag = A + (long)z * aOffZ;
  const unsigned short* Bg = Bm + (long)z * bOffZ;

  f32x4 acc[4][4];
#pragma unroll
  for (int i = 0; i < 4; i++)
#pragma unroll
    for (int j = 0; j < 4; j++) acc[i][j] = (f32x4){0.f, 0.f, 0.f, 0.f};

  const int wrow = w * 32;
  const int srow = lane >> 3;                    // 0..7
  const int scol = (((lane & 7) ^ srow) * 8);    // xor-swizzled source chunk
  const int wm   = (w >> 1) * 64;
  const int wn   = (w & 1) * 64;
  const int quad = lane >> 4;
  const int lo   = lane & 15;
  const int sw   = lo & 7;                       // row-based xor key for reads

  for (int k0 = 0; k0 < K; k0 += 64) {
    __syncthreads();
#pragma unroll
    for (int i = 0; i < 4; i++) {
      const int r = wrow + i * 8;  // wave-uniform LDS base
      gload_lds16(Ag + (tm + r + srow) * (long)lda + k0 + scol, &As[r][0]);
      gload_lds16(Bg + (tn + r + srow) * (long)K + k0 + scol, &Bs[r][0]);
    }
    __syncthreads();
#pragma unroll
    for (int kk = 0; kk < 64; kk += 32) {
      const int kc = kk >> 3;  // 0 or 4
      bf16x8 af[4], bfr[4];
#pragma unroll
      for (int mt = 0; mt < 4; mt++)
        af[mt] = *(const bf16x8*)&As[wm + mt * 16 + lo][((quad + kc) ^ sw) * 8];
#pragma unroll
      for (int nt = 0; nt < 4; nt++)
        bfr[nt] = *(const bf16x8*)&Bs[wn + nt * 16 + lo][((quad + kc) ^ sw) * 8];
#pragma unroll
      for (int mt = 0; mt < 4; mt++)
#pragma unroll
        for (int nt = 0; nt < 4; nt++)
          acc[mt][nt] = __builtin_amdgcn_mfma_f32_16x16x32_bf16(af[mt], bfr[nt], acc[mt][nt], 0, 0, 0);
    }
  }

  const int f32m = (EPI == 1 || EPI == 3) ? *flagp : 0;
#pragma unroll
  for (int mt = 0; mt < 4; mt++) {
#pragma unroll
    for (int nt = 0; nt < 4; nt++) {
#pragma unroll
      for (int r = 0; r < 4; r++) {
        const long grow = tm + wm + mt * 16 + quad * 4 + r;
        const long gcol = tn + wn + nt * 16 + lo;
        float v         = acc[mt][nt][r];
        if (EPI == 0) {
          ((unsigned short*)Cout + (long)z * cOffZ)[grow * (long)ldc + gcol] = f2bf(v);
        } else if (EPI == 1) {
          v += bf2f(bias[gcol]) + ldin(res, resOff + grow * (long)ldres + gcol, f32m);
          ((unsigned short*)Cout)[grow * (long)ldc + gcol] = f2bf(v);
        } else if (EPI == 2) {
          v += bf2f(((const unsigned short*)res + (long)z * cOffZ)[grow * (long)ldres + gcol]);
          ((unsigned short*)Cout + (long)z * cOffZ)[grow * (long)ldc + gcol] = f2bf(v);
        } else {  // EPI == 3: final output
          v += bf2f(((const unsigned short*)res)[grow * (long)ldres + gcol]);
          stout(Cout, outOff + grow * (long)ldc + gcol, f32m, v);
        }
      }
    }
  }
}

// ---------------- fused FF GEMM (legacy 128^2 path, used when MT<256) ---------
__launch_bounds__(256)
__global__ void gemm_ff(const unsigned short* __restrict__ A,
                        const unsigned short* __restrict__ Bgm,
                        const unsigned short* __restrict__ Bvm,
                        unsigned short* __restrict__ Cout) {
  __shared__ __align__(16) unsigned short As[128][64];
  __shared__ __align__(16) unsigned short Bgs[128][64];
  __shared__ __align__(16) unsigned short Bvs[128][64];

  const int tid  = threadIdx.x;
  const int w    = tid >> 6;
  const int lane = tid & 63;
  const long tm  = (long)blockIdx.y * 128;
  const long tn  = (long)blockIdx.x * 128;

  f32x4 accG[4][4], accV[4][4];
#pragma unroll
  for (int i = 0; i < 4; i++)
#pragma unroll
    for (int j = 0; j < 4; j++) {
      accG[i][j] = (f32x4){0.f, 0.f, 0.f, 0.f};
      accV[i][j] = (f32x4){0.f, 0.f, 0.f, 0.f};
    }

  const int wrow = w * 32;
  const int srow = lane >> 3;
  const int scol = (((lane & 7) ^ srow) * 8);
  const int wm   = (w >> 1) * 64;
  const int wn   = (w & 1) * 64;
  const int quad = lane >> 4;
  const int lo   = lane & 15;
  const int sw   = lo & 7;

  for (int k0 = 0; k0 < DM; k0 += 64) {
    __syncthreads();
#pragma unroll
    for (int i = 0; i < 4; i++) {
      const int r = wrow + i * 8;
      gload_lds16(A + (tm + r + srow) * (long)DM + k0 + scol, &As[r][0]);
      gload_lds16(Bgm + (tn + r + srow) * (long)DM + k0 + scol, &Bgs[r][0]);
      gload_lds16(Bvm + (tn + r + srow) * (long)DM + k0 + scol, &Bvs[r][0]);
    }
    __syncthreads();
#pragma unroll
    for (int kk = 0; kk < 64; kk += 32) {
      const int kc = kk >> 3;
      bf16x8 af[4], bfr[4];
#pragma unroll
      for (int mt = 0; mt < 4; mt++)
        af[mt] = *(const bf16x8*)&As[wm + mt * 16 + lo][((quad + kc) ^ sw) * 8];
#pragma unroll
      for (int nt = 0; nt < 4; nt++)
        bfr[nt] = *(const bf16x8*)&Bgs[wn + nt * 16 + lo][((quad + kc) ^ sw) * 8];
#pragma unroll
      for (int mt = 0; mt < 4; mt++)
#pragma unroll
        for (int nt = 0; nt < 4; nt++)
          accG[mt][nt] = __builtin_amdgcn_mfma_f32_16x16x32_bf16(af[mt], bfr[nt], accG[mt][nt], 0, 0, 0);
#pragma unroll
      for (int nt = 0; nt < 4; nt++)
        bfr[nt] = *(const bf16x8*)&Bvs[wn + nt * 16 + lo][((quad + kc) ^ sw) * 8];
#pragma unroll
      for (int mt = 0; mt < 4; mt++)
#pragma unroll
        for (int nt = 0; nt < 4; nt++)
          accV[mt][nt] = __builtin_amdgcn_mfma_f32_16x16x32_bf16(af[mt], bfr[nt], accV[mt][nt], 0, 0, 0);
    }
  }

#pragma unroll
  for (int mt = 0; mt < 4; mt++) {
#pragma unroll
    for (int nt = 0; nt < 4; nt++) {
#pragma unroll
      for (int r = 0; r < 4; r++) {
        const long grow = tm + wm + mt * 16 + quad * 4 + r;
        const long gcol = tn + wn + nt * 16 + lo;
        const float g   = accG[mt][nt][r];
        const float s   = g / (1.f + __expf(-g));
        Cout[grow * (long)FFP + gcol] = f2bf(s * accV[mt][nt][r]);
      }
    }
  }
}

// ---------------- 256^2 GEMM, 16 waves, 4 waves/SIMD, 32-reg frag peak -------
// (round-9 structure, unchanged: best measured MfmaUtil 36%, 228 us)
template <int EPI>
__launch_bounds__(1024, 4)
__global__ void gemm256(const unsigned short* __restrict__ A,
                        const unsigned short* __restrict__ Bm,
                        int K,
                        void* __restrict__ Cout,
                        const unsigned short* __restrict__ res,
                        long outOff,
                        const int* __restrict__ flagp) {
  __shared__ __align__(16) unsigned short As[2][256][64];
  __shared__ __align__(16) unsigned short Bs[2][256][64];

  const int tid  = threadIdx.x;
  const int w    = tid >> 6;      // 0..15
  const int lane = tid & 63;
  const int wr   = w >> 2;        // 0..3  (M band of 64)
  const int wc   = w & 3;         // 0..3  (N band of 64)
  const int quad = lane >> 4;
  const int lo   = lane & 15;
  const int sw   = lo & 7;

  // bijective XCD-aware block swizzle (m204 formula)
  const int gx  = gridDim.x;
  int bid       = blockIdx.y * gx + blockIdx.x;
  const int nwg = gx * gridDim.y;
  {
    const int q = nwg >> 3, r8 = nwg & 7;
    const int xc8 = bid & 7, j = bid >> 3;
    bid = (xc8 < r8 ? xc8 * (q + 1) : r8 * (q + 1) + (xc8 - r8) * q) + j;
  }
  const long tn = (long)(bid % gx) * 256;  // B-row tile base
  const long tm = (long)(bid / gx) * 256;  // M tile base

  const int NT = K >> 6;  // even, >= 4 by construction

  // staging source addressing: per-lane swizzled global address, linear LDS.
  const int srow = lane >> 3;                 // 0..7
  const int sch  = (lane & 7) ^ srow;         // source chunk = pos ^ key(row)
  const unsigned short* Ab = A + (tm + (long)w * 16 + srow) * (long)K + sch * 8;
  const unsigned short* Bb = Bm + (tn + (long)w * 16 + srow) * (long)K + sch * 8;

#define STAGE_A(BUF, TT)                                                          \
  gload_lds16(Ab + (long)(TT) * 64, &As[BUF][w * 16][0]);                         \
  gload_lds16(Ab + 8L * K + (long)(TT) * 64, &As[BUF][w * 16 + 8][0]);
#define STAGE_B(BUF, TT)                                                          \
  gload_lds16(Bb + (long)(TT) * 64, &Bs[BUF][w * 16][0]);                         \
  gload_lds16(Bb + 8L * K + (long)(TT) * 64, &Bs[BUF][w * 16 + 8][0]);

  // prologue: tile 0 only (tile 1 staged during tile 0)
  STAGE_B(0, 0)
  STAGE_A(0, 0)

  f32x4 acc[4][4];
#pragma unroll
  for (int i = 0; i < 4; i++)
#pragma unroll
    for (int j = 0; j < 4; j++) acc[i][j] = (f32x4){0.f, 0.f, 0.f, 0.f};

  asm volatile("s_waitcnt vmcnt(0)" ::: "memory");
  __builtin_amdgcn_s_barrier();

  bf16x8 a[2][2], b[2][2];

#define LDA2(CBUF, RB)                                                            \
  _Pragma("unroll") for (int m = 0; m < 2; m++) {                                 \
    _Pragma("unroll") for (int c = 0; c < 2; c++) {                               \
      a[m][c] = *(const bf16x8*)&As[CBUF][wr * 64 + ((RB) + m) * 16 + lo]         \
                                       [((quad + 4 * c) ^ sw) * 8];               \
    }                                                                             \
  }
#define LDB2(CBUF, NB)                                                            \
  _Pragma("unroll") for (int n = 0; n < 2; n++) {                                 \
    _Pragma("unroll") for (int c = 0; c < 2; c++) {                               \
      b[n][c] = *(const bf16x8*)&Bs[CBUF][wc * 64 + ((NB) + n) * 16 + lo]         \
                                       [((quad + 4 * c) ^ sw) * 8];               \
    }                                                                             \
  }
#define MFMA_Q(MB, NB)                                                            \
  __builtin_amdgcn_s_setprio(1);                                                  \
  _Pragma("unroll") for (int m = 0; m < 2; m++) {                                 \
    _Pragma("unroll") for (int n = 0; n < 2; n++) {                               \
      _Pragma("unroll") for (int c = 0; c < 2; c++) {                             \
        acc[(MB) + m][(NB) + n] = __builtin_amdgcn_mfma_f32_16x16x32_bf16(        \
            a[m][c], b[n][c], acc[(MB) + m][(NB) + n], 0, 0, 0);                  \
      }                                                                           \
    }                                                                             \
  }                                                                               \
  __builtin_amdgcn_s_setprio(0);

// One sub-tile. STG: stage tile TT+1 into CBUF^1 (holds dead tile TT-1).
#define SUBTILE(CBUF, TT, STG)                                                    \
  {                                                                               \
    /* P0: aL + b01; stage B(TT+1); MFMA Q0 = mLo x nLo */                        \
    LDA2(CBUF, 0);                                                                \
    LDB2(CBUF, 0);                                                                \
    if (STG) { STAGE_B(CBUF ^ 1, (TT) + 1) }                                      \
    MFMA_Q(0, 0);                                                                 \
    __builtin_amdgcn_s_barrier();                                                 \
    /* P1: b23 (b01 consumed); stage A(TT+1); MFMA Q1 = mLo x nHi */              \
    LDB2(CBUF, 2);                                                                \
    if (STG) { STAGE_A(CBUF ^ 1, (TT) + 1) }                                      \
    MFMA_Q(0, 2);                                                                 \
    __builtin_amdgcn_s_barrier();                                                 \
    /* P2: aH (aL consumed); MFMA Q2 = mHi x nHi */                               \
    LDA2(CBUF, 2);                                                                \
    MFMA_Q(2, 2);                                                                 \
    __builtin_amdgcn_s_barrier();                                                 \
    /* P3: re-read b01; MFMA Q3 = mHi x nLo; publish staged tile */               \
    LDB2(CBUF, 0);                                                                \
    MFMA_Q(2, 0);                                                                 \
    if (STG) asm volatile("s_waitcnt vmcnt(0)" ::: "memory");                     \
    __builtin_amdgcn_s_barrier();                                                 \
  }

  // main loop: tiles 0..NT-2 stage their successor; tile NT-1 stages nothing
  for (int t = 0; t < NT - 2; t += 2) {
    SUBTILE(0, t, 1)
    SUBTILE(1, t + 1, 1)
  }
  SUBTILE(0, NT - 2, 1)
  SUBTILE(1, NT - 1, 0)

  if (EPI == 0) {
    // silu(gate) * value, lane-local pairing; ffin col base = tn/2
    const long colb = (tn >> 1);
    const long rowb = tm + wr * 64;
#pragma unroll
    for (int m = 0; m < 4; m++) {
#pragma unroll
      for (int np = 0; np < 2; np++) {
        const long col = colb + (wc * 2 + np) * 16 + lo;
#pragma unroll
        for (int r = 0; r < 4; r++) {
          const long row = rowb + m * 16 + quad * 4 + r;
          const float g  = acc[m][2 * np][r];
          const float v  = acc[m][2 * np + 1][r];
          const float s  = g / (1.f + __expf(-g));
          ((unsigned short*)Cout)[row * (long)FFP + col] = f2bf(s * v);
        }
      }
    }
  } else {
    const int f32m = *flagp;
    const long rowb = tm + wr * 64;
    const long colb = tn + wc * 64;
#pragma unroll
    for (int m = 0; m < 4; m++) {
#pragma unroll
      for (int n = 0; n < 4; n++) {
#pragma unroll
        for (int r = 0; r < 4; r++) {
          const long row = rowb + m * 16 + quad * 4 + r;
          const long col = colb + n * 16 + lo;
          float v = acc[m][n][r] + bf2f(res[row * (long)DM + col]);
          stout(Cout, outOff + row * (long)DM + col, f32m, v);
        }
      }
    }
  }
#undef STAGE_A
#undef STAGE_B
#undef LDA2
#undef LDB2
#undef MFMA_Q
#undef SUBTILE
}

// ---------------- RMSNorm: raw input variant (flag) --------------------------
__global__ void rmsnorm_x(const void* __restrict__ in, long elemOff,
                          const unsigned short* __restrict__ gamma,
                          unsigned short* __restrict__ out,
                          const int* __restrict__ flagp) {
  const int t    = blockIdx.x;
  const int lane = threadIdx.x;
  const int f32m = *flagp;
  float v[16];
  const long base = elemOff + (long)t * DM;
  if (f32m) {
    const float4* rp = (const float4*)((const float*)in + base);
#pragma unroll
    for (int j = 0; j < 4; j++) {
      float4 u     = rp[j * 64 + lane];
      v[j * 4 + 0] = u.x; v[j * 4 + 1] = u.y; v[j * 4 + 2] = u.z; v[j * 4 + 3] = u.w;
    }
  } else {
    const ushort4* rp = (const ushort4*)((const unsigned short*)in + base);
#pragma unroll
    for (int j = 0; j < 4; j++) {
      ushort4 u    = rp[j * 64 + lane];
      v[j * 4 + 0] = bf2f(u.x); v[j * 4 + 1] = bf2f(u.y);
      v[j * 4 + 2] = bf2f(u.z); v[j * 4 + 3] = bf2f(u.w);
    }
  }
  float s = 0.f;
#pragma unroll
  for (int i = 0; i < 16; i++) s = fmaf(v[i], v[i], s);
#pragma unroll
  for (int off = 32; off > 0; off >>= 1) s += __shfl_xor(s, off, 64);
  const float scale = 32.f / fmaxf(sqrtf(s), 1e-12f);
  ushort4* op       = (ushort4*)(out + (long)t * DM);
  const ushort4* gp = (const ushort4*)gamma;
#pragma unroll
  for (int j = 0; j < 4; j++) {
    ushort4 g = gp[j * 64 + lane];
    ushort4 o;
    o.x = f2bf(v[j * 4 + 0] * scale * (bf2f(g.x) + 1.f));
    o.y = f2bf(v[j * 4 + 1] * scale * (bf2f(g.y) + 1.f));
    o.z = f2bf(v[j * 4 + 2] * scale * (bf2f(g.z) + 1.f));
    o.w = f2bf(v[j * 4 + 3] * scale * (bf2f(g.w) + 1.f));
    op[j * 64 + lane] = o;
  }
}

// ---------------- RMSNorm (bf16 in/out) --------------------------------------
__global__ void rmsnorm_k(const unsigned short* __restrict__ in,
                          const unsigned short* __restrict__ gamma,
                          unsigned short* __restrict__ out) {
  const int t    = blockIdx.x;
  const int lane = threadIdx.x;
  float v[16];
  const ushort4* rp = (const ushort4*)(in + (long)t * DM);
#pragma unroll
  for (int j = 0; j < 4; j++) {
    ushort4 u    = rp[j * 64 + lane];
    v[j * 4 + 0] = bf2f(u.x); v[j * 4 + 1] = bf2f(u.y);
    v[j * 4 + 2] = bf2f(u.z); v[j * 4 + 3] = bf2f(u.w);
  }
  float s = 0.f;
#pragma unroll
  for (int i = 0; i < 16; i++) s = fmaf(v[i], v[i], s);
#pragma unroll
  for (int off = 32; off > 0; off >>= 1) s += __shfl_xor(s, off, 64);
  const float scale = 32.f / fmaxf(sqrtf(s), 1e-12f);
  ushort4* op       = (ushort4*)(out + (long)t * DM);
  const ushort4* gp = (const ushort4*)gamma;
#pragma unroll
  for (int j = 0; j < 4; j++) {
    ushort4 g = gp[j * 64 + lane];
    ushort4 o;
    o.x = f2bf(v[j * 4 + 0] * scale * (bf2f(g.x) + 1.f));
    o.y = f2bf(v[j * 4 + 1] * scale * (bf2f(g.y) + 1.f));
    o.z = f2bf(v[j * 4 + 2] * scale * (bf2f(g.z) + 1.f));
    o.w = f2bf(v[j * 4 + 3] * scale * (bf2f(g.w) + 1.f));
    op[j * 64 + lane] = o;
  }
}

// ---------------- causal depthwise conv K=4 ----------------------------------
__global__ void dwconv_k(const unsigned short* __restrict__ xn,
                         const unsigned short* __restrict__ dww,
                         const unsigned short* __restrict__ dwb,
                         unsigned short* __restrict__ y, int l0) {
  const int t = blockIdx.x;
  const int d = blockIdx.y * 256 + threadIdx.x;
  const int l = l0 + (t & (SEQL - 1));
  ushort4 w4  = ((const ushort4*)dww)[d];
  float wk[4] = {bf2f(w4.x), bf2f(w4.y), bf2f(w4.z), bf2f(w4.w)};
  float acc   = bf2f(dwb[d]);
#pragma unroll
  for (int k = 0; k < 4; k++) {
    const int ll = l + k - 3;
    if (ll >= 0) acc = fmaf(bf2f(xn[(long)(t + k - 3) * DM + d]), wk[k], acc);
  }
  y[(long)t * DM + d] = f2bf(acc);
}

// ---------------- scan --------------------------------------------------------
__device__ __forceinline__ void cv_compute(float gt, float& c, float& sg) {
  gt = fminf(fmaxf(gt, -40.f), 40.f);
  const float e  = __expf(-fabsf(gt));
  const float r  = 1.f / (1.f + e);
  const float rs = e * r;
  c  = (gt >= 0.f) ? rs : r;   // sigmoid(-gt)
  sg = (gt >= 0.f) ? r : rs;   // sigmoid(gt)
}
__device__ __forceinline__ float gfun(float hid) {
  hid = fminf(fmaxf(hid, -40.f), 40.f);
  if (hid >= 0.f) return hid + 0.5f;
  const float e = __expf(hid);
  return e / (1.f + e);
}

__global__ void scan_p1(const unsigned short* __restrict__ hg, float* __restrict__ cC,
                        float* __restrict__ cV, int chTot, int SL) {
  const int e = threadIdx.x, bh = blockIdx.y, cid = blockIdx.x;
  const int bL = bh >> 2, hh = bh & 3;
  long base = ((long)(bL * SL + cid * CHLEN)) * 3072 + hh * 768 + e;
  float C = 1.f, V = 0.f;
  for (int i = 0; i < CHLEN; i++) {
    const float hid = bf2f(hg[base]), gt = bf2f(hg[base + 384]);
    float c, sg; cv_compute(gt, c, sg);
    C *= c;
    V = fmaf(c, V, sg * gfun(hid));
    base += 3072;
  }
  const int idx = cid * chTot + bh * 384 + e;
  cC[idx] = C; cV[idx] = V;
}

__global__ void scan_p2(const float* __restrict__ cC, const float* __restrict__ cV,
                        float* __restrict__ hin, int chTot, int CHNp,
                        const float* __restrict__ hcarry, int useCarry) {
  const int ch = blockIdx.x * 384 + threadIdx.x;
  float h = useCarry ? hcarry[ch] : 0.f;
  for (int cid = 0; cid < CHNp; cid++) {
    const int idx = cid * chTot + ch;
    hin[idx] = h;
    h = fmaf(cC[idx], h, cV[idx]);
  }
}

__global__ void scan_p3(const unsigned short* __restrict__ hg, const float* __restrict__ hin,
                        unsigned short* __restrict__ hout, void* __restrict__ nh, long nhOff,
                        float* __restrict__ hcarry, int chTot, int SL, int CHNp,
                        int writeNh, const int* __restrict__ flagp) {
  const int e = threadIdx.x, bh = blockIdx.y, cid = blockIdx.x;
  const int bL = bh >> 2, hh = bh & 3;
  const long tok = (long)bL * SL + (long)cid * CHLEN;
  long base  = tok * 3072 + hh * 768 + e;
  long obase = tok * 1536 + hh * 384 + e;
  float h = hin[cid * chTot + bh * 384 + e];
  for (int i = 0; i < CHLEN; i++) {
    const float hid = bf2f(hg[base]), gt = bf2f(hg[base + 384]);
    float c, sg; cv_compute(gt, c, sg);
    h = fmaf(c, h, sg * gfun(hid));
    hout[obase] = f2bf(h);
    base += 3072; obase += 1536;
  }
  if (cid == CHNp - 1) {
    hcarry[bh * 384 + e] = h;
    if (writeNh) stout(nh, nhOff + bL * 1536 + hh * 384 + e, *flagp, h);
  }
}

// ---------------- weight conversion -------------------------------------------
__global__ void cvt_k(const void* __restrict__ in, unsigned short* __restrict__ out,
                      int n, const int* __restrict__ flagp) {
  const int i = blockIdx.x * 256 + threadIdx.x;
  if (i < n) out[i] = f2bf(ldin(in, i, *flagp));
}

// ---------------- LDS-tiled coalesced transpose -------------------------------
// out[(z*NRz + nb + r)*LDO + k0 + kx] = in[(z*NKz + k0 + kx)*LDI + nb + r]
// (zero when src k >= KV). Block = 16 out-rows x 64 out-cols.
// Read: 16 consecutive lanes read 16 consecutive f32/bf16 (64B segments).
// Write: 64 consecutive lanes write 128B contiguous bf16.
// LDS stride 17 -> <=2-way bank aliasing both phases (free).
__global__ void tr_tile(const void* __restrict__ in, unsigned short* __restrict__ out,
                        int LDI, int NKz, int LDO, int NRz, int KV,
                        const int* __restrict__ flagp) {
  __shared__ float tile[64][17];
  const int f32m = *flagp;
  const int k0 = blockIdx.x * 64;
  const int nb = blockIdx.y * 16;
  const int z  = blockIdx.z;
  const int t  = threadIdx.x;
  const int c  = t & 15;     // n offset (contiguous in src)
  const int kl = t >> 4;     // 0..15
#pragma unroll
  for (int j = 0; j < 4; j++) {
    const int k = k0 + j * 16 + kl;
    tile[j * 16 + kl][c] =
        (k < KV) ? ldin(in, ((long)z * NKz + k) * (long)LDI + nb + c, f32m) : 0.f;
  }
  __syncthreads();
  const int kx = t & 63;
  const int rr = t >> 6;     // 0..3
#pragma unroll
  for (int j = 0; j < 4; j++) {
    const int r = j * 4 + rr;
    out[((long)z * NRz + nb + r) * (long)LDO + k0 + kx] = f2bf(tile[kx][r]);
  }
}

// interleaved gate/value transpose, tiled. Out row R (R<5632): tile=R>>8,
// pair=(R&255)>>5, sel=(R>>4)&1, col=tile*128+pair*16+(R&15). A 16-aligned
// R-group shares {tile,pair,sel} and spans cols colb..colb+15 -> same tile
// scheme as tr_tile with the group's source selected per block.
__global__ void tr_wgv_t(const void* __restrict__ wg, const void* __restrict__ wv,
                         unsigned short* __restrict__ out, const int* __restrict__ flagp) {
  __shared__ float tile[64][17];
  const int f32m = *flagp;
  const int k0 = blockIdx.x * 64;   // 16 chunks (k < 1024)
  const int Rb = blockIdx.y * 16;   // 352 groups (R < 5632)
  const int tIdx = Rb >> 8;
  const int rb8  = Rb & 255;
  const int pair = rb8 >> 5, sel = (rb8 >> 4) & 1;
  const int colb = tIdx * 128 + pair * 16;
  const void* src = sel ? wv : wg;
  const int t  = threadIdx.x;
  const int c  = t & 15;
  const int kl = t >> 4;
#pragma unroll
  for (int j = 0; j < 4; j++) {
    const int k   = k0 + j * 16 + kl;
    const int col = colb + c;
    tile[j * 16 + kl][c] = (col < FFN) ? ldin(src, (long)k * FFN + col, f32m) : 0.f;
  }
  __syncthreads();
  const int kx = t & 63;
  const int rr = t >> 6;
#pragma unroll
  for (int j = 0; j < 4; j++) {
    const int r = j * 4 + rr;
    out[(long)(Rb + r) * 1024 + k0 + kx] = f2bf(tile[kx][r]);
  }
}

// scalar fallback transpose for the small-MT path (W as [N][K] w/ zero pad)
__global__ void tr_wg(const void* __restrict__ in, unsigned short* __restrict__ out,
                      const int* __restrict__ flagp) {
  const int idx = blockIdx.x * 256 + threadIdx.x;  // n*1024+k, n<2816
  const int k = idx & 1023, n = idx >> 10;
  out[idx] = (n < FFN) ? f2bf(ldin(in, (long)k * FFN + n, *flagp)) : (unsigned short)0;
}

// ---------------- launch ------------------------------------------------------
extern "C" void kernel_launch(void* const* d_in, const int* in_sizes, int n_in,
                              void* d_out, int out_size, void* d_ws, size_t ws_size,
                              hipStream_t stream) {
  const void* x      = d_in[0];
  const void* dw_w   = d_in[1];
  const void* dw_b   = d_in[2];
  const void* pw_w   = d_in[3];  // [N=1024][K=1024] already
  const void* pw_b   = d_in[4];
  const void* conv_g = d_in[5];
  const void* gru_g  = d_in[6];
  const void* ff_g   = d_in[7];
  const void* w_hg   = d_in[8];
  const void* w_out  = d_in[9];
  const void* w_gate = d_in[10];
  const void* w_val  = d_in[11];
  const void* w_ffo  = d_in[12];

  // Pass size from ws_size (deterministic): need(MT) = 21,795,072 + MT*13,888.
  const long FIXED = 21795072L;
  int MT = 128;
  if      (ws_size >= (size_t)(FIXED + 16384L * 13888)) MT = 16384;
  else if (ws_size >= (size_t)(FIXED + 8192L * 13888))  MT = 8192;
  else if (ws_size >= (size_t)(FIXED + 4096L * 13888))  MT = 4096;
  else if (ws_size >= (size_t)(FIXED + 2048L * 13888))  MT = 2048;
  else if (ws_size >= (size_t)(FIXED + 1024L * 13888))  MT = 1024;
  else if (ws_size >= (size_t)(FIXED + 512L * 13888))   MT = 512;
  else if (ws_size >= (size_t)(FIXED + 256L * 13888))   MT = 256;

  const int SL    = (MT >= SEQL) ? SEQL : MT;
  const int nSeq  = MT / SL;
  const int CHNp  = SL / CHLEN;
  const int chTot = nSeq * 1536;
  const int big   = (MT >= 256);  // 256^2 16-wave path for the two FF GEMMs

  char* p = (char*)d_ws;
  unsigned short* whgT  = (unsigned short*)p; p += 1572864;
  unsigned short* woutT = (unsigned short*)p; p += 786432;
  unsigned short* wgT   = (unsigned short*)p; p += 5767168;
  unsigned short* wvT   = (unsigned short*)p; p += 5767168;
  unsigned short* wfoT  = (unsigned short*)p; p += 5767168;
  unsigned short* pwT   = (unsigned short*)p; p += 2097152;
  unsigned short* dwwB  = (unsigned short*)p; p += 8192;
  unsigned short* dwbB  = (unsigned short*)p; p += 2048;
  unsigned short* pwbB  = (unsigned short*)p; p += 2048;
  unsigned short* cgB   = (unsigned short*)p; p += 2048;
  unsigned short* ggB   = (unsigned short*)p; p += 2048;
  unsigned short* fgB   = (unsigned short*)p; p += 2048;
  int*            flag  = (int*)p;            p += 256;
  float*          hcarry= (float*)p;          p += 12288;
  float*          cC    = (float*)p;          p += (long)MT * 192;
  float*          cV    = (float*)p;          p += (long)MT * 192;
  float*          hin   = (float*)p;          p += (long)MT * 192;
  unsigned short* xnb   = (unsigned short*)p; p += 6144 + (long)MT * 2048;
  unsigned short* xc    = (unsigned short*)p; p += (long)MT * 2048;
  unsigned short* hbuf  = (unsigned short*)p; p += (long)MT * 3072;
  unsigned short* ybuf  = (unsigned short*)p;  // region R: ybuf / hg / ffin
  unsigned short* hg    = (unsigned short*)p;
  unsigned short* ffin  = (unsigned short*)p;
  unsigned short* xn    = xnb + 3 * DM;
  unsigned short* wgvT  = wgT;  // interleaved [5632][1024] spans wgT+wvT slots

  // dtype detection + weight conversion (once per call)
  detect_k<<<1, 256, 0, stream>>>((const unsigned short*)x, flag);
  // whg: in (h*256+k)*768+n -> out (h*768+n)*256+k
  tr_tile<<<dim3(4, 48, 4), 256, 0, stream>>>(w_hg, whgT, 768, 256, 256, 768, 256, flag);
  // wout: in (h*384+k)*256+n -> out (h*256+n)*384+k
  tr_tile<<<dim3(6, 16, 4), 256, 0, stream>>>(w_out, woutT, 256, 384, 384, 256, 384, flag);
  if (big) {
    tr_wgv_t<<<dim3(16, 352), 256, 0, stream>>>(w_gate, w_val, wgvT, flag);
  } else {
    tr_wg<<<11264, 256, 0, stream>>>(w_gate, wgT, flag);
    tr_wg<<<11264, 256, 0, stream>>>(w_val, wvT, flag);
  }
  // wfo: in kk*DM+n (kk<FFN) -> out n*FFP+kk, zero pad kk>=FFN
  tr_tile<<<dim3(44, 64, 1), 256, 0, stream>>>(w_ffo, wfoT, DM, FFP, FFP, DM, FFN, flag);
  cvt_k<<<4096, 256, 0, stream>>>(pw_w, pwT, 1048576, flag);
  cvt_k<<<16, 256, 0, stream>>>(dw_w, dwwB, 4096, flag);
  cvt_k<<<4, 256, 0, stream>>>(dw_b, dwbB, 1024, flag);
  cvt_k<<<4, 256, 0, stream>>>(pw_b, pwbB, 1024, flag);
  cvt_k<<<4, 256, 0, stream>>>(conv_g, cgB, 1024, flag);
  cvt_k<<<4, 256, 0, stream>>>(gru_g, ggB, 1024, flag);
  cvt_k<<<4, 256, 0, stream>>>(ff_g, fgB, 1024, flag);

  for (long t0 = 0; t0 < 16384; t0 += MT) {
    const int l0     = (int)(t0 & (SEQL - 1));
    const int P      = (l0 > 0) ? 3 : 0;
    const int seqEnd = (l0 + SL == SEQL);
    const long nhOff = NH_OFF + (t0 / SEQL) * 1536;

    // conv block: xc = pw(dwconv(rmsnorm(x))) + pw_b + x
    rmsnorm_x<<<MT + P, 64, 0, stream>>>(x, (t0 - P) * DM, cgB, xn - (long)P * DM, flag);
    dwconv_k<<<dim3(MT, 4), 256, 0, stream>>>(xn, dwwB, dwbB, ybuf, l0);
    gemm_bf16<1><<<dim3(8, MT / 128, 1), 256, 0, stream>>>(ybuf, DM, 0, pwT, 0, DM,
        xc, DM, 0, 0L, pwbB, x, DM, t0 * DM, flag);

    // GRU block
    rmsnorm_k<<<MT, 64, 0, stream>>>(xc, ggB, xn);
    gemm_bf16<0><<<dim3(6, MT / 128, 4), 256, 0, stream>>>(xn, DM, 256, whgT, 196608, 256,
        hg, 3072, 768, 0L, nullptr, nullptr, 0, 0L, nullptr);
    scan_p1<<<dim3(CHNp, nSeq * 4), 384, 0, stream>>>(hg, cC, cV, chTot, SL);
    scan_p2<<<nSeq * 4, 384, 0, stream>>>(cC, cV, hin, chTot, CHNp, hcarry, l0 > 0);
    scan_p3<<<dim3(CHNp, nSeq * 4), 384, 0, stream>>>(hg, hin, hbuf, d_out, nhOff,
        hcarry, chTot, SL, CHNp, seqEnd, flag);
    gemm_bf16<2><<<dim3(2, MT / 128, 4), 256, 0, stream>>>(hbuf, 1536, 384, woutT, 98304, 384,
        xc, DM, 256, 0L, nullptr, xc, DM, 0L, nullptr);

    // FF block
    rmsnorm_k<<<MT, 64, 0, stream>>>(xc, fgB, xn);
    if (big) {
      gemm256<0><<<dim3(22, MT / 256), 1024, 0, stream>>>(xn, wgvT, DM,
          ffin, nullptr, 0L, nullptr);
      gemm256<1><<<dim3(4, MT / 256), 1024, 0, stream>>>(ffin, wfoT, FFP,
          d_out, xc, t0 * DM, flag);
    } else {
      gemm_ff<<<dim3(22, MT / 128), 256, 0, stream>>>(xn, wgT, wvT, ffin);
      gemm_bf16<3><<<dim3(8, MT / 128, 1), 256, 0, stream>>>(ffin, FFP, 0, wfoT, 0, FFP,
          d_out, DM, 0, t0 * DM, nullptr, xc, DM, 0L, flag);
    }
  }
}

// Round 11
// 913.209 us; speedup vs baseline: 4.0817x; 1.0285x over previous
//
#include <hip/hip_runtime.h>
#include <stdint.h>

// MinGRUBlock on MI355X (gfx950). Input/output dtype (f32 vs bf16) DETECTED at
// runtime from x's bit patterns (flag in ws). Internals bf16. Residual in ws.
// Small GEMMs: mfma_f32_16x16x32_bf16, 128x128 tile, BK=64, global_load_lds
// w=16, XOR-swizzled LDS, K as TEMPLATE param (compile-time strides).
// Big GEMMs (FF gate/value and FF out): 256x256 tile, 16 waves (1024 thr,
// 4 waves/SIMD), per-wave 64x64, acc 64 AGPR + 32 VGPR frag peak, BK=64,
// dbuf 128 KiB LDS, chunk-XOR swizzle, stage-into-dead-buffer + vmcnt(0)
// publish. K templated (round-11: runtime-K addressing was the residual
// spill source at the exact-128-reg budget; WRITE_SIZE 135 vs 90 MB).
// Weight-prep transposes: LDS-tiled coalesced. scan/dwconv: ushort2-vectorized.
// Scan: 3-phase chunked, h_t = sigmoid(-g)*h + sigmoid(g)*gfun(hid), f32 carry.

#define DM     1024
#define SEQL   4096
#define FFN    2730
#define FFP    2816
#define NH_OFF 16777216L
#define CHLEN  128

using bf16x8 = __attribute__((ext_vector_type(8))) short;
using f32x4  = __attribute__((ext_vector_type(4))) float;

__device__ __forceinline__ float bf2f(unsigned short h) {
  union { unsigned int u; float f; } v; v.u = ((unsigned int)h) << 16; return v.f;
}
__device__ __forceinline__ unsigned short f2bf(float f) {
  union { float f; unsigned int u; } v; v.f = f;
  unsigned int u = v.u;
  return (unsigned short)((u + 0x7fffu + ((u >> 16) & 1u)) >> 16);
}
__device__ __forceinline__ float bf2f_lo(unsigned int u2) {
  union { unsigned int u; float f; } v; v.u = u2 << 16; return v.f;
}
__device__ __forceinline__ float bf2f_hi(unsigned int u2) {
  union { unsigned int u; float f; } v; v.u = u2 & 0xffff0000u; return v.f;
}
__device__ __forceinline__ unsigned int pack2(float a, float b) {
  return (unsigned int)f2bf(a) | ((unsigned int)f2bf(b) << 16);
}
__device__ __forceinline__ float ldin(const void* p, long i, int f32mode) {
  return f32mode ? ((const float*)p)[i] : bf2f(((const unsigned short*)p)[i]);
}
__device__ __forceinline__ void stout(void* p, long i, int f32mode, float v) {
  if (f32mode) ((float*)p)[i] = v; else ((unsigned short*)p)[i] = f2bf(v);
}
__device__ __forceinline__ void gload_lds16(const unsigned short* g, unsigned short* lds) {
  __builtin_amdgcn_global_load_lds(
      (const __attribute__((address_space(1))) unsigned int*)g,
      (__attribute__((address_space(3))) unsigned int*)lds,
      16, 0, 0);
}

// ---------------- dtype detection --------------------------------------------
__global__ void detect_k(const unsigned short* __restrict__ x, int* __restrict__ flag) {
  __shared__ int cnt;
  if (threadIdx.x == 0) cnt = 0;
  __syncthreads();
  int c = 0;
  for (int j = 0; j < 4; j++) {
    unsigned short v = x[2 * (threadIdx.x * 4 + j)];
    int ex = (v >> 7) & 0xFF;
    if (ex >= 0x84) c++;
  }
  atomicAdd(&cnt, c);
  __syncthreads();
  if (threadIdx.x == 0) *flag = (cnt >= 32) ? 1 : 0;
}

// ---------------- GEMM: C[M,N] = A[M,K] * B^T  (B stored [N][K], ldb=K) -------
// K compile-time. EPI 0: bf16 plain. EPI 1: bf16 = acc + bias[col] + raw_res.
// EPI 2: bf16 = acc + bf16res. EPI 3: raw_out (flag) = acc + bf16res.
template <int EPI, int K>
__launch_bounds__(256)
__global__ void gemm_bf16(const unsigned short* __restrict__ A, int lda, int aOffZ,
                          const unsigned short* __restrict__ Bm, int bOffZ,
                          void* __restrict__ Cout, int ldc, int cOffZ, long outOff,
                          const unsigned short* __restrict__ bias,
                          const void* __restrict__ res, int ldres, long resOff,
                          const int* __restrict__ flagp) {
  __shared__ __align__(16) unsigned short As[128][64];
  __shared__ __align__(16) unsigned short Bs[128][64];

  const int tid  = threadIdx.x;
  const int w    = tid >> 6;
  const int lane = tid & 63;
  const int z    = blockIdx.z;
  const long tm  = (long)blockIdx.y * 128;
  const long tn  = (long)blockIdx.x * 128;

  const unsigned short* Ag = A + (long)z * aOffZ;
  const unsigned short* Bg = Bm + (long)z * bOffZ;

  f32x4 acc[4][4];
#pragma unroll
  for (int i = 0; i < 4; i++)
#pragma unroll
    for (int j = 0; j < 4; j++) acc[i][j] = (f32x4){0.f, 0.f, 0.f, 0.f};

  const int wrow = w * 32;
  const int srow = lane >> 3;                    // 0..7
  const int scol = (((lane & 7) ^ srow) * 8);    // xor-swizzled source chunk
  const int wm   = (w >> 1) * 64;
  const int wn   = (w & 1) * 64;
  const int quad = lane >> 4;
  const int lo   = lane & 15;
  const int sw   = lo & 7;                       // row-based xor key for reads

  for (int k0 = 0; k0 < K; k0 += 64) {
    __syncthreads();
#pragma unroll
    for (int i = 0; i < 4; i++) {
      const int r = wrow + i * 8;  // wave-uniform LDS base
      gload_lds16(Ag + (tm + r + srow) * (long)lda + k0 + scol, &As[r][0]);
      gload_lds16(Bg + (tn + r + srow) * (long)K + k0 + scol, &Bs[r][0]);
    }
    __syncthreads();
#pragma unroll
    for (int kk = 0; kk < 64; kk += 32) {
      const int kc = kk >> 3;  // 0 or 4
      bf16x8 af[4], bfr[4];
#pragma unroll
      for (int mt = 0; mt < 4; mt++)
        af[mt] = *(const bf16x8*)&As[wm + mt * 16 + lo][((quad + kc) ^ sw) * 8];
#pragma unroll
      for (int nt = 0; nt < 4; nt++)
        bfr[nt] = *(const bf16x8*)&Bs[wn + nt * 16 + lo][((quad + kc) ^ sw) * 8];
#pragma unroll
      for (int mt = 0; mt < 4; mt++)
#pragma unroll
        for (int nt = 0; nt < 4; nt++)
          acc[mt][nt] = __builtin_amdgcn_mfma_f32_16x16x32_bf16(af[mt], bfr[nt], acc[mt][nt], 0, 0, 0);
    }
  }

  const int f32m = (EPI == 1 || EPI == 3) ? *flagp : 0;
#pragma unroll
  for (int mt = 0; mt < 4; mt++) {
#pragma unroll
    for (int nt = 0; nt < 4; nt++) {
#pragma unroll
      for (int r = 0; r < 4; r++) {
        const long grow = tm + wm + mt * 16 + quad * 4 + r;
        const long gcol = tn + wn + nt * 16 + lo;
        float v         = acc[mt][nt][r];
        if (EPI == 0) {
          ((unsigned short*)Cout + (long)z * cOffZ)[grow * (long)ldc + gcol] = f2bf(v);
        } else if (EPI == 1) {
          v += bf2f(bias[gcol]) + ldin(res, resOff + grow * (long)ldres + gcol, f32m);
          ((unsigned short*)Cout)[grow * (long)ldc + gcol] = f2bf(v);
        } else if (EPI == 2) {
          v += bf2f(((const unsigned short*)res + (long)z * cOffZ)[grow * (long)ldres + gcol]);
          ((unsigned short*)Cout + (long)z * cOffZ)[grow * (long)ldc + gcol] = f2bf(v);
        } else {  // EPI == 3: final output
          v += bf2f(((const unsigned short*)res)[grow * (long)ldres + gcol]);
          stout(Cout, outOff + grow * (long)ldc + gcol, f32m, v);
        }
      }
    }
  }
}

// ---------------- fused FF GEMM (legacy 128^2 path, used when MT<256) ---------
__launch_bounds__(256)
__global__ void gemm_ff(const unsigned short* __restrict__ A,
                        const unsigned short* __restrict__ Bgm,
                        const unsigned short* __restrict__ Bvm,
                        unsigned short* __restrict__ Cout) {
  __shared__ __align__(16) unsigned short As[128][64];
  __shared__ __align__(16) unsigned short Bgs[128][64];
  __shared__ __align__(16) unsigned short Bvs[128][64];

  const int tid  = threadIdx.x;
  const int w    = tid >> 6;
  const int lane = tid & 63;
  const long tm  = (long)blockIdx.y * 128;
  const long tn  = (long)blockIdx.x * 128;

  f32x4 accG[4][4], accV[4][4];
#pragma unroll
  for (int i = 0; i < 4; i++)
#pragma unroll
    for (int j = 0; j < 4; j++) {
      accG[i][j] = (f32x4){0.f, 0.f, 0.f, 0.f};
      accV[i][j] = (f32x4){0.f, 0.f, 0.f, 0.f};
    }

  const int wrow = w * 32;
  const int srow = lane >> 3;
  const int scol = (((lane & 7) ^ srow) * 8);
  const int wm   = (w >> 1) * 64;
  const int wn   = (w & 1) * 64;
  const int quad = lane >> 4;
  const int lo   = lane & 15;
  const int sw   = lo & 7;

  for (int k0 = 0; k0 < DM; k0 += 64) {
    __syncthreads();
#pragma unroll
    for (int i = 0; i < 4; i++) {
      const int r = wrow + i * 8;
      gload_lds16(A + (tm + r + srow) * (long)DM + k0 + scol, &As[r][0]);
      gload_lds16(Bgm + (tn + r + srow) * (long)DM + k0 + scol, &Bgs[r][0]);
      gload_lds16(Bvm + (tn + r + srow) * (long)DM + k0 + scol, &Bvs[r][0]);
    }
    __syncthreads();
#pragma unroll
    for (int kk = 0; kk < 64; kk += 32) {
      const int kc = kk >> 3;
      bf16x8 af[4], bfr[4];
#pragma unroll
      for (int mt = 0; mt < 4; mt++)
        af[mt] = *(const bf16x8*)&As[wm + mt * 16 + lo][((quad + kc) ^ sw) * 8];
#pragma unroll
      for (int nt = 0; nt < 4; nt++)
        bfr[nt] = *(const bf16x8*)&Bgs[wn + nt * 16 + lo][((quad + kc) ^ sw) * 8];
#pragma unroll
      for (int mt = 0; mt < 4; mt++)
#pragma unroll
        for (int nt = 0; nt < 4; nt++)
          accG[mt][nt] = __builtin_amdgcn_mfma_f32_16x16x32_bf16(af[mt], bfr[nt], accG[mt][nt], 0, 0, 0);
#pragma unroll
      for (int nt = 0; nt < 4; nt++)
        bfr[nt] = *(const bf16x8*)&Bvs[wn + nt * 16 + lo][((quad + kc) ^ sw) * 8];
#pragma unroll
      for (int mt = 0; mt < 4; mt++)
#pragma unroll
        for (int nt = 0; nt < 4; nt++)
          accV[mt][nt] = __builtin_amdgcn_mfma_f32_16x16x32_bf16(af[mt], bfr[nt], accV[mt][nt], 0, 0, 0);
    }
  }

#pragma unroll
  for (int mt = 0; mt < 4; mt++) {
#pragma unroll
    for (int nt = 0; nt < 4; nt++) {
#pragma unroll
      for (int r = 0; r < 4; r++) {
        const long grow = tm + wm + mt * 16 + quad * 4 + r;
        const long gcol = tn + wn + nt * 16 + lo;
        const float g   = accG[mt][nt][r];
        const float s   = g / (1.f + __expf(-g));
        Cout[grow * (long)FFP + gcol] = f2bf(s * accV[mt][nt][r]);
      }
    }
  }
}

// ---------------- 256^2 GEMM, 16 waves, 4 waves/SIMD, K compile-time ---------
// (round-9 structure + templated K: constant strides free addressing regs at
// the exact-128 budget -> expect spill WRITE_SIZE 135->90 MB)
template <int EPI, int K>
__launch_bounds__(1024, 4)
__global__ void gemm256(const unsigned short* __restrict__ A,
                        const unsigned short* __restrict__ Bm,
                        void* __restrict__ Cout,
                        const unsigned short* __restrict__ res,
                        long outOff,
                        const int* __restrict__ flagp) {
  __shared__ __align__(16) unsigned short As[2][256][64];
  __shared__ __align__(16) unsigned short Bs[2][256][64];

  const int tid  = threadIdx.x;
  const int w    = tid >> 6;      // 0..15
  const int lane = tid & 63;
  const int wr   = w >> 2;        // 0..3  (M band of 64)
  const int wc   = w & 3;         // 0..3  (N band of 64)
  const int quad = lane >> 4;
  const int lo   = lane & 15;
  const int sw   = lo & 7;

  // bijective XCD-aware block swizzle (m204 formula)
  const int gx  = gridDim.x;
  int bid       = blockIdx.y * gx + blockIdx.x;
  const int nwg = gx * gridDim.y;
  {
    const int q = nwg >> 3, r8 = nwg & 7;
    const int xc8 = bid & 7, j = bid >> 3;
    bid = (xc8 < r8 ? xc8 * (q + 1) : r8 * (q + 1) + (xc8 - r8) * q) + j;
  }
  const long tn = (long)(bid % gx) * 256;  // B-row tile base
  const long tm = (long)(bid / gx) * 256;  // M tile base

  constexpr int NT = K >> 6;  // 16 (K=1024) or 44 (K=2816); even >= 4

  // staging source addressing: per-lane swizzled global address, linear LDS.
  const int srow = lane >> 3;                 // 0..7
  const int sch  = (lane & 7) ^ srow;         // source chunk = pos ^ key(row)
  const unsigned short* Ab = A + (tm + (long)w * 16 + srow) * (long)K + sch * 8;
  const unsigned short* Bb = Bm + (tn + (long)w * 16 + srow) * (long)K + sch * 8;

#define STAGE_A(BUF, TT)                                                          \
  gload_lds16(Ab + (long)(TT) * 64, &As[BUF][w * 16][0]);                         \
  gload_lds16(Ab + 8L * K + (long)(TT) * 64, &As[BUF][w * 16 + 8][0]);
#define STAGE_B(BUF, TT)                                                          \
  gload_lds16(Bb + (long)(TT) * 64, &Bs[BUF][w * 16][0]);                         \
  gload_lds16(Bb + 8L * K + (long)(TT) * 64, &Bs[BUF][w * 16 + 8][0]);

  // prologue: tile 0 only (tile 1 staged during tile 0)
  STAGE_B(0, 0)
  STAGE_A(0, 0)

  f32x4 acc[4][4];
#pragma unroll
  for (int i = 0; i < 4; i++)
#pragma unroll
    for (int j = 0; j < 4; j++) acc[i][j] = (f32x4){0.f, 0.f, 0.f, 0.f};

  asm volatile("s_waitcnt vmcnt(0)" ::: "memory");
  __builtin_amdgcn_s_barrier();

  bf16x8 a[2][2], b[2][2];

#define LDA2(CBUF, RB)                                                            \
  _Pragma("unroll") for (int m = 0; m < 2; m++) {                                 \
    _Pragma("unroll") for (int c = 0; c < 2; c++) {                               \
      a[m][c] = *(const bf16x8*)&As[CBUF][wr * 64 + ((RB) + m) * 16 + lo]         \
                                       [((quad + 4 * c) ^ sw) * 8];               \
    }                                                                             \
  }
#define LDB2(CBUF, NB)                                                            \
  _Pragma("unroll") for (int n = 0; n < 2; n++) {                                 \
    _Pragma("unroll") for (int c = 0; c < 2; c++) {                               \
      b[n][c] = *(const bf16x8*)&Bs[CBUF][wc * 64 + ((NB) + n) * 16 + lo]         \
                                       [((quad + 4 * c) ^ sw) * 8];               \
    }                                                                             \
  }
#define MFMA_Q(MB, NB)                                                            \
  __builtin_amdgcn_s_setprio(1);                                                  \
  _Pragma("unroll") for (int m = 0; m < 2; m++) {                                 \
    _Pragma("unroll") for (int n = 0; n < 2; n++) {                               \
      _Pragma("unroll") for (int c = 0; c < 2; c++) {                             \
        acc[(MB) + m][(NB) + n] = __builtin_amdgcn_mfma_f32_16x16x32_bf16(        \
            a[m][c], b[n][c], acc[(MB) + m][(NB) + n], 0, 0, 0);                  \
      }                                                                           \
    }                                                                             \
  }                                                                               \
  __builtin_amdgcn_s_setprio(0);

// One sub-tile. STG: stage tile TT+1 into CBUF^1 (holds dead tile TT-1).
#define SUBTILE(CBUF, TT, STG)                                                    \
  {                                                                               \
    /* P0: aL + b01; stage B(TT+1); MFMA Q0 = mLo x nLo */                        \
    LDA2(CBUF, 0);                                                                \
    LDB2(CBUF, 0);                                                                \
    if (STG) { STAGE_B(CBUF ^ 1, (TT) + 1) }                                      \
    MFMA_Q(0, 0);                                                                 \
    __builtin_amdgcn_s_barrier();                                                 \
    /* P1: b23 (b01 consumed); stage A(TT+1); MFMA Q1 = mLo x nHi */              \
    LDB2(CBUF, 2);                                                                \
    if (STG) { STAGE_A(CBUF ^ 1, (TT) + 1) }                                      \
    MFMA_Q(0, 2);                                                                 \
    __builtin_amdgcn_s_barrier();                                                 \
    /* P2: aH (aL consumed); MFMA Q2 = mHi x nHi */                               \
    LDA2(CBUF, 2);                                                                \
    MFMA_Q(2, 2);                                                                 \
    __builtin_amdgcn_s_barrier();                                                 \
    /* P3: re-read b01; MFMA Q3 = mHi x nLo; publish staged tile */               \
    LDB2(CBUF, 0);                                                                \
    MFMA_Q(2, 0);                                                                 \
    if (STG) asm volatile("s_waitcnt vmcnt(0)" ::: "memory");                     \
    __builtin_amdgcn_s_barrier();                                                 \
  }

  // main loop: tiles 0..NT-2 stage their successor; tile NT-1 stages nothing
  for (int t = 0; t < NT - 2; t += 2) {
    SUBTILE(0, t, 1)
    SUBTILE(1, t + 1, 1)
  }
  SUBTILE(0, NT - 2, 1)
  SUBTILE(1, NT - 1, 0)

  if (EPI == 0) {
    // silu(gate) * value, lane-local pairing; ffin col base = tn/2
    const long colb = (tn >> 1);
    const long rowb = tm + wr * 64;
#pragma unroll
    for (int m = 0; m < 4; m++) {
#pragma unroll
      for (int np = 0; np < 2; np++) {
        const long col = colb + (wc * 2 + np) * 16 + lo;
#pragma unroll
        for (int r = 0; r < 4; r++) {
          const long row = rowb + m * 16 + quad * 4 + r;
          const float g  = acc[m][2 * np][r];
          const float v  = acc[m][2 * np + 1][r];
          const float s  = g / (1.f + __expf(-g));
          ((unsigned short*)Cout)[row * (long)FFP + col] = f2bf(s * v);
        }
      }
    }
  } else {
    const int f32m = *flagp;
    const long rowb = tm + wr * 64;
    const long colb = tn + wc * 64;
#pragma unroll
    for (int m = 0; m < 4; m++) {
#pragma unroll
      for (int n = 0; n < 4; n++) {
#pragma unroll
        for (int r = 0; r < 4; r++) {
          const long row = rowb + m * 16 + quad * 4 + r;
          const long col = colb + n * 16 + lo;
          float v = acc[m][n][r] + bf2f(res[row * (long)DM + col]);
          stout(Cout, outOff + row * (long)DM + col, f32m, v);
        }
      }
    }
  }
#undef STAGE_A
#undef STAGE_B
#undef LDA2
#undef LDB2
#undef MFMA_Q
#undef SUBTILE
}

// ---------------- RMSNorm: raw input variant (flag) --------------------------
__global__ void rmsnorm_x(const void* __restrict__ in, long elemOff,
                          const unsigned short* __restrict__ gamma,
                          unsigned short* __restrict__ out,
                          const int* __restrict__ flagp) {
  const int t    = blockIdx.x;
  const int lane = threadIdx.x;
  const int f32m = *flagp;
  float v[16];
  const long base = elemOff + (long)t * DM;
  if (f32m) {
    const float4* rp = (const float4*)((const float*)in + base);
#pragma unroll
    for (int j = 0; j < 4; j++) {
      float4 u     = rp[j * 64 + lane];
      v[j * 4 + 0] = u.x; v[j * 4 + 1] = u.y; v[j * 4 + 2] = u.z; v[j * 4 + 3] = u.w;
    }
  } else {
    const ushort4* rp = (const ushort4*)((const unsigned short*)in + base);
#pragma unroll
    for (int j = 0; j < 4; j++) {
      ushort4 u    = rp[j * 64 + lane];
      v[j * 4 + 0] = bf2f(u.x); v[j * 4 + 1] = bf2f(u.y);
      v[j * 4 + 2] = bf2f(u.z); v[j * 4 + 3] = bf2f(u.w);
    }
  }
  float s = 0.f;
#pragma unroll
  for (int i = 0; i < 16; i++) s = fmaf(v[i], v[i], s);
#pragma unroll
  for (int off = 32; off > 0; off >>= 1) s += __shfl_xor(s, off, 64);
  const float scale = 32.f / fmaxf(sqrtf(s), 1e-12f);
  ushort4* op       = (ushort4*)(out + (long)t * DM);
  const ushort4* gp = (const ushort4*)gamma;
#pragma unroll
  for (int j = 0; j < 4; j++) {
    ushort4 g = gp[j * 64 + lane];
    ushort4 o;
    o.x = f2bf(v[j * 4 + 0] * scale * (bf2f(g.x) + 1.f));
    o.y = f2bf(v[j * 4 + 1] * scale * (bf2f(g.y) + 1.f));
    o.z = f2bf(v[j * 4 + 2] * scale * (bf2f(g.z) + 1.f));
    o.w = f2bf(v[j * 4 + 3] * scale * (bf2f(g.w) + 1.f));
    op[j * 64 + lane] = o;
  }
}

// ---------------- RMSNorm (bf16 in/out) --------------------------------------
__global__ void rmsnorm_k(const unsigned short* __restrict__ in,
                          const unsigned short* __restrict__ gamma,
                          unsigned short* __restrict__ out) {
  const int t    = blockIdx.x;
  const int lane = threadIdx.x;
  float v[16];
  const ushort4* rp = (const ushort4*)(in + (long)t * DM);
#pragma unroll
  for (int j = 0; j < 4; j++) {
    ushort4 u    = rp[j * 64 + lane];
    v[j * 4 + 0] = bf2f(u.x); v[j * 4 + 1] = bf2f(u.y);
    v[j * 4 + 2] = bf2f(u.z); v[j * 4 + 3] = bf2f(u.w);
  }
  float s = 0.f;
#pragma unroll
  for (int i = 0; i < 16; i++) s = fmaf(v[i], v[i], s);
#pragma unroll
  for (int off = 32; off > 0; off >>= 1) s += __shfl_xor(s, off, 64);
  const float scale = 32.f / fmaxf(sqrtf(s), 1e-12f);
  ushort4* op       = (ushort4*)(out + (long)t * DM);
  const ushort4* gp = (const ushort4*)gamma;
#pragma unroll
  for (int j = 0; j < 4; j++) {
    ushort4 g = gp[j * 64 + lane];
    ushort4 o;
    o.x = f2bf(v[j * 4 + 0] * scale * (bf2f(g.x) + 1.f));
    o.y = f2bf(v[j * 4 + 1] * scale * (bf2f(g.y) + 1.f));
    o.z = f2bf(v[j * 4 + 2] * scale * (bf2f(g.z) + 1.f));
    o.w = f2bf(v[j * 4 + 3] * scale * (bf2f(g.w) + 1.f));
    op[j * 64 + lane] = o;
  }
}

// ---------------- causal depthwise conv K=4, ushort2-vectorized ---------------
__global__ void dwconv_k(const unsigned short* __restrict__ xn,
                         const unsigned short* __restrict__ dww,
                         const unsigned short* __restrict__ dwb,
                         unsigned short* __restrict__ y, int l0) {
  const int t  = blockIdx.x;
  const int d0 = blockIdx.y * 512 + threadIdx.x * 2;
  const int l  = l0 + (t & (SEQL - 1));
  ushort4 wa = ((const ushort4*)dww)[d0];
  ushort4 wb = ((const ushort4*)dww)[d0 + 1];
  float wk0[4] = {bf2f(wa.x), bf2f(wa.y), bf2f(wa.z), bf2f(wa.w)};
  float wk1[4] = {bf2f(wb.x), bf2f(wb.y), bf2f(wb.z), bf2f(wb.w)};
  unsigned int b2 = *(const unsigned int*)&dwb[d0];
  float acc0 = bf2f_lo(b2), acc1 = bf2f_hi(b2);
#pragma unroll
  for (int k = 0; k < 4; k++) {
    const int ll = l + k - 3;
    if (ll >= 0) {
      unsigned int x2 = *(const unsigned int*)&xn[(long)(t + k - 3) * DM + d0];
      acc0 = fmaf(bf2f_lo(x2), wk0[k], acc0);
      acc1 = fmaf(bf2f_hi(x2), wk1[k], acc1);
    }
  }
  *(unsigned int*)&y[(long)t * DM + d0] = pack2(acc0, acc1);
}

// ---------------- scan --------------------------------------------------------
__device__ __forceinline__ void cv_compute(float gt, float& c, float& sg) {
  gt = fminf(fmaxf(gt, -40.f), 40.f);
  const float e  = __expf(-fabsf(gt));
  const float r  = 1.f / (1.f + e);
  const float rs = e * r;
  c  = (gt >= 0.f) ? rs : r;   // sigmoid(-gt)
  sg = (gt >= 0.f) ? r : rs;   // sigmoid(gt)
}
__device__ __forceinline__ float gfun(float hid) {
  hid = fminf(fmaxf(hid, -40.f), 40.f);
  if (hid >= 0.f) return hid + 0.5f;
  const float e = __expf(hid);
  return e / (1.f + e);
}

// 192 threads, 2 channels/thread (ushort2 loads)
__global__ void scan_p1(const unsigned short* __restrict__ hg, float* __restrict__ cC,
                        float* __restrict__ cV, int chTot, int SL) {
  const int e0 = threadIdx.x * 2, bh = blockIdx.y, cid = blockIdx.x;
  const int bL = bh >> 2, hh = bh & 3;
  long base = ((long)(bL * SL + cid * CHLEN)) * 3072 + hh * 768 + e0;
  float C0 = 1.f, V0 = 0.f, C1 = 1.f, V1 = 0.f;
  for (int i = 0; i < CHLEN; i++) {
    const unsigned int h2 = *(const unsigned int*)&hg[base];
    const unsigned int g2 = *(const unsigned int*)&hg[base + 384];
    float c, sg;
    cv_compute(bf2f_lo(g2), c, sg);
    C0 *= c; V0 = fmaf(c, V0, sg * gfun(bf2f_lo(h2)));
    cv_compute(bf2f_hi(g2), c, sg);
    C1 *= c; V1 = fmaf(c, V1, sg * gfun(bf2f_hi(h2)));
    base += 3072;
  }
  const int idx = cid * chTot + bh * 384 + e0;
  cC[idx] = C0; cC[idx + 1] = C1;
  cV[idx] = V0; cV[idx + 1] = V1;
}

__global__ void scan_p2(const float* __restrict__ cC, const float* __restrict__ cV,
                        float* __restrict__ hin, int chTot, int CHNp,
                        const float* __restrict__ hcarry, int useCarry) {
  const int ch = blockIdx.x * 384 + threadIdx.x;
  float h = useCarry ? hcarry[ch] : 0.f;
  for (int cid = 0; cid < CHNp; cid++) {
    const int idx = cid * chTot + ch;
    hin[idx] = h;
    h = fmaf(cC[idx], h, cV[idx]);
  }
}

// 192 threads, 2 channels/thread
__global__ void scan_p3(const unsigned short* __restrict__ hg, const float* __restrict__ hin,
                        unsigned short* __restrict__ hout, void* __restrict__ nh, long nhOff,
                        float* __restrict__ hcarry, int chTot, int SL, int CHNp,
                        int writeNh, const int* __restrict__ flagp) {
  const int e0 = threadIdx.x * 2, bh = blockIdx.y, cid = blockIdx.x;
  const int bL = bh >> 2, hh = bh & 3;
  const long tok = (long)bL * SL + (long)cid * CHLEN;
  long base  = tok * 3072 + hh * 768 + e0;
  long obase = tok * 1536 + hh * 384 + e0;
  const int idx = cid * chTot + bh * 384 + e0;
  float h0 = hin[idx], h1 = hin[idx + 1];
  for (int i = 0; i < CHLEN; i++) {
    const unsigned int h2 = *(const unsigned int*)&hg[base];
    const unsigned int g2 = *(const unsigned int*)&hg[base + 384];
    float c, sg;
    cv_compute(bf2f_lo(g2), c, sg);
    h0 = fmaf(c, h0, sg * gfun(bf2f_lo(h2)));
    cv_compute(bf2f_hi(g2), c, sg);
    h1 = fmaf(c, h1, sg * gfun(bf2f_hi(h2)));
    *(unsigned int*)&hout[obase] = pack2(h0, h1);
    base += 3072; obase += 1536;
  }
  if (cid == CHNp - 1) {
    hcarry[bh * 384 + e0]     = h0;
    hcarry[bh * 384 + e0 + 1] = h1;
    if (writeNh) {
      const int f32m = *flagp;
      stout(nh, nhOff + bL * 1536 + hh * 384 + e0, f32m, h0);
      stout(nh, nhOff + bL * 1536 + hh * 384 + e0 + 1, f32m, h1);
    }
  }
}

// ---------------- weight conversion -------------------------------------------
__global__ void cvt_k(const void* __restrict__ in, unsigned short* __restrict__ out,
                      int n, const int* __restrict__ flagp) {
  const int i = blockIdx.x * 256 + threadIdx.x;
  if (i < n) out[i] = f2bf(ldin(in, i, *flagp));
}

// ---------------- LDS-tiled coalesced transpose -------------------------------
// out[(z*NRz + nb + r)*LDO + k0 + kx] = in[(z*NKz + k0 + kx)*LDI + nb + r]
// (zero when src k >= KV). Block = 16 out-rows x 64 out-cols.
__global__ void tr_tile(const void* __restrict__ in, unsigned short* __restrict__ out,
                        int LDI, int NKz, int LDO, int NRz, int KV,
                        const int* __restrict__ flagp) {
  __shared__ float tile[64][17];
  const int f32m = *flagp;
  const int k0 = blockIdx.x * 64;
  const int nb = blockIdx.y * 16;
  const int z  = blockIdx.z;
  const int t  = threadIdx.x;
  const int c  = t & 15;     // n offset (contiguous in src)
  const int kl = t >> 4;     // 0..15
#pragma unroll
  for (int j = 0; j < 4; j++) {
    const int k = k0 + j * 16 + kl;
    tile[j * 16 + kl][c] =
        (k < KV) ? ldin(in, ((long)z * NKz + k) * (long)LDI + nb + c, f32m) : 0.f;
  }
  __syncthreads();
  const int kx = t & 63;
  const int rr = t >> 6;     // 0..3
#pragma unroll
  for (int j = 0; j < 4; j++) {
    const int r = j * 4 + rr;
    out[((long)z * NRz + nb + r) * (long)LDO + k0 + kx] = f2bf(tile[kx][r]);
  }
}

// interleaved gate/value transpose, tiled (16-aligned R-groups share sel/colb)
__global__ void tr_wgv_t(const void* __restrict__ wg, const void* __restrict__ wv,
                         unsigned short* __restrict__ out, const int* __restrict__ flagp) {
  __shared__ float tile[64][17];
  const int f32m = *flagp;
  const int k0 = blockIdx.x * 64;   // 16 chunks (k < 1024)
  const int Rb = blockIdx.y * 16;   // 352 groups (R < 5632)
  const int tIdx = Rb >> 8;
  const int rb8  = Rb & 255;
  const int pair = rb8 >> 5, sel = (rb8 >> 4) & 1;
  const int colb = tIdx * 128 + pair * 16;
  const void* src = sel ? wv : wg;
  const int t  = threadIdx.x;
  const int c  = t & 15;
  const int kl = t >> 4;
#pragma unroll
  for (int j = 0; j < 4; j++) {
    const int k   = k0 + j * 16 + kl;
    const int col = colb + c;
    tile[j * 16 + kl][c] = (col < FFN) ? ldin(src, (long)k * FFN + col, f32m) : 0.f;
  }
  __syncthreads();
  const int kx = t & 63;
  const int rr = t >> 6;
#pragma unroll
  for (int j = 0; j < 4; j++) {
    const int r = j * 4 + rr;
    out[(long)(Rb + r) * 1024 + k0 + kx] = f2bf(tile[kx][r]);
  }
}

// scalar fallback transpose for the small-MT path (W as [N][K] w/ zero pad)
__global__ void tr_wg(const void* __restrict__ in, unsigned short* __restrict__ out,
                      const int* __restrict__ flagp) {
  const int idx = blockIdx.x * 256 + threadIdx.x;  // n*1024+k, n<2816
  const int k = idx & 1023, n = idx >> 10;
  out[idx] = (n < FFN) ? f2bf(ldin(in, (long)k * FFN + n, *flagp)) : (unsigned short)0;
}

// ---------------- launch ------------------------------------------------------
extern "C" void kernel_launch(void* const* d_in, const int* in_sizes, int n_in,
                              void* d_out, int out_size, void* d_ws, size_t ws_size,
                              hipStream_t stream) {
  const void* x      = d_in[0];
  const void* dw_w   = d_in[1];
  const void* dw_b   = d_in[2];
  const void* pw_w   = d_in[3];  // [N=1024][K=1024] already
  const void* pw_b   = d_in[4];
  const void* conv_g = d_in[5];
  const void* gru_g  = d_in[6];
  const void* ff_g   = d_in[7];
  const void* w_hg   = d_in[8];
  const void* w_out  = d_in[9];
  const void* w_gate = d_in[10];
  const void* w_val  = d_in[11];
  const void* w_ffo  = d_in[12];

  // Pass size from ws_size (deterministic): need(MT) = 21,795,072 + MT*13,888.
  const long FIXED = 21795072L;
  int MT = 128;
  if      (ws_size >= (size_t)(FIXED + 16384L * 13888)) MT = 16384;
  else if (ws_size >= (size_t)(FIXED + 8192L * 13888))  MT = 8192;
  else if (ws_size >= (size_t)(FIXED + 4096L * 13888))  MT = 4096;
  else if (ws_size >= (size_t)(FIXED + 2048L * 13888))  MT = 2048;
  else if (ws_size >= (size_t)(FIXED + 1024L * 13888))  MT = 1024;
  else if (ws_size >= (size_t)(FIXED + 512L * 13888))   MT = 512;
  else if (ws_size >= (size_t)(FIXED + 256L * 13888))   MT = 256;

  const int SL    = (MT >= SEQL) ? SEQL : MT;
  const int nSeq  = MT / SL;
  const int CHNp  = SL / CHLEN;
  const int chTot = nSeq * 1536;
  const int big   = (MT >= 256);  // 256^2 16-wave path for the two FF GEMMs

  char* p = (char*)d_ws;
  unsigned short* whgT  = (unsigned short*)p; p += 1572864;
  unsigned short* woutT = (unsigned short*)p; p += 786432;
  unsigned short* wgT   = (unsigned short*)p; p += 5767168;
  unsigned short* wvT   = (unsigned short*)p; p += 5767168;
  unsigned short* wfoT  = (unsigned short*)p; p += 5767168;
  unsigned short* pwT   = (unsigned short*)p; p += 2097152;
  unsigned short* dwwB  = (unsigned short*)p; p += 8192;
  unsigned short* dwbB  = (unsigned short*)p; p += 2048;
  unsigned short* pwbB  = (unsigned short*)p; p += 2048;
  unsigned short* cgB   = (unsigned short*)p; p += 2048;
  unsigned short* ggB   = (unsigned short*)p; p += 2048;
  unsigned short* fgB   = (unsigned short*)p; p += 2048;
  int*            flag  = (int*)p;            p += 256;
  float*          hcarry= (float*)p;          p += 12288;
  float*          cC    = (float*)p;          p += (long)MT * 192;
  float*          cV    = (float*)p;          p += (long)MT * 192;
  float*          hin   = (float*)p;          p += (long)MT * 192;
  unsigned short* xnb   = (unsigned short*)p; p += 6144 + (long)MT * 2048;
  unsigned short* xc    = (unsigned short*)p; p += (long)MT * 2048;
  unsigned short* hbuf  = (unsigned short*)p; p += (long)MT * 3072;
  unsigned short* ybuf  = (unsigned short*)p;  // region R: ybuf / hg / ffin
  unsigned short* hg    = (unsigned short*)p;
  unsigned short* ffin  = (unsigned short*)p;
  unsigned short* xn    = xnb + 3 * DM;
  unsigned short* wgvT  = wgT;  // interleaved [5632][1024] spans wgT+wvT slots

  // dtype detection + weight conversion (once per call)
  detect_k<<<1, 256, 0, stream>>>((const unsigned short*)x, flag);
  // whg: in (h*256+k)*768+n -> out (h*768+n)*256+k
  tr_tile<<<dim3(4, 48, 4), 256, 0, stream>>>(w_hg, whgT, 768, 256, 256, 768, 256, flag);
  // wout: in (h*384+k)*256+n -> out (h*256+n)*384+k
  tr_tile<<<dim3(6, 16, 4), 256, 0, stream>>>(w_out, woutT, 256, 384, 384, 256, 384, flag);
  if (big) {
    tr_wgv_t<<<dim3(16, 352), 256, 0, stream>>>(w_gate, w_val, wgvT, flag);
  } else {
    tr_wg<<<11264, 256, 0, stream>>>(w_gate, wgT, flag);
    tr_wg<<<11264, 256, 0, stream>>>(w_val, wvT, flag);
  }
  // wfo: in kk*DM+n (kk<FFN) -> out n*FFP+kk, zero pad kk>=FFN
  tr_tile<<<dim3(44, 64, 1), 256, 0, stream>>>(w_ffo, wfoT, DM, FFP, FFP, DM, FFN, flag);
  cvt_k<<<4096, 256, 0, stream>>>(pw_w, pwT, 1048576, flag);
  cvt_k<<<16, 256, 0, stream>>>(dw_w, dwwB, 4096, flag);
  cvt_k<<<4, 256, 0, stream>>>(dw_b, dwbB, 1024, flag);
  cvt_k<<<4, 256, 0, stream>>>(pw_b, pwbB, 1024, flag);
  cvt_k<<<4, 256, 0, stream>>>(conv_g, cgB, 1024, flag);
  cvt_k<<<4, 256, 0, stream>>>(gru_g, ggB, 1024, flag);
  cvt_k<<<4, 256, 0, stream>>>(ff_g, fgB, 1024, flag);

  for (long t0 = 0; t0 < 16384; t0 += MT) {
    const int l0     = (int)(t0 & (SEQL - 1));
    const int P      = (l0 > 0) ? 3 : 0;
    const int seqEnd = (l0 + SL == SEQL);
    const long nhOff = NH_OFF + (t0 / SEQL) * 1536;

    // conv block: xc = pw(dwconv(rmsnorm(x))) + pw_b + x
    rmsnorm_x<<<MT + P, 64, 0, stream>>>(x, (t0 - P) * DM, cgB, xn - (long)P * DM, flag);
    dwconv_k<<<dim3(MT, 2), 256, 0, stream>>>(xn, dwwB, dwbB, ybuf, l0);
    gemm_bf16<1, DM><<<dim3(8, MT / 128, 1), 256, 0, stream>>>(ybuf, DM, 0, pwT, 0,
        xc, DM, 0, 0L, pwbB, x, DM, t0 * DM, flag);

    // GRU block
    rmsnorm_k<<<MT, 64, 0, stream>>>(xc, ggB, xn);
    gemm_bf16<0, 256><<<dim3(6, MT / 128, 4), 256, 0, stream>>>(xn, DM, 256, whgT, 196608,
        hg, 3072, 768, 0L, nullptr, nullptr, 0, 0L, nullptr);
    scan_p1<<<dim3(CHNp, nSeq * 4), 192, 0, stream>>>(hg, cC, cV, chTot, SL);
    scan_p2<<<nSeq * 4, 384, 0, stream>>>(cC, cV, hin, chTot, CHNp, hcarry, l0 > 0);
    scan_p3<<<dim3(CHNp, nSeq * 4), 192, 0, stream>>>(hg, hin, hbuf, d_out, nhOff,
        hcarry, chTot, SL, CHNp, seqEnd, flag);
    gemm_bf16<2, 384><<<dim3(2, MT / 128, 4), 256, 0, stream>>>(hbuf, 1536, 384, woutT, 98304,
        xc, DM, 256, 0L, nullptr, xc, DM, 0L, nullptr);

    // FF block
    rmsnorm_k<<<MT, 64, 0, stream>>>(xc, fgB, xn);
    if (big) {
      gemm256<0, DM><<<dim3(22, MT / 256), 1024, 0, stream>>>(xn, wgvT,
          ffin, nullptr, 0L, nullptr);
      gemm256<1, FFP><<<dim3(4, MT / 256), 1024, 0, stream>>>(ffin, wfoT,
          d_out, xc, t0 * DM, flag);
    } else {
      gemm_ff<<<dim3(22, MT / 128), 256, 0, stream>>>(xn, wgT, wvT, ffin);
      gemm_bf16<3, FFP><<<dim3(8, MT / 128, 1), 256, 0, stream>>>(ffin, FFP, 0, wfoT, 0,
          d_out, DM, 0, t0 * DM, nullptr, xc, DM, 0L, flag);
    }
  }
}

// Round 12
// 877.051 us; speedup vs baseline: 4.2500x; 1.0412x over previous
//
#include <hip/hip_runtime.h>
#include <stdint.h>

// MinGRUBlock on MI355X (gfx950). Input/output dtype (f32 vs bf16) DETECTED at
// runtime from x's bit patterns (flag in ws). Internals bf16. Residual in ws.
// ALL five big-path GEMMs now use the 16-wave 256^2 structure (round-12):
// 1024 thr = 4 waves/SIMD, per-wave 64x64, acc 64 AGPR + 32 VGPR frag peak,
// BK=64, dbuf 128 KiB LDS, chunk-XOR swizzle, stage-into-dead-buffer +
// vmcnt(0) publish, K templated (NT = 16/4/6/44), runtime lda/ldc/offsets in
// SGPRs (reg-neutral). EPIs: 0 plain, 1 bias+raw-res, 2 bf16-res (z cols),
// 3 FF silu-combine (gate/value interleaved B), 4 raw-out+bf16-res.
// Weight-prep transposes: LDS-tiled coalesced. scan/dwconv: ushort2-vectorized.
// Scan: 3-phase chunked, h_t = sigmoid(-g)*h + sigmoid(g)*gfun(hid), f32 carry.

#define DM     1024
#define SEQL   4096
#define FFN    2730
#define FFP    2816
#define NH_OFF 16777216L
#define CHLEN  128

using bf16x8 = __attribute__((ext_vector_type(8))) short;
using f32x4  = __attribute__((ext_vector_type(4))) float;

__device__ __forceinline__ float bf2f(unsigned short h) {
  union { unsigned int u; float f; } v; v.u = ((unsigned int)h) << 16; return v.f;
}
__device__ __forceinline__ unsigned short f2bf(float f) {
  union { float f; unsigned int u; } v; v.f = f;
  unsigned int u = v.u;
  return (unsigned short)((u + 0x7fffu + ((u >> 16) & 1u)) >> 16);
}
__device__ __forceinline__ float bf2f_lo(unsigned int u2) {
  union { unsigned int u; float f; } v; v.u = u2 << 16; return v.f;
}
__device__ __forceinline__ float bf2f_hi(unsigned int u2) {
  union { unsigned int u; float f; } v; v.u = u2 & 0xffff0000u; return v.f;
}
__device__ __forceinline__ unsigned int pack2(float a, float b) {
  return (unsigned int)f2bf(a) | ((unsigned int)f2bf(b) << 16);
}
__device__ __forceinline__ float ldin(const void* p, long i, int f32mode) {
  return f32mode ? ((const float*)p)[i] : bf2f(((const unsigned short*)p)[i]);
}
__device__ __forceinline__ void stout(void* p, long i, int f32mode, float v) {
  if (f32mode) ((float*)p)[i] = v; else ((unsigned short*)p)[i] = f2bf(v);
}
__device__ __forceinline__ void gload_lds16(const unsigned short* g, unsigned short* lds) {
  __builtin_amdgcn_global_load_lds(
      (const __attribute__((address_space(1))) unsigned int*)g,
      (__attribute__((address_space(3))) unsigned int*)lds,
      16, 0, 0);
}

// ---------------- dtype detection --------------------------------------------
__global__ void detect_k(const unsigned short* __restrict__ x, int* __restrict__ flag) {
  __shared__ int cnt;
  if (threadIdx.x == 0) cnt = 0;
  __syncthreads();
  int c = 0;
  for (int j = 0; j < 4; j++) {
    unsigned short v = x[2 * (threadIdx.x * 4 + j)];
    int ex = (v >> 7) & 0xFF;
    if (ex >= 0x84) c++;
  }
  atomicAdd(&cnt, c);
  __syncthreads();
  if (threadIdx.x == 0) *flag = (cnt >= 32) ? 1 : 0;
}

// ---------------- legacy 128^2 GEMM (small-MT fallback path) ------------------
template <int EPI, int K>
__launch_bounds__(256)
__global__ void gemm_bf16(const unsigned short* __restrict__ A, int lda, int aOffZ,
                          const unsigned short* __restrict__ Bm, int bOffZ,
                          void* __restrict__ Cout, int ldc, int cOffZ, long outOff,
                          const unsigned short* __restrict__ bias,
                          const void* __restrict__ res, int ldres, long resOff,
                          const int* __restrict__ flagp) {
  __shared__ __align__(16) unsigned short As[128][64];
  __shared__ __align__(16) unsigned short Bs[128][64];

  const int tid  = threadIdx.x;
  const int w    = tid >> 6;
  const int lane = tid & 63;
  const int z    = blockIdx.z;
  const long tm  = (long)blockIdx.y * 128;
  const long tn  = (long)blockIdx.x * 128;

  const unsigned short* Ag = A + (long)z * aOffZ;
  const unsigned short* Bg = Bm + (long)z * bOffZ;

  f32x4 acc[4][4];
#pragma unroll
  for (int i = 0; i < 4; i++)
#pragma unroll
    for (int j = 0; j < 4; j++) acc[i][j] = (f32x4){0.f, 0.f, 0.f, 0.f};

  const int wrow = w * 32;
  const int srow = lane >> 3;
  const int scol = (((lane & 7) ^ srow) * 8);
  const int wm   = (w >> 1) * 64;
  const int wn   = (w & 1) * 64;
  const int quad = lane >> 4;
  const int lo   = lane & 15;
  const int sw   = lo & 7;

  for (int k0 = 0; k0 < K; k0 += 64) {
    __syncthreads();
#pragma unroll
    for (int i = 0; i < 4; i++) {
      const int r = wrow + i * 8;
      gload_lds16(Ag + (tm + r + srow) * (long)lda + k0 + scol, &As[r][0]);
      gload_lds16(Bg + (tn + r + srow) * (long)K + k0 + scol, &Bs[r][0]);
    }
    __syncthreads();
#pragma unroll
    for (int kk = 0; kk < 64; kk += 32) {
      const int kc = kk >> 3;
      bf16x8 af[4], bfr[4];
#pragma unroll
      for (int mt = 0; mt < 4; mt++)
        af[mt] = *(const bf16x8*)&As[wm + mt * 16 + lo][((quad + kc) ^ sw) * 8];
#pragma unroll
      for (int nt = 0; nt < 4; nt++)
        bfr[nt] = *(const bf16x8*)&Bs[wn + nt * 16 + lo][((quad + kc) ^ sw) * 8];
#pragma unroll
      for (int mt = 0; mt < 4; mt++)
#pragma unroll
        for (int nt = 0; nt < 4; nt++)
          acc[mt][nt] = __builtin_amdgcn_mfma_f32_16x16x32_bf16(af[mt], bfr[nt], acc[mt][nt], 0, 0, 0);
    }
  }

  const int f32m = (EPI == 1 || EPI == 3) ? *flagp : 0;
#pragma unroll
  for (int mt = 0; mt < 4; mt++) {
#pragma unroll
    for (int nt = 0; nt < 4; nt++) {
#pragma unroll
      for (int r = 0; r < 4; r++) {
        const long grow = tm + wm + mt * 16 + quad * 4 + r;
        const long gcol = tn + wn + nt * 16 + lo;
        float v         = acc[mt][nt][r];
        if (EPI == 0) {
          ((unsigned short*)Cout + (long)z * cOffZ)[grow * (long)ldc + gcol] = f2bf(v);
        } else if (EPI == 1) {
          v += bf2f(bias[gcol]) + ldin(res, resOff + grow * (long)ldres + gcol, f32m);
          ((unsigned short*)Cout)[grow * (long)ldc + gcol] = f2bf(v);
        } else if (EPI == 2) {
          v += bf2f(((const unsigned short*)res + (long)z * cOffZ)[grow * (long)ldres + gcol]);
          ((unsigned short*)Cout + (long)z * cOffZ)[grow * (long)ldc + gcol] = f2bf(v);
        } else {  // EPI == 3: final output
          v += bf2f(((const unsigned short*)res)[grow * (long)ldres + gcol]);
          stout(Cout, outOff + grow * (long)ldc + gcol, f32m, v);
        }
      }
    }
  }
}

// ---------------- fused FF GEMM (legacy 128^2 path, used when MT<256) ---------
__launch_bounds__(256)
__global__ void gemm_ff(const unsigned short* __restrict__ A,
                        const unsigned short* __restrict__ Bgm,
                        const unsigned short* __restrict__ Bvm,
                        unsigned short* __restrict__ Cout) {
  __shared__ __align__(16) unsigned short As[128][64];
  __shared__ __align__(16) unsigned short Bgs[128][64];
  __shared__ __align__(16) unsigned short Bvs[128][64];

  const int tid  = threadIdx.x;
  const int w    = tid >> 6;
  const int lane = tid & 63;
  const long tm  = (long)blockIdx.y * 128;
  const long tn  = (long)blockIdx.x * 128;

  f32x4 accG[4][4], accV[4][4];
#pragma unroll
  for (int i = 0; i < 4; i++)
#pragma unroll
    for (int j = 0; j < 4; j++) {
      accG[i][j] = (f32x4){0.f, 0.f, 0.f, 0.f};
      accV[i][j] = (f32x4){0.f, 0.f, 0.f, 0.f};
    }

  const int wrow = w * 32;
  const int srow = lane >> 3;
  const int scol = (((lane & 7) ^ srow) * 8);
  const int wm   = (w >> 1) * 64;
  const int wn   = (w & 1) * 64;
  const int quad = lane >> 4;
  const int lo   = lane & 15;
  const int sw   = lo & 7;

  for (int k0 = 0; k0 < DM; k0 += 64) {
    __syncthreads();
#pragma unroll
    for (int i = 0; i < 4; i++) {
      const int r = wrow + i * 8;
      gload_lds16(A + (tm + r + srow) * (long)DM + k0 + scol, &As[r][0]);
      gload_lds16(Bgm + (tn + r + srow) * (long)DM + k0 + scol, &Bgs[r][0]);
      gload_lds16(Bvm + (tn + r + srow) * (long)DM + k0 + scol, &Bvs[r][0]);
    }
    __syncthreads();
#pragma unroll
    for (int kk = 0; kk < 64; kk += 32) {
      const int kc = kk >> 3;
      bf16x8 af[4], bfr[4];
#pragma unroll
      for (int mt = 0; mt < 4; mt++)
        af[mt] = *(const bf16x8*)&As[wm + mt * 16 + lo][((quad + kc) ^ sw) * 8];
#pragma unroll
      for (int nt = 0; nt < 4; nt++)
        bfr[nt] = *(const bf16x8*)&Bgs[wn + nt * 16 + lo][((quad + kc) ^ sw) * 8];
#pragma unroll
      for (int mt = 0; mt < 4; mt++)
#pragma unroll
        for (int nt = 0; nt < 4; nt++)
          accG[mt][nt] = __builtin_amdgcn_mfma_f32_16x16x32_bf16(af[mt], bfr[nt], accG[mt][nt], 0, 0, 0);
#pragma unroll
      for (int nt = 0; nt < 4; nt++)
        bfr[nt] = *(const bf16x8*)&Bvs[wn + nt * 16 + lo][((quad + kc) ^ sw) * 8];
#pragma unroll
      for (int mt = 0; mt < 4; mt++)
#pragma unroll
        for (int nt = 0; nt < 4; nt++)
          accV[mt][nt] = __builtin_amdgcn_mfma_f32_16x16x32_bf16(af[mt], bfr[nt], accV[mt][nt], 0, 0, 0);
    }
  }

#pragma unroll
  for (int mt = 0; mt < 4; mt++) {
#pragma unroll
    for (int nt = 0; nt < 4; nt++) {
#pragma unroll
      for (int r = 0; r < 4; r++) {
        const long grow = tm + wm + mt * 16 + quad * 4 + r;
        const long gcol = tn + wn + nt * 16 + lo;
        const float g   = accG[mt][nt][r];
        const float s   = g / (1.f + __expf(-g));
        Cout[grow * (long)FFP + gcol] = f2bf(s * accV[mt][nt][r]);
      }
    }
  }
}

// ---------------- generalized 256^2 GEMM, 16 waves, 4 waves/SIMD -------------
// C[M,N] = A[M,K] * B^T, B stored [N][K] (ldb=K compile-time). Runtime lda /
// ldc / cOffZ / aOffZ / bOffZ are wave-uniform (SGPRs, reg-neutral vs the
// round-11 kernel which sat at exactly 64 VGPR + 64 AGPR with no spill).
// NT = K/64 must be even >= 4 (K = 1024/256/384/2816 -> 16/4/6/44).
// EPI 0: bf16 out at (Cout + z*cOffZ)[row*ldc + col].
// EPI 1: bf16 = acc + bias[col] + raw res (flag) at resOff + row*ldres + col.
// EPI 2: bf16 = acc + bf16 res (res + z*cOffZ); out (Cout + z*cOffZ).
// EPI 3: FF fused silu: B rows interleaved gate/value at 16-col granularity;
//        out ffin[row*FFP + tn/2 + ...] lane-local pairing.
// EPI 4: raw out (flag) = acc + bf16 res; at outOff + row*ldc + col.
template <int EPI, int K>
__launch_bounds__(1024, 4)
__global__ void gemm256(const unsigned short* __restrict__ A, int lda, int aOffZ,
                        const unsigned short* __restrict__ Bm, int bOffZ,
                        void* __restrict__ Cout, int ldc, int cOffZ, long outOff,
                        const unsigned short* __restrict__ bias,
                        const void* __restrict__ res, int ldres, long resOff,
                        const int* __restrict__ flagp) {
  __shared__ __align__(16) unsigned short As[2][256][64];
  __shared__ __align__(16) unsigned short Bs[2][256][64];

  const int tid  = threadIdx.x;
  const int w    = tid >> 6;      // 0..15
  const int lane = tid & 63;
  const int wr   = w >> 2;        // 0..3  (M band of 64)
  const int wc   = w & 3;         // 0..3  (N band of 64)
  const int quad = lane >> 4;
  const int lo   = lane & 15;
  const int sw   = lo & 7;
  const int z    = blockIdx.z;

  // bijective XCD-aware block swizzle (m204 formula)
  const int gx  = gridDim.x;
  int bid       = blockIdx.y * gx + blockIdx.x;
  const int nwg = gx * gridDim.y;
  {
    const int q = nwg >> 3, r8 = nwg & 7;
    const int xc8 = bid & 7, j = bid >> 3;
    bid = (xc8 < r8 ? xc8 * (q + 1) : r8 * (q + 1) + (xc8 - r8) * q) + j;
  }
  const long tn = (long)(bid % gx) * 256;  // B-row tile base
  const long tm = (long)(bid / gx) * 256;  // M tile base

  constexpr int NT = K >> 6;  // even, >= 4 by construction

  // staging source addressing: per-lane swizzled global address, linear LDS.
  const int srow = lane >> 3;                 // 0..7
  const int sch  = (lane & 7) ^ srow;         // source chunk = pos ^ key(row)
  const unsigned short* Ab = A + (long)z * aOffZ +
                             (tm + (long)(w * 16 + srow)) * (long)lda + sch * 8;
  const unsigned short* Bb = Bm + (long)z * bOffZ +
                             (tn + (long)(w * 16 + srow)) * (long)K + sch * 8;
  const long arstep = 8L * lda;  // wave-uniform (SGPR)

#define STAGE_A(BUF, TT)                                                          \
  gload_lds16(Ab + (long)(TT) * 64, &As[BUF][w * 16][0]);                         \
  gload_lds16(Ab + arstep + (long)(TT) * 64, &As[BUF][w * 16 + 8][0]);
#define STAGE_B(BUF, TT)                                                          \
  gload_lds16(Bb + (long)(TT) * 64, &Bs[BUF][w * 16][0]);                         \
  gload_lds16(Bb + 8L * K + (long)(TT) * 64, &Bs[BUF][w * 16 + 8][0]);

  // prologue: tile 0 only (tile 1 staged during tile 0)
  STAGE_B(0, 0)
  STAGE_A(0, 0)

  f32x4 acc[4][4];
#pragma unroll
  for (int i = 0; i < 4; i++)
#pragma unroll
    for (int j = 0; j < 4; j++) acc[i][j] = (f32x4){0.f, 0.f, 0.f, 0.f};

  asm volatile("s_waitcnt vmcnt(0)" ::: "memory");
  __builtin_amdgcn_s_barrier();

  bf16x8 a[2][2], b[2][2];

#define LDA2(CBUF, RB)                                                            \
  _Pragma("unroll") for (int m = 0; m < 2; m++) {                                 \
    _Pragma("unroll") for (int c = 0; c < 2; c++) {                               \
      a[m][c] = *(const bf16x8*)&As[CBUF][wr * 64 + ((RB) + m) * 16 + lo]         \
                                       [((quad + 4 * c) ^ sw) * 8];               \
    }                                                                             \
  }
#define LDB2(CBUF, NB)                                                            \
  _Pragma("unroll") for (int n = 0; n < 2; n++) {                                 \
    _Pragma("unroll") for (int c = 0; c < 2; c++) {                               \
      b[n][c] = *(const bf16x8*)&Bs[CBUF][wc * 64 + ((NB) + n) * 16 + lo]         \
                                       [((quad + 4 * c) ^ sw) * 8];               \
    }                                                                             \
  }
#define MFMA_Q(MB, NB)                                                            \
  __builtin_amdgcn_s_setprio(1);                                                  \
  _Pragma("unroll") for (int m = 0; m < 2; m++) {                                 \
    _Pragma("unroll") for (int n = 0; n < 2; n++) {                               \
      _Pragma("unroll") for (int c = 0; c < 2; c++) {                             \
        acc[(MB) + m][(NB) + n] = __builtin_amdgcn_mfma_f32_16x16x32_bf16(        \
            a[m][c], b[n][c], acc[(MB) + m][(NB) + n], 0, 0, 0);                  \
      }                                                                           \
    }                                                                             \
  }                                                                               \
  __builtin_amdgcn_s_setprio(0);

// One sub-tile. STG: stage tile TT+1 into CBUF^1 (holds dead tile TT-1).
#define SUBTILE(CBUF, TT, STG)                                                    \
  {                                                                               \
    /* P0: aL + b01; stage B(TT+1); MFMA Q0 = mLo x nLo */                        \
    LDA2(CBUF, 0);                                                                \
    LDB2(CBUF, 0);                                                                \
    if (STG) { STAGE_B(CBUF ^ 1, (TT) + 1) }                                      \
    MFMA_Q(0, 0);                                                                 \
    __builtin_amdgcn_s_barrier();                                                 \
    /* P1: b23 (b01 consumed); stage A(TT+1); MFMA Q1 = mLo x nHi */              \
    LDB2(CBUF, 2);                                                                \
    if (STG) { STAGE_A(CBUF ^ 1, (TT) + 1) }                                      \
    MFMA_Q(0, 2);                                                                 \
    __builtin_amdgcn_s_barrier();                                                 \
    /* P2: aH (aL consumed); MFMA Q2 = mHi x nHi */                               \
    LDA2(CBUF, 2);                                                                \
    MFMA_Q(2, 2);                                                                 \
    __builtin_amdgcn_s_barrier();                                                 \
    /* P3: re-read b01; MFMA Q3 = mHi x nLo; publish staged tile */               \
    LDB2(CBUF, 0);                                                                \
    MFMA_Q(2, 0);                                                                 \
    if (STG) asm volatile("s_waitcnt vmcnt(0)" ::: "memory");                     \
    __builtin_amdgcn_s_barrier();                                                 \
  }

  // main loop: tiles 0..NT-2 stage their successor; tile NT-1 stages nothing
  for (int t = 0; t < NT - 2; t += 2) {
    SUBTILE(0, t, 1)
    SUBTILE(1, t + 1, 1)
  }
  SUBTILE(0, NT - 2, 1)
  SUBTILE(1, NT - 1, 0)

  const long rowb = tm + wr * 64;
  if (EPI == 3) {
    // silu(gate) * value, lane-local pairing; ffin col base = tn/2
    const long colb = (tn >> 1);
#pragma unroll
    for (int m = 0; m < 4; m++) {
#pragma unroll
      for (int np = 0; np < 2; np++) {
        const long col = colb + (wc * 2 + np) * 16 + lo;
#pragma unroll
        for (int r = 0; r < 4; r++) {
          const long row = rowb + m * 16 + quad * 4 + r;
          const float g  = acc[m][2 * np][r];
          const float v  = acc[m][2 * np + 1][r];
          const float s  = g / (1.f + __expf(-g));
          ((unsigned short*)Cout)[row * (long)FFP + col] = f2bf(s * v);
        }
      }
    }
  } else {
    const int f32m = (EPI == 1 || EPI == 4) ? *flagp : 0;
    const long colb = tn + wc * 64;
#pragma unroll
    for (int m = 0; m < 4; m++) {
#pragma unroll
      for (int n = 0; n < 4; n++) {
#pragma unroll
        for (int r = 0; r < 4; r++) {
          const long row = rowb + m * 16 + quad * 4 + r;
          const long col = colb + n * 16 + lo;
          float v = acc[m][n][r];
          if (EPI == 0) {
            ((unsigned short*)Cout + (long)z * cOffZ)[row * (long)ldc + col] = f2bf(v);
          } else if (EPI == 1) {
            v += bf2f(bias[col]) + ldin(res, resOff + row * (long)ldres + col, f32m);
            ((unsigned short*)Cout)[row * (long)ldc + col] = f2bf(v);
          } else if (EPI == 2) {
            v += bf2f(((const unsigned short*)res + (long)z * cOffZ)[row * (long)ldres + col]);
            ((unsigned short*)Cout + (long)z * cOffZ)[row * (long)ldc + col] = f2bf(v);
          } else {  // EPI == 4: final output
            v += bf2f(((const unsigned short*)res)[row * (long)ldres + col]);
            stout(Cout, outOff + row * (long)ldc + col, f32m, v);
          }
        }
      }
    }
  }
#undef STAGE_A
#undef STAGE_B
#undef LDA2
#undef LDB2
#undef MFMA_Q
#undef SUBTILE
}

// ---------------- RMSNorm: raw input variant (flag) --------------------------
__global__ void rmsnorm_x(const void* __restrict__ in, long elemOff,
                          const unsigned short* __restrict__ gamma,
                          unsigned short* __restrict__ out,
                          const int* __restrict__ flagp) {
  const int t    = blockIdx.x;
  const int lane = threadIdx.x;
  const int f32m = *flagp;
  float v[16];
  const long base = elemOff + (long)t * DM;
  if (f32m) {
    const float4* rp = (const float4*)((const float*)in + base);
#pragma unroll
    for (int j = 0; j < 4; j++) {
      float4 u     = rp[j * 64 + lane];
      v[j * 4 + 0] = u.x; v[j * 4 + 1] = u.y; v[j * 4 + 2] = u.z; v[j * 4 + 3] = u.w;
    }
  } else {
    const ushort4* rp = (const ushort4*)((const unsigned short*)in + base);
#pragma unroll
    for (int j = 0; j < 4; j++) {
      ushort4 u    = rp[j * 64 + lane];
      v[j * 4 + 0] = bf2f(u.x); v[j * 4 + 1] = bf2f(u.y);
      v[j * 4 + 2] = bf2f(u.z); v[j * 4 + 3] = bf2f(u.w);
    }
  }
  float s = 0.f;
#pragma unroll
  for (int i = 0; i < 16; i++) s = fmaf(v[i], v[i], s);
#pragma unroll
  for (int off = 32; off > 0; off >>= 1) s += __shfl_xor(s, off, 64);
  const float scale = 32.f / fmaxf(sqrtf(s), 1e-12f);
  ushort4* op       = (ushort4*)(out + (long)t * DM);
  const ushort4* gp = (const ushort4*)gamma;
#pragma unroll
  for (int j = 0; j < 4; j++) {
    ushort4 g = gp[j * 64 + lane];
    ushort4 o;
    o.x = f2bf(v[j * 4 + 0] * scale * (bf2f(g.x) + 1.f));
    o.y = f2bf(v[j * 4 + 1] * scale * (bf2f(g.y) + 1.f));
    o.z = f2bf(v[j * 4 + 2] * scale * (bf2f(g.z) + 1.f));
    o.w = f2bf(v[j * 4 + 3] * scale * (bf2f(g.w) + 1.f));
    op[j * 64 + lane] = o;
  }
}

// ---------------- RMSNorm (bf16 in/out) --------------------------------------
__global__ void rmsnorm_k(const unsigned short* __restrict__ in,
                          const unsigned short* __restrict__ gamma,
                          unsigned short* __restrict__ out) {
  const int t    = blockIdx.x;
  const int lane = threadIdx.x;
  float v[16];
  const ushort4* rp = (const ushort4*)(in + (long)t * DM);
#pragma unroll
  for (int j = 0; j < 4; j++) {
    ushort4 u    = rp[j * 64 + lane];
    v[j * 4 + 0] = bf2f(u.x); v[j * 4 + 1] = bf2f(u.y);
    v[j * 4 + 2] = bf2f(u.z); v[j * 4 + 3] = bf2f(u.w);
  }
  float s = 0.f;
#pragma unroll
  for (int i = 0; i < 16; i++) s = fmaf(v[i], v[i], s);
#pragma unroll
  for (int off = 32; off > 0; off >>= 1) s += __shfl_xor(s, off, 64);
  const float scale = 32.f / fmaxf(sqrtf(s), 1e-12f);
  ushort4* op       = (ushort4*)(out + (long)t * DM);
  const ushort4* gp = (const ushort4*)gamma;
#pragma unroll
  for (int j = 0; j < 4; j++) {
    ushort4 g = gp[j * 64 + lane];
    ushort4 o;
    o.x = f2bf(v[j * 4 + 0] * scale * (bf2f(g.x) + 1.f));
    o.y = f2bf(v[j * 4 + 1] * scale * (bf2f(g.y) + 1.f));
    o.z = f2bf(v[j * 4 + 2] * scale * (bf2f(g.z) + 1.f));
    o.w = f2bf(v[j * 4 + 3] * scale * (bf2f(g.w) + 1.f));
    op[j * 64 + lane] = o;
  }
}

// ---------------- causal depthwise conv K=4, ushort2-vectorized ---------------
__global__ void dwconv_k(const unsigned short* __restrict__ xn,
                         const unsigned short* __restrict__ dww,
                         const unsigned short* __restrict__ dwb,
                         unsigned short* __restrict__ y, int l0) {
  const int t  = blockIdx.x;
  const int d0 = blockIdx.y * 512 + threadIdx.x * 2;
  const int l  = l0 + (t & (SEQL - 1));
  ushort4 wa = ((const ushort4*)dww)[d0];
  ushort4 wb = ((const ushort4*)dww)[d0 + 1];
  float wk0[4] = {bf2f(wa.x), bf2f(wa.y), bf2f(wa.z), bf2f(wa.w)};
  float wk1[4] = {bf2f(wb.x), bf2f(wb.y), bf2f(wb.z), bf2f(wb.w)};
  unsigned int b2 = *(const unsigned int*)&dwb[d0];
  float acc0 = bf2f_lo(b2), acc1 = bf2f_hi(b2);
#pragma unroll
  for (int k = 0; k < 4; k++) {
    const int ll = l + k - 3;
    if (ll >= 0) {
      unsigned int x2 = *(const unsigned int*)&xn[(long)(t + k - 3) * DM + d0];
      acc0 = fmaf(bf2f_lo(x2), wk0[k], acc0);
      acc1 = fmaf(bf2f_hi(x2), wk1[k], acc1);
    }
  }
  *(unsigned int*)&y[(long)t * DM + d0] = pack2(acc0, acc1);
}

// ---------------- scan --------------------------------------------------------
__device__ __forceinline__ void cv_compute(float gt, float& c, float& sg) {
  gt = fminf(fmaxf(gt, -40.f), 40.f);
  const float e  = __expf(-fabsf(gt));
  const float r  = 1.f / (1.f + e);
  const float rs = e * r;
  c  = (gt >= 0.f) ? rs : r;   // sigmoid(-gt)
  sg = (gt >= 0.f) ? r : rs;   // sigmoid(gt)
}
__device__ __forceinline__ float gfun(float hid) {
  hid = fminf(fmaxf(hid, -40.f), 40.f);
  if (hid >= 0.f) return hid + 0.5f;
  const float e = __expf(hid);
  return e / (1.f + e);
}

// 192 threads, 2 channels/thread (ushort2 loads)
__global__ void scan_p1(const unsigned short* __restrict__ hg, float* __restrict__ cC,
                        float* __restrict__ cV, int chTot, int SL) {
  const int e0 = threadIdx.x * 2, bh = blockIdx.y, cid = blockIdx.x;
  const int bL = bh >> 2, hh = bh & 3;
  long base = ((long)(bL * SL + cid * CHLEN)) * 3072 + hh * 768 + e0;
  float C0 = 1.f, V0 = 0.f, C1 = 1.f, V1 = 0.f;
  for (int i = 0; i < CHLEN; i++) {
    const unsigned int h2 = *(const unsigned int*)&hg[base];
    const unsigned int g2 = *(const unsigned int*)&hg[base + 384];
    float c, sg;
    cv_compute(bf2f_lo(g2), c, sg);
    C0 *= c; V0 = fmaf(c, V0, sg * gfun(bf2f_lo(h2)));
    cv_compute(bf2f_hi(g2), c, sg);
    C1 *= c; V1 = fmaf(c, V1, sg * gfun(bf2f_hi(h2)));
    base += 3072;
  }
  const int idx = cid * chTot + bh * 384 + e0;
  cC[idx] = C0; cC[idx + 1] = C1;
  cV[idx] = V0; cV[idx + 1] = V1;
}

__global__ void scan_p2(const float* __restrict__ cC, const float* __restrict__ cV,
                        float* __restrict__ hin, int chTot, int CHNp,
                        const float* __restrict__ hcarry, int useCarry) {
  const int ch = blockIdx.x * 384 + threadIdx.x;
  float h = useCarry ? hcarry[ch] : 0.f;
  for (int cid = 0; cid < CHNp; cid++) {
    const int idx = cid * chTot + ch;
    hin[idx] = h;
    h = fmaf(cC[idx], h, cV[idx]);
  }
}

// 192 threads, 2 channels/thread
__global__ void scan_p3(const unsigned short* __restrict__ hg, const float* __restrict__ hin,
                        unsigned short* __restrict__ hout, void* __restrict__ nh, long nhOff,
                        float* __restrict__ hcarry, int chTot, int SL, int CHNp,
                        int writeNh, const int* __restrict__ flagp) {
  const int e0 = threadIdx.x * 2, bh = blockIdx.y, cid = blockIdx.x;
  const int bL = bh >> 2, hh = bh & 3;
  const long tok = (long)bL * SL + (long)cid * CHLEN;
  long base  = tok * 3072 + hh * 768 + e0;
  long obase = tok * 1536 + hh * 384 + e0;
  const int idx = cid * chTot + bh * 384 + e0;
  float h0 = hin[idx], h1 = hin[idx + 1];
  for (int i = 0; i < CHLEN; i++) {
    const unsigned int h2 = *(const unsigned int*)&hg[base];
    const unsigned int g2 = *(const unsigned int*)&hg[base + 384];
    float c, sg;
    cv_compute(bf2f_lo(g2), c, sg);
    h0 = fmaf(c, h0, sg * gfun(bf2f_lo(h2)));
    cv_compute(bf2f_hi(g2), c, sg);
    h1 = fmaf(c, h1, sg * gfun(bf2f_hi(h2)));
    *(unsigned int*)&hout[obase] = pack2(h0, h1);
    base += 3072; obase += 1536;
  }
  if (cid == CHNp - 1) {
    hcarry[bh * 384 + e0]     = h0;
    hcarry[bh * 384 + e0 + 1] = h1;
    if (writeNh) {
      const int f32m = *flagp;
      stout(nh, nhOff + bL * 1536 + hh * 384 + e0, f32m, h0);
      stout(nh, nhOff + bL * 1536 + hh * 384 + e0 + 1, f32m, h1);
    }
  }
}

// ---------------- weight conversion -------------------------------------------
__global__ void cvt_k(const void* __restrict__ in, unsigned short* __restrict__ out,
                      int n, const int* __restrict__ flagp) {
  const int i = blockIdx.x * 256 + threadIdx.x;
  if (i < n) out[i] = f2bf(ldin(in, i, *flagp));
}

// ---------------- LDS-tiled coalesced transpose -------------------------------
// out[(z*NRz + nb + r)*LDO + k0 + kx] = in[(z*NKz + k0 + kx)*LDI + nb + r]
// (zero when src k >= KV). Block = 16 out-rows x 64 out-cols.
__global__ void tr_tile(const void* __restrict__ in, unsigned short* __restrict__ out,
                        int LDI, int NKz, int LDO, int NRz, int KV,
                        const int* __restrict__ flagp) {
  __shared__ float tile[64][17];
  const int f32m = *flagp;
  const int k0 = blockIdx.x * 64;
  const int nb = blockIdx.y * 16;
  const int z  = blockIdx.z;
  const int t  = threadIdx.x;
  const int c  = t & 15;     // n offset (contiguous in src)
  const int kl = t >> 4;     // 0..15
#pragma unroll
  for (int j = 0; j < 4; j++) {
    const int k = k0 + j * 16 + kl;
    tile[j * 16 + kl][c] =
        (k < KV) ? ldin(in, ((long)z * NKz + k) * (long)LDI + nb + c, f32m) : 0.f;
  }
  __syncthreads();
  const int kx = t & 63;
  const int rr = t >> 6;     // 0..3
#pragma unroll
  for (int j = 0; j < 4; j++) {
    const int r = j * 4 + rr;
    out[((long)z * NRz + nb + r) * (long)LDO + k0 + kx] = f2bf(tile[kx][r]);
  }
}

// interleaved gate/value transpose, tiled (16-aligned R-groups share sel/colb)
__global__ void tr_wgv_t(const void* __restrict__ wg, const void* __restrict__ wv,
                         unsigned short* __restrict__ out, const int* __restrict__ flagp) {
  __shared__ float tile[64][17];
  const int f32m = *flagp;
  const int k0 = blockIdx.x * 64;   // 16 chunks (k < 1024)
  const int Rb = blockIdx.y * 16;   // 352 groups (R < 5632)
  const int tIdx = Rb >> 8;
  const int rb8  = Rb & 255;
  const int pair = rb8 >> 5, sel = (rb8 >> 4) & 1;
  const int colb = tIdx * 128 + pair * 16;
  const void* src = sel ? wv : wg;
  const int t  = threadIdx.x;
  const int c  = t & 15;
  const int kl = t >> 4;
#pragma unroll
  for (int j = 0; j < 4; j++) {
    const int k   = k0 + j * 16 + kl;
    const int col = colb + c;
    tile[j * 16 + kl][c] = (col < FFN) ? ldin(src, (long)k * FFN + col, f32m) : 0.f;
  }
  __syncthreads();
  const int kx = t & 63;
  const int rr = t >> 6;
#pragma unroll
  for (int j = 0; j < 4; j++) {
    const int r = j * 4 + rr;
    out[(long)(Rb + r) * 1024 + k0 + kx] = f2bf(tile[kx][r]);
  }
}

// scalar fallback transpose for the small-MT path (W as [N][K] w/ zero pad)
__global__ void tr_wg(const void* __restrict__ in, unsigned short* __restrict__ out,
                      const int* __restrict__ flagp) {
  const int idx = blockIdx.x * 256 + threadIdx.x;  // n*1024+k, n<2816
  const int k = idx & 1023, n = idx >> 10;
  out[idx] = (n < FFN) ? f2bf(ldin(in, (long)k * FFN + n, *flagp)) : (unsigned short)0;
}

// ---------------- launch ------------------------------------------------------
extern "C" void kernel_launch(void* const* d_in, const int* in_sizes, int n_in,
                              void* d_out, int out_size, void* d_ws, size_t ws_size,
                              hipStream_t stream) {
  const void* x      = d_in[0];
  const void* dw_w   = d_in[1];
  const void* dw_b   = d_in[2];
  const void* pw_w   = d_in[3];  // [N=1024][K=1024] already
  const void* pw_b   = d_in[4];
  const void* conv_g = d_in[5];
  const void* gru_g  = d_in[6];
  const void* ff_g   = d_in[7];
  const void* w_hg   = d_in[8];
  const void* w_out  = d_in[9];
  const void* w_gate = d_in[10];
  const void* w_val  = d_in[11];
  const void* w_ffo  = d_in[12];

  // Pass size from ws_size (deterministic): need(MT) = 21,795,072 + MT*13,888.
  const long FIXED = 21795072L;
  int MT = 128;
  if      (ws_size >= (size_t)(FIXED + 16384L * 13888)) MT = 16384;
  else if (ws_size >= (size_t)(FIXED + 8192L * 13888))  MT = 8192;
  else if (ws_size >= (size_t)(FIXED + 4096L * 13888))  MT = 4096;
  else if (ws_size >= (size_t)(FIXED + 2048L * 13888))  MT = 2048;
  else if (ws_size >= (size_t)(FIXED + 1024L * 13888))  MT = 1024;
  else if (ws_size >= (size_t)(FIXED + 512L * 13888))   MT = 512;
  else if (ws_size >= (size_t)(FIXED + 256L * 13888))   MT = 256;

  const int SL    = (MT >= SEQL) ? SEQL : MT;
  const int nSeq  = MT / SL;
  const int CHNp  = SL / CHLEN;
  const int chTot = nSeq * 1536;
  const int big   = (MT >= 256);  // 256^2 16-wave path for all GEMMs

  char* p = (char*)d_ws;
  unsigned short* whgT  = (unsigned short*)p; p += 1572864;
  unsigned short* woutT = (unsigned short*)p; p += 786432;
  unsigned short* wgT   = (unsigned short*)p; p += 5767168;
  unsigned short* wvT   = (unsigned short*)p; p += 5767168;
  unsigned short* wfoT  = (unsigned short*)p; p += 5767168;
  unsigned short* pwT   = (unsigned short*)p; p += 2097152;
  unsigned short* dwwB  = (unsigned short*)p; p += 8192;
  unsigned short* dwbB  = (unsigned short*)p; p += 2048;
  unsigned short* pwbB  = (unsigned short*)p; p += 2048;
  unsigned short* cgB   = (unsigned short*)p; p += 2048;
  unsigned short* ggB   = (unsigned short*)p; p += 2048;
  unsigned short* fgB   = (unsigned short*)p; p += 2048;
  int*            flag  = (int*)p;            p += 256;
  float*          hcarry= (float*)p;          p += 12288;
  float*          cC    = (float*)p;          p += (long)MT * 192;
  float*          cV    = (float*)p;          p += (long)MT * 192;
  float*          hin   = (float*)p;          p += (long)MT * 192;
  unsigned short* xnb   = (unsigned short*)p; p += 6144 + (long)MT * 2048;
  unsigned short* xc    = (unsigned short*)p; p += (long)MT * 2048;
  unsigned short* hbuf  = (unsigned short*)p; p += (long)MT * 3072;
  unsigned short* ybuf  = (unsigned short*)p;  // region R: ybuf / hg / ffin
  unsigned short* hg    = (unsigned short*)p;
  unsigned short* ffin  = (unsigned short*)p;
  unsigned short* xn    = xnb + 3 * DM;
  unsigned short* wgvT  = wgT;  // interleaved [5632][1024] spans wgT+wvT slots

  // dtype detection + weight conversion (once per call)
  detect_k<<<1, 256, 0, stream>>>((const unsigned short*)x, flag);
  // whg: in (h*256+k)*768+n -> out (h*768+n)*256+k
  tr_tile<<<dim3(4, 48, 4), 256, 0, stream>>>(w_hg, whgT, 768, 256, 256, 768, 256, flag);
  // wout: in (h*384+k)*256+n -> out (h*256+n)*384+k
  tr_tile<<<dim3(6, 16, 4), 256, 0, stream>>>(w_out, woutT, 256, 384, 384, 256, 384, flag);
  if (big) {
    tr_wgv_t<<<dim3(16, 352), 256, 0, stream>>>(w_gate, w_val, wgvT, flag);
  } else {
    tr_wg<<<11264, 256, 0, stream>>>(w_gate, wgT, flag);
    tr_wg<<<11264, 256, 0, stream>>>(w_val, wvT, flag);
  }
  // wfo: in kk*DM+n (kk<FFN) -> out n*FFP+kk, zero pad kk>=FFN
  tr_tile<<<dim3(44, 64, 1), 256, 0, stream>>>(w_ffo, wfoT, DM, FFP, FFP, DM, FFN, flag);
  cvt_k<<<4096, 256, 0, stream>>>(pw_w, pwT, 1048576, flag);
  cvt_k<<<16, 256, 0, stream>>>(dw_w, dwwB, 4096, flag);
  cvt_k<<<4, 256, 0, stream>>>(dw_b, dwbB, 1024, flag);
  cvt_k<<<4, 256, 0, stream>>>(pw_b, pwbB, 1024, flag);
  cvt_k<<<4, 256, 0, stream>>>(conv_g, cgB, 1024, flag);
  cvt_k<<<4, 256, 0, stream>>>(gru_g, ggB, 1024, flag);
  cvt_k<<<4, 256, 0, stream>>>(ff_g, fgB, 1024, flag);

  for (long t0 = 0; t0 < 16384; t0 += MT) {
    const int l0     = (int)(t0 & (SEQL - 1));
    const int P      = (l0 > 0) ? 3 : 0;
    const int seqEnd = (l0 + SL == SEQL);
    const long nhOff = NH_OFF + (t0 / SEQL) * 1536;

    // conv block: xc = pw(dwconv(rmsnorm(x))) + pw_b + x
    rmsnorm_x<<<MT + P, 64, 0, stream>>>(x, (t0 - P) * DM, cgB, xn - (long)P * DM, flag);
    dwconv_k<<<dim3(MT, 2), 256, 0, stream>>>(xn, dwwB, dwbB, ybuf, l0);
    if (big) {
      gemm256<1, DM><<<dim3(4, MT / 256, 1), 1024, 0, stream>>>(ybuf, DM, 0, pwT, 0,
          xc, DM, 0, 0L, pwbB, x, DM, t0 * DM, flag);
    } else {
      gemm_bf16<1, DM><<<dim3(8, MT / 128, 1), 256, 0, stream>>>(ybuf, DM, 0, pwT, 0,
          xc, DM, 0, 0L, pwbB, x, DM, t0 * DM, flag);
    }

    // GRU block
    rmsnorm_k<<<MT, 64, 0, stream>>>(xc, ggB, xn);
    if (big) {
      gemm256<0, 256><<<dim3(3, MT / 256, 4), 1024, 0, stream>>>(xn, DM, 256, whgT, 196608,
          hg, 3072, 768, 0L, nullptr, nullptr, 0, 0L, nullptr);
    } else {
      gemm_bf16<0, 256><<<dim3(6, MT / 128, 4), 256, 0, stream>>>(xn, DM, 256, whgT, 196608,
          hg, 3072, 768, 0L, nullptr, nullptr, 0, 0L, nullptr);
    }
    scan_p1<<<dim3(CHNp, nSeq * 4), 192, 0, stream>>>(hg, cC, cV, chTot, SL);
    scan_p2<<<nSeq * 4, 384, 0, stream>>>(cC, cV, hin, chTot, CHNp, hcarry, l0 > 0);
    scan_p3<<<dim3(CHNp, nSeq * 4), 192, 0, stream>>>(hg, hin, hbuf, d_out, nhOff,
        hcarry, chTot, SL, CHNp, seqEnd, flag);
    if (big) {
      gemm256<2, 384><<<dim3(1, MT / 256, 4), 1024, 0, stream>>>(hbuf, 1536, 384, woutT, 98304,
          xc, DM, 256, 0L, nullptr, xc, DM, 0L, nullptr);
    } else {
      gemm_bf16<2, 384><<<dim3(2, MT / 128, 4), 256, 0, stream>>>(hbuf, 1536, 384, woutT, 98304,
          xc, DM, 256, 0L, nullptr, xc, DM, 0L, nullptr);
    }

    // FF block
    rmsnorm_k<<<MT, 64, 0, stream>>>(xc, fgB, xn);
    if (big) {
      gemm256<3, DM><<<dim3(22, MT / 256, 1), 1024, 0, stream>>>(xn, DM, 0, wgvT, 0,
          ffin, FFP, 0, 0L, nullptr, nullptr, 0, 0L, nullptr);
      gemm256<4, FFP><<<dim3(4, MT / 256, 1), 1024, 0, stream>>>(ffin, FFP, 0, wfoT, 0,
          d_out, DM, 0, t0 * DM, nullptr, xc, DM, 0L, flag);
    } else {
      gemm_ff<<<dim3(22, MT / 128), 256, 0, stream>>>(xn, wgT, wvT, ffin);
      gemm_bf16<3, FFP><<<dim3(8, MT / 128, 1), 256, 0, stream>>>(ffin, FFP, 0, wfoT, 0,
          d_out, DM, 0, t0 * DM, nullptr, xc, DM, 0L, flag);
    }
  }
}